// Round 10
// baseline (233.284 us; speedup 1.0000x reference)
//
#include <hip/hip_runtime.h>

typedef unsigned short u16;
typedef unsigned int u32;
typedef __attribute__((ext_vector_type(4))) float f32x4;
typedef __attribute__((ext_vector_type(8))) __bf16 bf16x8;
typedef __attribute__((ext_vector_type(8))) unsigned short u16x8;

#define MAXP_ 4096
#define TOTROWS 16384   // B*HQ*S = 2*16*512
#define NCHUNK 4
#define NCALLOC 4
#define CHUNKP 512

__device__ __forceinline__ u16 f2bf(float f) {
    union { float f; u32 u; } x; x.f = f;
    u32 r = x.u + 0x7FFFu + ((x.u >> 16) & 1u);
    return (u16)(r >> 16);
}
__device__ __forceinline__ float bf2f(u16 u) {
    union { u32 u; float f; } x; x.u = ((u32)u) << 16; return x.f;
}
// RNE bf16 pair pack
__device__ __forceinline__ u32 packbf(float lo, float hi) {
    return (u32)f2bf(lo) | ((u32)f2bf(hi) << 16);
}
__device__ __forceinline__ u32 bperm(int addr, u32 src) {
    return (u32)__builtin_amdgcn_ds_bpermute(addr, (int)src);
}

#define GLOAD16(g, l) __builtin_amdgcn_global_load_lds( \
    (const __attribute__((address_space(1))) void*)(g), \
    (__attribute__((address_space(3))) void*)(l), 16, 0, 0)

// ---------------- fp32 -> bf16 elementwise (n8 = count/8) ----------------
__global__ __launch_bounds__(256) void cvt_bf16(const float* __restrict__ x, u16* __restrict__ y, int n8) {
    int i = blockIdx.x * blockDim.x + threadIdx.x;
    if (i >= n8) return;
    const float* s = x + (long)i * 8;
    f32x4 a = *(const f32x4*)s;
    f32x4 b = *(const f32x4*)(s + 4);
    u16x8 o;
#pragma unroll
    for (int j = 0; j < 4; ++j) { o[j] = f2bf(a[j]); o[4 + j] = f2bf(b[j]); }
    *(u16x8*)&y[(long)i * 8] = o;
}

// ---------------- W[K][N] fp32 -> Wt[n_off+n][K] bf16 (tiled transpose) ----------------
__global__ __launch_bounds__(256) void trans_w(const float* __restrict__ W, u16* __restrict__ Wt,
                                               int N_w, int K, int n_off) {
    __shared__ __align__(16) u16 T[64][72];
    const int t = threadIdx.x;
    const int n0 = blockIdx.x * 64, k0 = blockIdx.y * 64;
    {
        int r = t >> 2, c4 = (t & 3) * 16;
        const float* src = W + (long)(k0 + r) * N_w + n0 + c4;
        f32x4 a0 = *(const f32x4*)src, a1 = *(const f32x4*)(src + 4);
        f32x4 a2 = *(const f32x4*)(src + 8), a3 = *(const f32x4*)(src + 12);
        u16x8 p0, p1;
#pragma unroll
        for (int j = 0; j < 4; ++j) {
            p0[j] = f2bf(a0[j]); p0[4 + j] = f2bf(a1[j]);
            p1[j] = f2bf(a2[j]); p1[4 + j] = f2bf(a3[j]);
        }
        *(u16x8*)&T[r][c4] = p0;
        *(u16x8*)&T[r][c4 + 8] = p1;
    }
    __syncthreads();
    {
        int n = t >> 2, k4 = (t & 3) * 16;
        u16x8 q0, q1;
#pragma unroll
        for (int j = 0; j < 8; ++j) { q0[j] = T[k4 + j][n]; q1[j] = T[k4 + 8 + j][n]; }
        u16* dst = Wt + (long)(n_off + n0 + n) * K + k0 + k4;
        *(u16x8*)dst = q0;
        *(u16x8*)(dst + 8) = q1;
    }
}

// ---------------- copy past -> present + bf16 K cache + bf16 V^T cache ----------------
__global__ __launch_bounds__(256) void copy_past2(const float* __restrict__ past,
        float* __restrict__ present, u16* __restrict__ Kc, u16* __restrict__ Vtc,
        const int* __restrict__ startp, const int* __restrict__ ctxp) {
    __shared__ __align__(16) u16 T[128][72];
    const int bkh = blockIdx.y;            // (b*2+kv)*4+h
    const int b = bkh >> 3, kv = (bkh >> 2) & 1, h = bkh & 3;
    const int p0 = blockIdx.x * 64;
    const int t = threadIdx.x;
    const int p = t >> 2, d0 = (t & 3) * 32;
    const float* src = past + ((long)bkh * MAXP_ + p0 + p) * 128 + d0;
    float* dst = present + ((long)bkh * MAXP_ + p0 + p) * 128 + d0;
    f32x4 v[8];
#pragma unroll
    for (int j = 0; j < 8; ++j) { v[j] = *(const f32x4*)(src + j * 4); *(f32x4*)(dst + j * 4) = v[j]; }
    // bf16 caches only needed for keys < min(start+512, ctx[b])
    int klim = startp[0] + 512;
    int cx = ctxp[b];
    if (klim > cx) klim = cx;
    if (p0 >= klim) return;
    if (kv == 0) {
        u16* kd = Kc + ((long)(b * 4 + h) * MAXP_ + p0 + p) * 128 + d0;
#pragma unroll
        for (int j2 = 0; j2 < 4; ++j2) {
            u16x8 o;
#pragma unroll
            for (int e = 0; e < 4; ++e) { o[e] = f2bf(v[j2 * 2][e]); o[4 + e] = f2bf(v[j2 * 2 + 1][e]); }
            *(u16x8*)&kd[j2 * 8] = o;
        }
    } else {
#pragma unroll
        for (int j = 0; j < 8; ++j)
#pragma unroll
            for (int e = 0; e < 4; ++e)
                T[d0 + j * 4 + e][p] = f2bf(v[j][e]);
        __syncthreads();
        int d = t >> 1, pc = (t & 1) * 32;
        u16* vd = Vtc + ((long)(b * 4 + h) * 128 + d) * MAXP_ + p0 + pc;
#pragma unroll
        for (int j = 0; j < 4; ++j)
            *(u16x8*)&vd[j * 8] = *(const u16x8*)&T[d][pc + j * 8];
    }
}

// ---------------- bf16 GEMM, A[M][K] @ Bt[N][K]^T -> C[M][N] f32 ----------------
__global__ __launch_bounds__(256) void gemm64(const u16* __restrict__ A, const u16* __restrict__ Bt,
                                              float* __restrict__ C, int M, int N, int K) {
    __shared__ __align__(16) u16 As0[4096], Bs0[4096], As1[4096], Bs1[4096];
    const int tid = threadIdx.x, lane = tid & 63, w = tid >> 6;
    const int wm = w >> 1, wn = w & 1;
    const int l15 = lane & 15, g = lane >> 4;
    const int m0 = blockIdx.y * 64, n0 = blockIdx.x * 64;
    f32x4 acc[2][2] = {};

    const int lrow = lane >> 3;
    const int sch = (lane & 7) ^ lrow;
    const int c0 = w, c1 = w + 4;
    const u16* ga0 = A + (long)(m0 + c0 * 8 + lrow) * K + sch * 8;
    const u16* ga1 = A + (long)(m0 + c1 * 8 + lrow) * K + sch * 8;
    const u16* gb0 = Bt + (long)(n0 + c0 * 8 + lrow) * K + sch * 8;
    const u16* gb1 = Bt + (long)(n0 + c1 * 8 + lrow) * K + sch * 8;
    const int ra = wm * 32, rb = wn * 32;
    const int h7 = l15 & 7;

#define STAGE_T(koff, AS_, BS_) do { \
        GLOAD16(ga0 + (koff), &AS_[c0 * 512]); \
        GLOAD16(ga1 + (koff), &AS_[c1 * 512]); \
        GLOAD16(gb0 + (koff), &BS_[c0 * 512]); \
        GLOAD16(gb1 + (koff), &BS_[c1 * 512]); \
    } while (0)

    auto compute = [&](const u16* as_, const u16* bs_) {
        bf16x8 af[2][2], bfr[2][2];
#pragma unroll
        for (int i = 0; i < 2; ++i) {
            int rr = ra + i * 16 + l15;
#pragma unroll
            for (int kk = 0; kk < 2; ++kk)
                af[i][kk] = *(const bf16x8*)&as_[rr * 64 + (((kk * 4 + g) ^ h7) * 8)];
        }
#pragma unroll
        for (int j = 0; j < 2; ++j) {
            int rr = rb + j * 16 + l15;
#pragma unroll
            for (int kk = 0; kk < 2; ++kk)
                bfr[j][kk] = *(const bf16x8*)&bs_[rr * 64 + (((kk * 4 + g) ^ h7) * 8)];
        }
#pragma unroll
        for (int i = 0; i < 2; ++i)
#pragma unroll
            for (int j = 0; j < 2; ++j) {
                acc[i][j] = __builtin_amdgcn_mfma_f32_16x16x32_bf16(af[i][0], bfr[j][0], acc[i][j], 0, 0, 0);
                acc[i][j] = __builtin_amdgcn_mfma_f32_16x16x32_bf16(af[i][1], bfr[j][1], acc[i][j], 0, 0, 0);
            }
    };

    STAGE_T(0, As0, Bs0);
    for (int k0 = 0; k0 < K; k0 += 128) {
        STAGE_T(k0 + 64, As1, Bs1);
        asm volatile("s_waitcnt vmcnt(4)" ::: "memory");
        __builtin_amdgcn_s_barrier();
        __builtin_amdgcn_sched_barrier(0);
        compute(As0, Bs0);
        __builtin_amdgcn_s_barrier();
        if (k0 + 128 < K) {
            STAGE_T(k0 + 128, As0, Bs0);
            asm volatile("s_waitcnt vmcnt(4)" ::: "memory");
        } else {
            asm volatile("s_waitcnt vmcnt(0)" ::: "memory");
        }
        __builtin_amdgcn_s_barrier();
        __builtin_amdgcn_sched_barrier(0);
        compute(As1, Bs1);
        __builtin_amdgcn_s_barrier();
    }
#undef STAGE_T

#pragma unroll
    for (int i = 0; i < 2; ++i)
#pragma unroll
        for (int j = 0; j < 2; ++j)
#pragma unroll
            for (int r = 0; r < 4; ++r)
                C[(long)(m0 + ra + i * 16 + g * 4 + r) * N + n0 + rb + j * 16 + l15] = acc[i][j][r];
}

// ---------------- RMS norm + RoPE + cache scatter (QKV fused layout, stride 3072) ----------------
__global__ __launch_bounds__(256) void normrope(const float* __restrict__ QKVf,
        const float* __restrict__ rope,
        const float* __restrict__ qw, const float* __restrict__ kw,
        const int* __restrict__ startp, float* __restrict__ present,
        u16* __restrict__ Qn, u16* __restrict__ Kc) {
    const int wid = blockIdx.x * 4 + (threadIdx.x >> 6);
    const int lane = threadIdx.x & 63;
    const int start = startp[0];
    if (wid < 16384) { // Q: 1024 rows x 16 heads
        int row = wid >> 4, h = wid & 15;
        int b = row >> 9, s = row & 511;
        const float* src = QKVf + (long)row * 3072 + h * 128;
        float x1 = src[lane], x2 = src[64 + lane];
        float v = x1 * x1 + x2 * x2;
#pragma unroll
        for (int off = 32; off; off >>= 1) v += __shfl_xor(v, off, 64);
        float sc = rsqrtf(v * (1.0f / 128.0f) + 1e-6f);
        float y1 = x1 * sc * qw[lane], y2 = x2 * sc * qw[64 + lane];
        float c = rope[(long)row * 128 + lane], sn = rope[(long)row * 128 + 64 + lane];
        u16* dst = Qn + (((long)(b * 16 + h) * 512 + s) * 128);
        dst[lane] = f2bf(y1 * c - y2 * sn);
        dst[64 + lane] = f2bf(y2 * c + y1 * sn);
    } else if (wid < 20480) { // K: 1024 rows x 4 heads
        int j = wid - 16384;
        int row = j >> 2, h = j & 3;
        int b = row >> 9, s = row & 511;
        const float* src = QKVf + (long)row * 3072 + 2048 + h * 128;
        float x1 = src[lane], x2 = src[64 + lane];
        float v = x1 * x1 + x2 * x2;
#pragma unroll
        for (int off = 32; off; off >>= 1) v += __shfl_xor(v, off, 64);
        float sc = rsqrtf(v * (1.0f / 128.0f) + 1e-6f);
        float y1 = x1 * sc * kw[lane], y2 = x2 * sc * kw[64 + lane];
        float c = rope[(long)row * 128 + lane], sn = rope[(long)row * 128 + 64 + lane];
        float k1 = y1 * c - y2 * sn, k2 = y2 * c + y1 * sn;
        float* dst = present + (((long)(b * 2 + 0) * 4 + h) * MAXP_ + (start + s)) * 128;
        dst[lane] = k1; dst[64 + lane] = k2;
        u16* kc = Kc + (((long)(b * 4 + h)) * MAXP_ + start + s) * 128;
        kc[lane] = f2bf(k1); kc[64 + lane] = f2bf(k2);
    } else if (wid < 24576) { // V: 1024 rows x 4 heads (present copy only)
        int j = wid - 20480;
        int row = j >> 2, h = j & 3;
        int b = row >> 9, s = row & 511;
        const float* src = QKVf + (long)row * 3072 + 2560 + h * 128;
        float* dst = present + (((long)(b * 2 + 1) * 4 + h) * MAXP_ + (start + s)) * 128;
        dst[lane] = src[lane];
        dst[64 + lane] = src[64 + lane];
    }
}

// ---------------- new-V transpose into Vtc (bf16 [d][p]) ----------------
__global__ __launch_bounds__(256) void vtrans_new(const float* __restrict__ QKVf,
        const int* __restrict__ startp, u16* __restrict__ Vtc) {
    __shared__ __align__(16) u16 T[128][72];
    const int t = threadIdx.x;
    const int s0 = blockIdx.x * 64;
    const int bh = blockIdx.y, b = bh >> 2, h = bh & 3;
    const int sr = t >> 2, d0 = (t & 3) * 32;
    const float* src = QKVf + (long)(b * 512 + s0 + sr) * 3072 + 2560 + h * 128 + d0;
#pragma unroll
    for (int j = 0; j < 8; ++j) {
        f32x4 v = *(const f32x4*)(src + j * 4);
#pragma unroll
        for (int e = 0; e < 4; ++e) T[d0 + j * 4 + e][sr] = f2bf(v[e]);
    }
    __syncthreads();
    const int start = startp[0];
    const int d = t >> 1, pc = (t & 1) * 32;
    u16* dst = Vtc + ((long)(b * 4 + h) * 128 + d) * MAXP_ + start + s0 + pc;
#pragma unroll
    for (int k = 0; k < 32; ++k) dst[k] = T[d][pc + k];  // scalar: start may be unaligned
}

// ---------------- flash attention: key-split-in-block, XCD-pinned, 4 waves/SIMD ----------------
// 1024 blocks: id -> bh=id&7 (XCD-pinned), c=(id>>3)&3, hp=(id>>5)&1, qt=id>>6.
// 4 waves: head hd=w&1 (hq = hkv*4+hp*2+hd), key-half=w>>1 (256 keys each of the 512-key chunk).
// Wave pairs merge (m,l,o) through LDS after the loop -> combine() sees one partial per chunk.
// Zero staging; swapped QK^T; in-register P via RNE pack + ds_bpermute; defer-max (T13); setprio (T5).
__global__ __launch_bounds__(256, 4) void attn(const u16* __restrict__ Qn,
        const u16* __restrict__ Kc, const u16* __restrict__ Vtc,
        const int* __restrict__ startp, const int* __restrict__ ctxp,
        u16* __restrict__ op, float* __restrict__ mp, float* __restrict__ lp) {
    __shared__ __align__(16) f32x4 Ol[2][2][8][64];   // [head][qf][df][lane]  32 KB
    __shared__ float Ml[2][2][64], Ll[2][2][64];      // stats from half-1 waves
    const int tid = threadIdx.x, lane = tid & 63, w = tid >> 6;
    const int l15 = lane & 15, g = lane >> 4;
    const bool ghi = (g >= 2);
    const int id = blockIdx.x;
    const int bh = id & 7;                  // b*4 + hkv, pinned to XCD id%8
    const int c = (id >> 3) & 3;            // chunk
    const int hp = (id >> 5) & 1;           // head pair
    const int q0 = (id >> 6) * 32;          // q-tile origin (16 tiles)
    const int b = bh >> 2, hkv = bh & 3;
    const int hd = w & 1, half = w >> 1;
    const int hq = hkv * 4 + hp * 2 + hd;
    const int start = startp[0];
    const int ctx = ctxp[b];

    int lim_blk = start + q0 + 32;
    if (lim_blk > ctx) lim_blk = ctx;
    const int pbeg = c * CHUNKP;
    int pend = pbeg + CHUNKP;
    if (pend > lim_blk) pend = lim_blk;
    if (pbeg >= pend) return;               // block-uniform

    // this wave's key half
    const int pbeg_h = pbeg + half * 256;
    int pend_h = pbeg + (half + 1) * 256;
    if (pend_h > pend) pend_h = pend;

    const long rowbase = (long)(b * 16 + hq) * 512 + q0;

    bf16x8 qb[2][4];
#pragma unroll
    for (int qf = 0; qf < 2; ++qf) {
        const u16* qp = Qn + (rowbase + qf * 16 + l15) * 128 + g * 8;
#pragma unroll
        for (int kf = 0; kf < 4; ++kf)
            qb[qf][kf] = *(const bf16x8*)(qp + kf * 32);
    }

    const u16* kbase = Kc + (long)bh * (MAXP_ * 128);
    const u16* vbase = Vtc + (long)bh * (128 * MAXP_) + (long)l15 * MAXP_;

    f32x4 o[2][8] = {};
    float m_run[2] = {-1e30f, -1e30f};
    float l_run[2] = {0.f, 0.f};
    int limq[2];
#pragma unroll
    for (int qf = 0; qf < 2; ++qf) {
        int lq = start + q0 + qf * 16 + l15 + 1;
        if (lq > ctx) lq = ctx;
        if (lq > pend_h) lq = pend_h;
        limq[qf] = lq;
    }
    const int addrA = (l15 + ((g & 1) << 5)) << 2;
    const int addrB = addrA + 64;
    const float scale = 0.08838834764831845f;

    if (pbeg_h < pend_h) {
        const int t0 = pbeg_h >> 6, t1 = (pend_h + 63) >> 6;
        for (int t = t0; t < t1; ++t) {
            const int p0 = t * 64;
            // QK^T swapped: sacc[kt][qf] = C[key=p0+kt*16+g*4+r][q=q0+qf*16+l15]
            f32x4 sacc[4][2] = {};
            __builtin_amdgcn_s_setprio(1);
#pragma unroll
            for (int kt = 0; kt < 4; ++kt) {
                const u16* ksrc = kbase + (long)(p0 + kt * 16 + l15) * 128 + g * 8;
#pragma unroll
                for (int kf = 0; kf < 4; ++kf) {
                    bf16x8 ka = *(const bf16x8*)(ksrc + kf * 32);
                    sacc[kt][0] = __builtin_amdgcn_mfma_f32_16x16x32_bf16(ka, qb[0][kf], sacc[kt][0], 0, 0, 0);
                    sacc[kt][1] = __builtin_amdgcn_mfma_f32_16x16x32_bf16(ka, qb[1][kf], sacc[kt][1], 0, 0, 0);
                }
            }
            __builtin_amdgcn_s_setprio(0);
            // mask + online softmax with defer-max; stats per q=l15 (replicated over g)
            u32 w0[4][2], w1[4][2];
#pragma unroll
            for (int qf = 0; qf < 2; ++qf) {
                float mx = -1e30f;
#pragma unroll
                for (int kt = 0; kt < 4; ++kt)
#pragma unroll
                    for (int r = 0; r < 4; ++r) {
                        int key = p0 + kt * 16 + g * 4 + r;
                        float x = (key < limq[qf]) ? sacc[kt][qf][r] * scale : -1e30f;
                        sacc[kt][qf][r] = x;
                        mx = fmaxf(mx, x);
                    }
                mx = fmaxf(mx, __shfl_xor(mx, 16, 64));
                mx = fmaxf(mx, __shfl_xor(mx, 32, 64));
                if (!__all(mx <= m_run[qf] + 8.f)) {
                    float mnew = fmaxf(m_run[qf], mx);
                    float alpha = __expf(m_run[qf] - mnew);
                    m_run[qf] = mnew;
                    l_run[qf] *= alpha;
                    f32x4 av;
#pragma unroll
                    for (int r = 0; r < 4; ++r) av[r] = __shfl(alpha, g * 4 + r, 64);
#pragma unroll
                    for (int df = 0; df < 8; ++df) {
                        o[qf][df][0] *= av[0]; o[qf][df][1] *= av[1];
                        o[qf][df][2] *= av[2]; o[qf][df][3] *= av[3];
                    }
                }
                const float mb = m_run[qf];
                float rs = 0.f;
#pragma unroll
                for (int kt = 0; kt < 4; ++kt) {
#pragma unroll
                    for (int r = 0; r < 4; ++r) {
                        float p = __expf(sacc[kt][qf][r] - mb);
                        sacc[kt][qf][r] = p;
                        rs += p;
                    }
                    w0[kt][qf] = packbf(sacc[kt][qf][0], sacc[kt][qf][1]);
                    w1[kt][qf] = packbf(sacc[kt][qf][2], sacc[kt][qf][3]);
                }
                rs += __shfl_xor(rs, 16, 64);
                rs += __shfl_xor(rs, 32, 64);
                l_run[qf] += rs;
            }
            // PV in two K=32 steps; P A-frag rebuilt via bpermute
#pragma unroll
            for (int ks = 0; ks < 2; ++ks) {
                bf16x8 pa[2];
#pragma unroll
                for (int qf = 0; qf < 2; ++qf) {
                    const int sL = 2 * ks, sH = 2 * ks + 1;
                    u32 d0 = ghi ? bperm(addrA, w0[sH][qf]) : bperm(addrA, w0[sL][qf]);
                    u32 d1 = ghi ? bperm(addrA, w1[sH][qf]) : bperm(addrA, w1[sL][qf]);
                    u32 d2 = ghi ? bperm(addrB, w0[sH][qf]) : bperm(addrB, w0[sL][qf]);
                    u32 d3 = ghi ? bperm(addrB, w1[sH][qf]) : bperm(addrB, w1[sL][qf]);
                    union { u32 d[4]; bf16x8 v; } pu;
                    pu.d[0] = d0; pu.d[1] = d1; pu.d[2] = d2; pu.d[3] = d3;
                    pa[qf] = pu.v;
                }
                const u16* vsrc = vbase + p0 + ks * 32 + g * 8;
                __builtin_amdgcn_s_setprio(1);
#pragma unroll
                for (int df = 0; df < 8; ++df) {
                    bf16x8 vb = *(const bf16x8*)(vsrc + (long)df * 16 * MAXP_);
                    o[0][df] = __builtin_amdgcn_mfma_f32_16x16x32_bf16(pa[0], vb, o[0][df], 0, 0, 0);
                    o[1][df] = __builtin_amdgcn_mfma_f32_16x16x32_bf16(pa[1], vb, o[1][df], 0, 0, 0);
                }
                __builtin_amdgcn_s_setprio(0);
            }
        }
    }

    // ---- merge key-halves through LDS: half-1 publishes, half-0 combines ----
    if (half == 1) {
#pragma unroll
        for (int qf = 0; qf < 2; ++qf) {
            Ml[hd][qf][lane] = m_run[qf];
            Ll[hd][qf][lane] = l_run[qf];
#pragma unroll
            for (int df = 0; df < 8; ++df)
                Ol[hd][qf][df][lane] = o[qf][df];
        }
    }
    __syncthreads();
    if (half == 1) return;
#pragma unroll
    for (int qf = 0; qf < 2; ++qf) {
        float mb_ = Ml[hd][qf][lane], lb_ = Ll[hd][qf][lane];
        float ma_ = m_run[qf], la_ = l_run[qf];
        float M = fmaxf(ma_, mb_);
        float wa = (la_ > 0.f) ? __expf(ma_ - M) : 0.f;
        float wb = (lb_ > 0.f) ? __expf(mb_ - M) : 0.f;
        m_run[qf] = M;
        l_run[qf] = la_ * wa + lb_ * wb;
        f32x4 wav, wbv;
#pragma unroll
        for (int r = 0; r < 4; ++r) {
            wav[r] = __shfl(wa, g * 4 + r, 64);
            wbv[r] = __shfl(wb, g * 4 + r, 64);
        }
#pragma unroll
        for (int df = 0; df < 8; ++df) {
            f32x4 ob = Ol[hd][qf][df][lane];
#pragma unroll
            for (int r = 0; r < 4; ++r)
                o[qf][df][r] = o[qf][df][r] * wav[r] + ob[r] * wbv[r];
        }
    }

    // epilogue: normalized bf16 partial + (m,l)
#pragma unroll
    for (int qf = 0; qf < 2; ++qf) {
        float invl = l_run[qf] > 0.f ? 1.0f / l_run[qf] : 0.f;
        f32x4 iv;
#pragma unroll
        for (int r = 0; r < 4; ++r) iv[r] = __shfl(invl, g * 4 + r, 64);
        u16* dst = op + ((long)c * TOTROWS + rowbase + qf * 16 + g * 4) * 128 + l15;
#pragma unroll
        for (int r = 0; r < 4; ++r)
#pragma unroll
            for (int df = 0; df < 8; ++df)
                dst[(long)r * 128 + df * 16] = f2bf(o[qf][df][r] * iv[r]);
        if (g == 0) {
            mp[(long)c * TOTROWS + rowbase + qf * 16 + l15] = m_run[qf];
            lp[(long)c * TOTROWS + rowbase + qf * 16 + l15] = l_run[qf];
        }
    }
}

// ---------------- combine split-KV partials -> Af bf16 [b*512+s][2048] ----------------
__global__ __launch_bounds__(256) void combine(const u16* __restrict__ op,
        const float* __restrict__ mp, const float* __restrict__ lp,
        const int* __restrict__ startp, const int* __restrict__ ctxp,
        u16* __restrict__ Af) {
    const int w = threadIdx.x >> 6, lane = threadIdx.x & 63;
    const long row = (long)blockIdx.x * 4 + w;
    const int b = (int)(row >> 13), hq = ((int)row >> 9) & 15, s = (int)row & 511;
    const int start = startp[0];
    int lim = start + s + 1;
    int cx = ctxp[b];
    if (lim > cx) lim = cx;
    float mc[NCALLOC], lc[NCALLOC];
    bool has[NCALLOC];
    float M = -1e30f;
#pragma unroll
    for (int c = 0; c < NCALLOC; ++c) {
        has[c] = (c * CHUNKP < lim);
        if (has[c]) {
            mc[c] = mp[(long)c * TOTROWS + row];
            lc[c] = lp[(long)c * TOTROWS + row];
            if (lc[c] > 0.f && mc[c] > M) M = mc[c];
        }
    }
    const int d0 = lane * 2;
    float Wt = 0.f, a0 = 0.f, a1 = 0.f;
#pragma unroll
    for (int c = 0; c < NCALLOC; ++c) {
        if (has[c] && lc[c] > 0.f) {
            float wg = lc[c] * __expf(mc[c] - M);
            Wt += wg;
            u32 pr = *(const u32*)&op[((long)c * TOTROWS + row) * 128 + d0];
            a0 += wg * bf2f((u16)(pr & 0xFFFF));
            a1 += wg * bf2f((u16)(pr >> 16));
        }
    }
    float inv = 1.0f / Wt;
    u32 pk = (u32)f2bf(a0 * inv) | ((u32)f2bf(a1 * inv) << 16);
    *(u32*)&Af[((long)(b * 512 + s) * 2048) + hq * 128 + d0] = pk;
}

extern "C" void kernel_launch(void* const* d_in, const int* in_sizes, int n_in,
                              void* d_out, int out_size, void* d_ws, size_t ws_size,
                              hipStream_t stream) {
    const float* hidden = (const float*)d_in[0];
    const float* past   = (const float*)d_in[1];
    const float* rope   = (const float*)d_in[2];
    const float* Wq     = (const float*)d_in[3];
    const float* Wk     = (const float*)d_in[4];
    const float* Wv     = (const float*)d_in[5];
    const float* Wo     = (const float*)d_in[6];
    const float* qw     = (const float*)d_in[7];
    const float* kw     = (const float*)d_in[8];
    const int*   ctx    = (const int*)d_in[9];
    const int*   start  = (const int*)d_in[10];

    float* out = (float*)d_out;
    float* present = out + 2097152;
    u16* Kc = (u16*)d_out;   // parked in attn-output region of d_out

    char* wsb = (char*)d_ws;
    u16*   hb    = (u16*)(wsb + 0);
    u16*   Wqkvt = (u16*)(wsb + 4194304);
    float* QKVf  = (float*)(wsb + 16777216);
    u16*   op    = (u16*)(wsb + 0);
    float* mp    = (float*)(wsb + 16777216);
    float* lp    = (float*)(wsb + 17039360);
    u16*   Wot   = (u16*)(wsb + 17301504);
    u16*   Qn    = (u16*)(wsb + 29360128);
    u16*   Af    = (u16*)(wsb + 29360128);
    u16*   Vtc   = (u16*)(wsb + 33554432);

    cvt_bf16<<<dim3(1024), dim3(256), 0, stream>>>(hidden, hb, 262144);                     // 1
    trans_w<<<dim3(32, 32), dim3(256), 0, stream>>>(Wq, Wqkvt, 2048, 2048, 0);              // 2
    trans_w<<<dim3(8, 32),  dim3(256), 0, stream>>>(Wk, Wqkvt, 512, 2048, 2048);            // 3
    trans_w<<<dim3(8, 32),  dim3(256), 0, stream>>>(Wv, Wqkvt, 512, 2048, 2560);            // 4
    copy_past2<<<dim3(64, 16), dim3(256), 0, stream>>>(past, present, Kc, Vtc, start, ctx); // 5
    gemm64<<<dim3(48, 16), dim3(256), 0, stream>>>(hb, Wqkvt, QKVf, 1024, 3072, 2048);      // 6
    normrope<<<dim3(6144), dim3(256), 0, stream>>>(QKVf, rope, qw, kw, start, present, Qn, Kc); // 7
    vtrans_new<<<dim3(8, 8), dim3(256), 0, stream>>>(QKVf, start, Vtc);                     // 8
    trans_w<<<dim3(32, 32), dim3(256), 0, stream>>>(Wo, Wot, 2048, 2048, 0);                // 9
    attn<<<dim3(1024), dim3(256), 0, stream>>>(Qn, Kc, Vtc, start, ctx, op, mp, lp);        // 10
    combine<<<dim3(4096), dim3(256), 0, stream>>>(op, mp, lp, start, ctx, Af);              // 11
    gemm64<<<dim3(32, 16), dim3(256), 0, stream>>>(Af, Wot, out, 1024, 2048, 2048);         // 12
}

// Round 11
// 179.495 us; speedup vs baseline: 1.2997x; 1.2997x over previous
//
#include <hip/hip_runtime.h>

typedef unsigned short u16;
typedef unsigned int u32;
typedef __attribute__((ext_vector_type(4))) float f32x4;
typedef __attribute__((ext_vector_type(8))) __bf16 bf16x8;
typedef __attribute__((ext_vector_type(8))) unsigned short u16x8;

#define MAXP_ 4096
#define TOTROWS 16384   // B*HQ*S = 2*16*512
#define NCHUNK 4
#define NCALLOC 4
#define CHUNKP 512

__device__ __forceinline__ u16 f2bf(float f) {
    union { float f; u32 u; } x; x.f = f;
    u32 r = x.u + 0x7FFFu + ((x.u >> 16) & 1u);
    return (u16)(r >> 16);
}
__device__ __forceinline__ float bf2f(u16 u) {
    union { u32 u; float f; } x; x.u = ((u32)u) << 16; return x.f;
}
// RNE bf16 pair pack
__device__ __forceinline__ u32 packbf(float lo, float hi) {
    return (u32)f2bf(lo) | ((u32)f2bf(hi) << 16);
}
__device__ __forceinline__ u32 bperm(int addr, u32 src) {
    return (u32)__builtin_amdgcn_ds_bpermute(addr, (int)src);
}

#define GLOAD16(g, l) __builtin_amdgcn_global_load_lds( \
    (const __attribute__((address_space(1))) void*)(g), \
    (__attribute__((address_space(3))) void*)(l), 16, 0, 0)

// ---------------- fp32 -> bf16 elementwise (n8 = count/8) ----------------
__global__ __launch_bounds__(256) void cvt_bf16(const float* __restrict__ x, u16* __restrict__ y, int n8) {
    int i = blockIdx.x * blockDim.x + threadIdx.x;
    if (i >= n8) return;
    const float* s = x + (long)i * 8;
    f32x4 a = *(const f32x4*)s;
    f32x4 b = *(const f32x4*)(s + 4);
    u16x8 o;
#pragma unroll
    for (int j = 0; j < 4; ++j) { o[j] = f2bf(a[j]); o[4 + j] = f2bf(b[j]); }
    *(u16x8*)&y[(long)i * 8] = o;
}

// ---------------- W[K][N] fp32 -> Wt[n_off+n][K] bf16 (tiled transpose) ----------------
__global__ __launch_bounds__(256) void trans_w(const float* __restrict__ W, u16* __restrict__ Wt,
                                               int N_w, int K, int n_off) {
    __shared__ __align__(16) u16 T[64][72];
    const int t = threadIdx.x;
    const int n0 = blockIdx.x * 64, k0 = blockIdx.y * 64;
    {
        int r = t >> 2, c4 = (t & 3) * 16;
        const float* src = W + (long)(k0 + r) * N_w + n0 + c4;
        f32x4 a0 = *(const f32x4*)src, a1 = *(const f32x4*)(src + 4);
        f32x4 a2 = *(const f32x4*)(src + 8), a3 = *(const f32x4*)(src + 12);
        u16x8 p0, p1;
#pragma unroll
        for (int j = 0; j < 4; ++j) {
            p0[j] = f2bf(a0[j]); p0[4 + j] = f2bf(a1[j]);
            p1[j] = f2bf(a2[j]); p1[4 + j] = f2bf(a3[j]);
        }
        *(u16x8*)&T[r][c4] = p0;
        *(u16x8*)&T[r][c4 + 8] = p1;
    }
    __syncthreads();
    {
        int n = t >> 2, k4 = (t & 3) * 16;
        u16x8 q0, q1;
#pragma unroll
        for (int j = 0; j < 8; ++j) { q0[j] = T[k4 + j][n]; q1[j] = T[k4 + 8 + j][n]; }
        u16* dst = Wt + (long)(n_off + n0 + n) * K + k0 + k4;
        *(u16x8*)dst = q0;
        *(u16x8*)(dst + 8) = q1;
    }
}

// ---------------- copy past -> present + bf16 K cache + bf16 V^T cache ----------------
__global__ __launch_bounds__(256) void copy_past2(const float* __restrict__ past,
        float* __restrict__ present, u16* __restrict__ Kc, u16* __restrict__ Vtc,
        const int* __restrict__ startp, const int* __restrict__ ctxp) {
    __shared__ __align__(16) u16 T[128][72];
    const int bkh = blockIdx.y;            // (b*2+kv)*4+h
    const int b = bkh >> 3, kv = (bkh >> 2) & 1, h = bkh & 3;
    const int p0 = blockIdx.x * 64;
    const int t = threadIdx.x;
    const int p = t >> 2, d0 = (t & 3) * 32;
    const float* src = past + ((long)bkh * MAXP_ + p0 + p) * 128 + d0;
    float* dst = present + ((long)bkh * MAXP_ + p0 + p) * 128 + d0;
    f32x4 v[8];
#pragma unroll
    for (int j = 0; j < 8; ++j) { v[j] = *(const f32x4*)(src + j * 4); *(f32x4*)(dst + j * 4) = v[j]; }
    // bf16 caches only needed for keys < min(start+512, ctx[b])
    int klim = startp[0] + 512;
    int cx = ctxp[b];
    if (klim > cx) klim = cx;
    if (p0 >= klim) return;
    if (kv == 0) {
        u16* kd = Kc + ((long)(b * 4 + h) * MAXP_ + p0 + p) * 128 + d0;
#pragma unroll
        for (int j2 = 0; j2 < 4; ++j2) {
            u16x8 o;
#pragma unroll
            for (int e = 0; e < 4; ++e) { o[e] = f2bf(v[j2 * 2][e]); o[4 + e] = f2bf(v[j2 * 2 + 1][e]); }
            *(u16x8*)&kd[j2 * 8] = o;
        }
    } else {
#pragma unroll
        for (int j = 0; j < 8; ++j)
#pragma unroll
            for (int e = 0; e < 4; ++e)
                T[d0 + j * 4 + e][p] = f2bf(v[j][e]);
        __syncthreads();
        int d = t >> 1, pc = (t & 1) * 32;
        u16* vd = Vtc + ((long)(b * 4 + h) * 128 + d) * MAXP_ + p0 + pc;
#pragma unroll
        for (int j = 0; j < 4; ++j)
            *(u16x8*)&vd[j * 8] = *(const u16x8*)&T[d][pc + j * 8];
    }
}

// ---------------- bf16 GEMM, A[M][K] @ Bt[N][K]^T -> C[M][N] f32 ----------------
// 128x128 tile, 512 threads (8 waves 2x4), BK=64, dbuf gload_lds + counted vmcnt.
// Requires M,N % 128 == 0, K % 128 == 0.
__global__ __launch_bounds__(512) void gemm128(const u16* __restrict__ A, const u16* __restrict__ Bt,
                                               float* __restrict__ C, int M, int N, int K) {
    __shared__ __align__(16) u16 As0[8192], Bs0[8192], As1[8192], Bs1[8192];
    const int tid = threadIdx.x, lane = tid & 63, w = tid >> 6;
    const int wm = w >> 2, wn = w & 3;            // 2 x 4 wave grid
    const int l15 = lane & 15, g = lane >> 4;
    const int m0 = blockIdx.y * 128, n0 = blockIdx.x * 128;
    f32x4 acc[4][2] = {};

    // staging: 16 chunks of 1KB per tile (8 rows x 64 k each); wave w issues chunks w and w+8.
    // lane: row = c*8 + (l>>3); 16B piece (l&7)^(row&7) (source pre-swizzle, read-side XOR)
    const int lrow = lane >> 3;
    const int sch = (lane & 7) ^ lrow;
    const int c0 = w, c1 = w + 8;
    const u16* ga0 = A + (long)(m0 + c0 * 8 + lrow) * K + sch * 8;
    const u16* ga1 = A + (long)(m0 + c1 * 8 + lrow) * K + sch * 8;
    const u16* gb0 = Bt + (long)(n0 + c0 * 8 + lrow) * K + sch * 8;
    const u16* gb1 = Bt + (long)(n0 + c1 * 8 + lrow) * K + sch * 8;
    const int ra = wm * 64, rb = wn * 32;
    const int h7 = l15 & 7;

#define STAGE_T(koff, AS_, BS_) do { \
        GLOAD16(ga0 + (koff), &AS_[c0 * 512]); \
        GLOAD16(ga1 + (koff), &AS_[c1 * 512]); \
        GLOAD16(gb0 + (koff), &BS_[c0 * 512]); \
        GLOAD16(gb1 + (koff), &BS_[c1 * 512]); \
    } while (0)

    auto compute = [&](const u16* as_, const u16* bs_) {
        bf16x8 af[4][2], bfr[2][2];
#pragma unroll
        for (int i = 0; i < 4; ++i) {
            int rr = ra + i * 16 + l15;
#pragma unroll
            for (int kk = 0; kk < 2; ++kk)
                af[i][kk] = *(const bf16x8*)&as_[rr * 64 + (((kk * 4 + g) ^ h7) * 8)];
        }
#pragma unroll
        for (int j = 0; j < 2; ++j) {
            int rr = rb + j * 16 + l15;
#pragma unroll
            for (int kk = 0; kk < 2; ++kk)
                bfr[j][kk] = *(const bf16x8*)&bs_[rr * 64 + (((kk * 4 + g) ^ h7) * 8)];
        }
#pragma unroll
        for (int i = 0; i < 4; ++i)
#pragma unroll
            for (int j = 0; j < 2; ++j) {
                acc[i][j] = __builtin_amdgcn_mfma_f32_16x16x32_bf16(af[i][0], bfr[j][0], acc[i][j], 0, 0, 0);
                acc[i][j] = __builtin_amdgcn_mfma_f32_16x16x32_bf16(af[i][1], bfr[j][1], acc[i][j], 0, 0, 0);
            }
    };

    STAGE_T(0, As0, Bs0);
    for (int k0 = 0; k0 < K; k0 += 128) {
        STAGE_T(k0 + 64, As1, Bs1);
        asm volatile("s_waitcnt vmcnt(4)" ::: "memory");
        __builtin_amdgcn_s_barrier();
        __builtin_amdgcn_sched_barrier(0);
        compute(As0, Bs0);
        __builtin_amdgcn_s_barrier();
        if (k0 + 128 < K) {
            STAGE_T(k0 + 128, As0, Bs0);
            asm volatile("s_waitcnt vmcnt(4)" ::: "memory");
        } else {
            asm volatile("s_waitcnt vmcnt(0)" ::: "memory");
        }
        __builtin_amdgcn_s_barrier();
        __builtin_amdgcn_sched_barrier(0);
        compute(As1, Bs1);
        __builtin_amdgcn_s_barrier();
    }
#undef STAGE_T

#pragma unroll
    for (int i = 0; i < 4; ++i)
#pragma unroll
        for (int j = 0; j < 2; ++j)
#pragma unroll
            for (int r = 0; r < 4; ++r)
                C[(long)(m0 + ra + i * 16 + g * 4 + r) * N + n0 + rb + j * 16 + l15] = acc[i][j][r];
}

// ---------------- RMS norm + RoPE + cache scatter (QKV fused layout, stride 3072) ----------------
__global__ __launch_bounds__(256) void normrope(const float* __restrict__ QKVf,
        const float* __restrict__ rope,
        const float* __restrict__ qw, const float* __restrict__ kw,
        const int* __restrict__ startp, float* __restrict__ present,
        u16* __restrict__ Qn, u16* __restrict__ Kc) {
    const int wid = blockIdx.x * 4 + (threadIdx.x >> 6);
    const int lane = threadIdx.x & 63;
    const int start = startp[0];
    if (wid < 16384) { // Q: 1024 rows x 16 heads
        int row = wid >> 4, h = wid & 15;
        int b = row >> 9, s = row & 511;
        const float* src = QKVf + (long)row * 3072 + h * 128;
        float x1 = src[lane], x2 = src[64 + lane];
        float v = x1 * x1 + x2 * x2;
#pragma unroll
        for (int off = 32; off; off >>= 1) v += __shfl_xor(v, off, 64);
        float sc = rsqrtf(v * (1.0f / 128.0f) + 1e-6f);
        float y1 = x1 * sc * qw[lane], y2 = x2 * sc * qw[64 + lane];
        float c = rope[(long)row * 128 + lane], sn = rope[(long)row * 128 + 64 + lane];
        u16* dst = Qn + (((long)(b * 16 + h) * 512 + s) * 128);
        dst[lane] = f2bf(y1 * c - y2 * sn);
        dst[64 + lane] = f2bf(y2 * c + y1 * sn);
    } else if (wid < 20480) { // K: 1024 rows x 4 heads
        int j = wid - 16384;
        int row = j >> 2, h = j & 3;
        int b = row >> 9, s = row & 511;
        const float* src = QKVf + (long)row * 3072 + 2048 + h * 128;
        float x1 = src[lane], x2 = src[64 + lane];
        float v = x1 * x1 + x2 * x2;
#pragma unroll
        for (int off = 32; off; off >>= 1) v += __shfl_xor(v, off, 64);
        float sc = rsqrtf(v * (1.0f / 128.0f) + 1e-6f);
        float y1 = x1 * sc * kw[lane], y2 = x2 * sc * kw[64 + lane];
        float c = rope[(long)row * 128 + lane], sn = rope[(long)row * 128 + 64 + lane];
        float k1 = y1 * c - y2 * sn, k2 = y2 * c + y1 * sn;
        float* dst = present + (((long)(b * 2 + 0) * 4 + h) * MAXP_ + (start + s)) * 128;
        dst[lane] = k1; dst[64 + lane] = k2;
        u16* kc = Kc + (((long)(b * 4 + h)) * MAXP_ + start + s) * 128;
        kc[lane] = f2bf(k1); kc[64 + lane] = f2bf(k2);
    } else if (wid < 24576) { // V: 1024 rows x 4 heads (present copy only)
        int j = wid - 20480;
        int row = j >> 2, h = j & 3;
        int b = row >> 9, s = row & 511;
        const float* src = QKVf + (long)row * 3072 + 2560 + h * 128;
        float* dst = present + (((long)(b * 2 + 1) * 4 + h) * MAXP_ + (start + s)) * 128;
        dst[lane] = src[lane];
        dst[64 + lane] = src[64 + lane];
    }
}

// ---------------- new-V transpose into Vtc (bf16 [d][p]) ----------------
__global__ __launch_bounds__(256) void vtrans_new(const float* __restrict__ QKVf,
        const int* __restrict__ startp, u16* __restrict__ Vtc) {
    __shared__ __align__(16) u16 T[128][72];
    const int t = threadIdx.x;
    const int s0 = blockIdx.x * 64;
    const int bh = blockIdx.y, b = bh >> 2, h = bh & 3;
    const int sr = t >> 2, d0 = (t & 3) * 32;
    const float* src = QKVf + (long)(b * 512 + s0 + sr) * 3072 + 2560 + h * 128 + d0;
#pragma unroll
    for (int j = 0; j < 8; ++j) {
        f32x4 v = *(const f32x4*)(src + j * 4);
#pragma unroll
        for (int e = 0; e < 4; ++e) T[d0 + j * 4 + e][sr] = f2bf(v[e]);
    }
    __syncthreads();
    const int start = startp[0];
    const int d = t >> 1, pc = (t & 1) * 32;
    u16* dst = Vtc + ((long)(b * 4 + h) * 128 + d) * MAXP_ + start + s0 + pc;
#pragma unroll
    for (int k = 0; k < 32; ++k) dst[k] = T[d][pc + k];  // scalar: start may be unaligned
}

// ---------------- flash attention: zero-LDS, GQA-fused, XCD-pinned, V-hoist (T14) ----------------
// 512 hw blocks, 1D. bh = id&7 (XCD-pinned), c = (id>>3)>>4, q0 = ((id>>3)&15)*32.
// 4 waves = 4 q-heads; 32 q-rows/wave. Swapped QK^T; in-register P via RNE pack + ds_bpermute.
// V loads for the CURRENT tile are hoisted to right after QK^T issue so their latency hides
// under the softmax VALU chain (T14 issue-early). No barriers, no LDS.
__global__ __launch_bounds__(256, 2) void attn(const u16* __restrict__ Qn,
        const u16* __restrict__ Kc, const u16* __restrict__ Vtc,
        const int* __restrict__ startp, const int* __restrict__ ctxp,
        u16* __restrict__ op, float* __restrict__ mp, float* __restrict__ lp) {
    const int tid = threadIdx.x, lane = tid & 63, w = tid >> 6;
    const int l15 = lane & 15, g = lane >> 4;
    const bool ghi = (g >= 2);
    const int id = blockIdx.x;
    const int bh = id & 7;                  // b*4 + hkv, pinned to XCD id%8
    const int rest = id >> 3;
    const int c = rest >> 4;                // chunk 0..3
    const int q0 = (rest & 15) * 32;        // q-tile origin
    const int b = bh >> 2, hkv = bh & 3;
    const int hq = hkv * 4 + w;
    const int start = startp[0];
    const int ctx = ctxp[b];

    int lim_blk = start + q0 + 32;
    if (lim_blk > ctx) lim_blk = ctx;
    const int pbeg = c * CHUNKP;
    int pend = pbeg + CHUNKP;
    if (pend > lim_blk) pend = lim_blk;
    if (pbeg >= pend) return;               // block-uniform

    const long rowbase = (long)(b * 16 + hq) * 512 + q0;

    // Q B-frags: B[k=d][n=q], n=l15 -> q row, k=g*8+j (+kf*32) -> d
    bf16x8 qb[2][4];
#pragma unroll
    for (int qf = 0; qf < 2; ++qf) {
        const u16* qp = Qn + (rowbase + qf * 16 + l15) * 128 + g * 8;
#pragma unroll
        for (int kf = 0; kf < 4; ++kf)
            qb[qf][kf] = *(const bf16x8*)(qp + kf * 32);
    }

    const u16* kbase = Kc + (long)bh * (MAXP_ * 128);
    const u16* vbase = Vtc + (long)bh * (128 * MAXP_) + (long)l15 * MAXP_;

    f32x4 o[2][8] = {};
    float m_run[2] = {-1e30f, -1e30f};
    float l_run[2] = {0.f, 0.f};
    int limq[2];
#pragma unroll
    for (int qf = 0; qf < 2; ++qf) {
        int lq = start + q0 + qf * 16 + l15 + 1;
        if (lq > ctx) lq = ctx;
        if (lq > pend) lq = pend;
        limq[qf] = lq;
    }
    const int addrA = (l15 + ((g & 1) << 5)) << 2;  // source lane l15 + 32*(g&1)
    const int addrB = addrA + 64;                   // +16 lanes
    const float scale = 0.08838834764831845f;

    const int t0 = pbeg >> 6, t1 = (pend + 63) >> 6;
    for (int t = t0; t < t1; ++t) {
        const int p0 = t * 64;
        // QK^T swapped: sacc[kt][qf] = C[key=p0+kt*16+g*4+r][q=q0+qf*16+l15]
        f32x4 sacc[4][2] = {};
#pragma unroll
        for (int kt = 0; kt < 4; ++kt) {
            const u16* ksrc = kbase + (long)(p0 + kt * 16 + l15) * 128 + g * 8;
#pragma unroll
            for (int kf = 0; kf < 4; ++kf) {
                bf16x8 ka = *(const bf16x8*)(ksrc + kf * 32);
                sacc[kt][0] = __builtin_amdgcn_mfma_f32_16x16x32_bf16(ka, qb[0][kf], sacc[kt][0], 0, 0, 0);
                sacc[kt][1] = __builtin_amdgcn_mfma_f32_16x16x32_bf16(ka, qb[1][kf], sacc[kt][1], 0, 0, 0);
            }
        }
        // V-hoist (T14): issue all 16 V loads NOW — latency hides under the softmax chain
        bf16x8 vr[2][8];
#pragma unroll
        for (int ks = 0; ks < 2; ++ks) {
            const u16* vsrc = vbase + p0 + ks * 32 + g * 8;
#pragma unroll
            for (int df = 0; df < 8; ++df)
                vr[ks][df] = *(const bf16x8*)(vsrc + (long)df * 16 * MAXP_);
        }
        // mask + online softmax; stats per q=l15 (replicated over g)
        u32 w0[4][2], w1[4][2];
#pragma unroll
        for (int qf = 0; qf < 2; ++qf) {
            float mx = -1e30f;
#pragma unroll
            for (int kt = 0; kt < 4; ++kt)
#pragma unroll
                for (int r = 0; r < 4; ++r) {
                    int key = p0 + kt * 16 + g * 4 + r;
                    float x = (key < limq[qf]) ? sacc[kt][qf][r] * scale : -1e30f;
                    sacc[kt][qf][r] = x;
                    mx = fmaxf(mx, x);
                }
            mx = fmaxf(mx, __shfl_xor(mx, 16, 64));
            mx = fmaxf(mx, __shfl_xor(mx, 32, 64));
            float mnew = fmaxf(m_run[qf], mx);
            float alpha = __expf(m_run[qf] - mnew);
            m_run[qf] = mnew;
            float rs = 0.f;
#pragma unroll
            for (int kt = 0; kt < 4; ++kt) {
#pragma unroll
                for (int r = 0; r < 4; ++r) {
                    float p = __expf(sacc[kt][qf][r] - mnew);
                    sacc[kt][qf][r] = p;
                    rs += p;
                }
                w0[kt][qf] = packbf(sacc[kt][qf][0], sacc[kt][qf][1]);
                w1[kt][qf] = packbf(sacc[kt][qf][2], sacc[kt][qf][3]);
            }
            rs += __shfl_xor(rs, 16, 64);
            rs += __shfl_xor(rs, 32, 64);
            l_run[qf] = l_run[qf] * alpha + rs;
            f32x4 av;
#pragma unroll
            for (int r = 0; r < 4; ++r) av[r] = __shfl(alpha, g * 4 + r, 64);
#pragma unroll
            for (int df = 0; df < 8; ++df) {
                o[qf][df][0] *= av[0]; o[qf][df][1] *= av[1];
                o[qf][df][2] *= av[2]; o[qf][df][3] *= av[3];
            }
        }
        // PV in two K=32 steps; P A-frag rebuilt via bpermute; V already in registers
#pragma unroll
        for (int ks = 0; ks < 2; ++ks) {
            bf16x8 pa[2];
#pragma unroll
            for (int qf = 0; qf < 2; ++qf) {
                const int sL = 2 * ks, sH = 2 * ks + 1;
                u32 d0 = ghi ? bperm(addrA, w0[sH][qf]) : bperm(addrA, w0[sL][qf]);
                u32 d1 = ghi ? bperm(addrA, w1[sH][qf]) : bperm(addrA, w1[sL][qf]);
                u32 d2 = ghi ? bperm(addrB, w0[sH][qf]) : bperm(addrB, w0[sL][qf]);
                u32 d3 = ghi ? bperm(addrB, w1[sH][qf]) : bperm(addrB, w1[sL][qf]);
                union { u32 d[4]; bf16x8 v; } pu;
                pu.d[0] = d0; pu.d[1] = d1; pu.d[2] = d2; pu.d[3] = d3;
                pa[qf] = pu.v;
            }
#pragma unroll
            for (int df = 0; df < 8; ++df) {
                o[0][df] = __builtin_amdgcn_mfma_f32_16x16x32_bf16(pa[0], vr[ks][df], o[0][df], 0, 0, 0);
                o[1][df] = __builtin_amdgcn_mfma_f32_16x16x32_bf16(pa[1], vr[ks][df], o[1][df], 0, 0, 0);
            }
        }
    }
    // epilogue: normalized bf16 partial + (m,l)
#pragma unroll
    for (int qf = 0; qf < 2; ++qf) {
        float invl = l_run[qf] > 0.f ? 1.0f / l_run[qf] : 0.f;
        f32x4 iv;
#pragma unroll
        for (int r = 0; r < 4; ++r) iv[r] = __shfl(invl, g * 4 + r, 64);
        u16* dst = op + ((long)c * TOTROWS + rowbase + qf * 16 + g * 4) * 128 + l15;
#pragma unroll
        for (int r = 0; r < 4; ++r)
#pragma unroll
            for (int df = 0; df < 8; ++df)
                dst[(long)r * 128 + df * 16] = f2bf(o[qf][df][r] * iv[r]);
        if (g == 0) {
            mp[(long)c * TOTROWS + rowbase + qf * 16 + l15] = m_run[qf];
            lp[(long)c * TOTROWS + rowbase + qf * 16 + l15] = l_run[qf];
        }
    }
}

// ---------------- combine split-KV partials -> Af bf16 [b*512+s][2048] ----------------
__global__ __launch_bounds__(256) void combine(const u16* __restrict__ op,
        const float* __restrict__ mp, const float* __restrict__ lp,
        const int* __restrict__ startp, const int* __restrict__ ctxp,
        u16* __restrict__ Af) {
    const int w = threadIdx.x >> 6, lane = threadIdx.x & 63;
    const long row = (long)blockIdx.x * 4 + w;
    const int b = (int)(row >> 13), hq = ((int)row >> 9) & 15, s = (int)row & 511;
    const int start = startp[0];
    int lim = start + s + 1;
    int cx = ctxp[b];
    if (lim > cx) lim = cx;
    float mc[NCALLOC], lc[NCALLOC];
    bool has[NCALLOC];
    float M = -1e30f;
#pragma unroll
    for (int c = 0; c < NCALLOC; ++c) {
        has[c] = (c * CHUNKP < lim);
        if (has[c]) {
            mc[c] = mp[(long)c * TOTROWS + row];
            lc[c] = lp[(long)c * TOTROWS + row];
            if (lc[c] > 0.f && mc[c] > M) M = mc[c];
        }
    }
    const int d0 = lane * 2;
    float Wt = 0.f, a0 = 0.f, a1 = 0.f;
#pragma unroll
    for (int c = 0; c < NCALLOC; ++c) {
        if (has[c] && lc[c] > 0.f) {
            float wg = lc[c] * __expf(mc[c] - M);
            Wt += wg;
            u32 pr = *(const u32*)&op[((long)c * TOTROWS + row) * 128 + d0];
            a0 += wg * bf2f((u16)(pr & 0xFFFF));
            a1 += wg * bf2f((u16)(pr >> 16));
        }
    }
    float inv = 1.0f / Wt;
    u32 pk = (u32)f2bf(a0 * inv) | ((u32)f2bf(a1 * inv) << 16);
    *(u32*)&Af[((long)(b * 512 + s) * 2048) + hq * 128 + d0] = pk;
}

extern "C" void kernel_launch(void* const* d_in, const int* in_sizes, int n_in,
                              void* d_out, int out_size, void* d_ws, size_t ws_size,
                              hipStream_t stream) {
    const float* hidden = (const float*)d_in[0];
    const float* past   = (const float*)d_in[1];
    const float* rope   = (const float*)d_in[2];
    const float* Wq     = (const float*)d_in[3];
    const float* Wk     = (const float*)d_in[4];
    const float* Wv     = (const float*)d_in[5];
    const float* Wo     = (const float*)d_in[6];
    const float* qw     = (const float*)d_in[7];
    const float* kw     = (const float*)d_in[8];
    const int*   ctx    = (const int*)d_in[9];
    const int*   start  = (const int*)d_in[10];

    float* out = (float*)d_out;
    float* present = out + 2097152;
    u16* Kc = (u16*)d_out;   // parked in attn-output region of d_out

    char* wsb = (char*)d_ws;
    u16*   hb    = (u16*)(wsb + 0);
    u16*   Wqkvt = (u16*)(wsb + 4194304);
    float* QKVf  = (float*)(wsb + 16777216);
    u16*   op    = (u16*)(wsb + 0);
    float* mp    = (float*)(wsb + 16777216);
    float* lp    = (float*)(wsb + 17039360);
    u16*   Wot   = (u16*)(wsb + 17301504);
    u16*   Qn    = (u16*)(wsb + 29360128);
    u16*   Af    = (u16*)(wsb + 29360128);
    u16*   Vtc   = (u16*)(wsb + 33554432);

    cvt_bf16<<<dim3(1024), dim3(256), 0, stream>>>(hidden, hb, 262144);                     // 1
    trans_w<<<dim3(32, 32), dim3(256), 0, stream>>>(Wq, Wqkvt, 2048, 2048, 0);              // 2
    trans_w<<<dim3(8, 32),  dim3(256), 0, stream>>>(Wk, Wqkvt, 512, 2048, 2048);            // 3
    trans_w<<<dim3(8, 32),  dim3(256), 0, stream>>>(Wv, Wqkvt, 512, 2048, 2560);            // 4
    copy_past2<<<dim3(64, 16), dim3(256), 0, stream>>>(past, present, Kc, Vtc, start, ctx); // 5
    gemm128<<<dim3(24, 8), dim3(512), 0, stream>>>(hb, Wqkvt, QKVf, 1024, 3072, 2048);      // 6
    normrope<<<dim3(6144), dim3(256), 0, stream>>>(QKVf, rope, qw, kw, start, present, Qn, Kc); // 7
    vtrans_new<<<dim3(8, 8), dim3(256), 0, stream>>>(QKVf, start, Vtc);                     // 8
    trans_w<<<dim3(32, 32), dim3(256), 0, stream>>>(Wo, Wot, 2048, 2048, 0);                // 9
    attn<<<dim3(512), dim3(256), 0, stream>>>(Qn, Kc, Vtc, start, ctx, op, mp, lp);         // 10
    combine<<<dim3(4096), dim3(256), 0, stream>>>(op, mp, lp, start, ctx, Af);              // 11
    gemm128<<<dim3(16, 8), dim3(512), 0, stream>>>(Af, Wot, out, 1024, 2048, 2048);         // 12
}

// Round 12
// 179.368 us; speedup vs baseline: 1.3006x; 1.0007x over previous
//
#include <hip/hip_runtime.h>

typedef unsigned short u16;
typedef unsigned int u32;
typedef __attribute__((ext_vector_type(4))) float f32x4;
typedef __attribute__((ext_vector_type(8))) __bf16 bf16x8;
typedef __attribute__((ext_vector_type(8))) unsigned short u16x8;

#define MAXP_ 4096
#define TOTROWS 16384   // B*HQ*S = 2*16*512
#define NCHUNK 4
#define NCALLOC 4
#define CHUNKP 512

__device__ __forceinline__ u16 f2bf(float f) {
    union { float f; u32 u; } x; x.f = f;
    u32 r = x.u + 0x7FFFu + ((x.u >> 16) & 1u);
    return (u16)(r >> 16);
}
__device__ __forceinline__ float bf2f(u16 u) {
    union { u32 u; float f; } x; x.u = ((u32)u) << 16; return x.f;
}
// RNE bf16 pair pack
__device__ __forceinline__ u32 packbf(float lo, float hi) {
    return (u32)f2bf(lo) | ((u32)f2bf(hi) << 16);
}
__device__ __forceinline__ u32 bperm(int addr, u32 src) {
    return (u32)__builtin_amdgcn_ds_bpermute(addr, (int)src);
}

#define GLOAD16(g, l) __builtin_amdgcn_global_load_lds( \
    (const __attribute__((address_space(1))) void*)(g), \
    (__attribute__((address_space(3))) void*)(l), 16, 0, 0)

// ---------------- fp32 -> bf16 elementwise (n8 = count/8) ----------------
__global__ __launch_bounds__(256) void cvt_bf16(const float* __restrict__ x, u16* __restrict__ y, int n8) {
    int i = blockIdx.x * blockDim.x + threadIdx.x;
    if (i >= n8) return;
    const float* s = x + (long)i * 8;
    f32x4 a = *(const f32x4*)s;
    f32x4 b = *(const f32x4*)(s + 4);
    u16x8 o;
#pragma unroll
    for (int j = 0; j < 4; ++j) { o[j] = f2bf(a[j]); o[4 + j] = f2bf(b[j]); }
    *(u16x8*)&y[(long)i * 8] = o;
}

// ---------------- W[K][N] fp32 -> Wt[n_off+n][K] bf16 (tiled transpose) ----------------
__global__ __launch_bounds__(256) void trans_w(const float* __restrict__ W, u16* __restrict__ Wt,
                                               int N_w, int K, int n_off) {
    __shared__ __align__(16) u16 T[64][72];
    const int t = threadIdx.x;
    const int n0 = blockIdx.x * 64, k0 = blockIdx.y * 64;
    {
        int r = t >> 2, c4 = (t & 3) * 16;
        const float* src = W + (long)(k0 + r) * N_w + n0 + c4;
        f32x4 a0 = *(const f32x4*)src, a1 = *(const f32x4*)(src + 4);
        f32x4 a2 = *(const f32x4*)(src + 8), a3 = *(const f32x4*)(src + 12);
        u16x8 p0, p1;
#pragma unroll
        for (int j = 0; j < 4; ++j) {
            p0[j] = f2bf(a0[j]); p0[4 + j] = f2bf(a1[j]);
            p1[j] = f2bf(a2[j]); p1[4 + j] = f2bf(a3[j]);
        }
        *(u16x8*)&T[r][c4] = p0;
        *(u16x8*)&T[r][c4 + 8] = p1;
    }
    __syncthreads();
    {
        int n = t >> 2, k4 = (t & 3) * 16;
        u16x8 q0, q1;
#pragma unroll
        for (int j = 0; j < 8; ++j) { q0[j] = T[k4 + j][n]; q1[j] = T[k4 + 8 + j][n]; }
        u16* dst = Wt + (long)(n_off + n0 + n) * K + k0 + k4;
        *(u16x8*)dst = q0;
        *(u16x8*)(dst + 8) = q1;
    }
}

// ---------------- copy past -> present + bf16 K cache + bf16 V^T cache ----------------
__global__ __launch_bounds__(256) void copy_past2(const float* __restrict__ past,
        float* __restrict__ present, u16* __restrict__ Kc, u16* __restrict__ Vtc,
        const int* __restrict__ startp, const int* __restrict__ ctxp) {
    __shared__ __align__(16) u16 T[128][72];
    const int bkh = blockIdx.y;            // (b*2+kv)*4+h
    const int b = bkh >> 3, kv = (bkh >> 2) & 1, h = bkh & 3;
    const int p0 = blockIdx.x * 64;
    const int t = threadIdx.x;
    const int p = t >> 2, d0 = (t & 3) * 32;
    const float* src = past + ((long)bkh * MAXP_ + p0 + p) * 128 + d0;
    float* dst = present + ((long)bkh * MAXP_ + p0 + p) * 128 + d0;
    f32x4 v[8];
#pragma unroll
    for (int j = 0; j < 8; ++j) { v[j] = *(const f32x4*)(src + j * 4); *(f32x4*)(dst + j * 4) = v[j]; }
    // bf16 caches only needed for keys < min(start+512, ctx[b])
    int klim = startp[0] + 512;
    int cx = ctxp[b];
    if (klim > cx) klim = cx;
    if (p0 >= klim) return;
    if (kv == 0) {
        u16* kd = Kc + ((long)(b * 4 + h) * MAXP_ + p0 + p) * 128 + d0;
#pragma unroll
        for (int j2 = 0; j2 < 4; ++j2) {
            u16x8 o;
#pragma unroll
            for (int e = 0; e < 4; ++e) { o[e] = f2bf(v[j2 * 2][e]); o[4 + e] = f2bf(v[j2 * 2 + 1][e]); }
            *(u16x8*)&kd[j2 * 8] = o;
        }
    } else {
#pragma unroll
        for (int j = 0; j < 8; ++j)
#pragma unroll
            for (int e = 0; e < 4; ++e)
                T[d0 + j * 4 + e][p] = f2bf(v[j][e]);
        __syncthreads();
        int d = t >> 1, pc = (t & 1) * 32;
        u16* vd = Vtc + ((long)(b * 4 + h) * 128 + d) * MAXP_ + p0 + pc;
#pragma unroll
        for (int j = 0; j < 4; ++j)
            *(u16x8*)&vd[j * 8] = *(const u16x8*)&T[d][pc + j * 8];
    }
}

// ---------------- bf16 GEMM, A[M][K] @ Bt[N][K]^T -> C[M][N] f32 ----------------
// 64x64 tile, BK=64, double-buffered gload_lds with counted vmcnt (T3/T4). Requires K % 128 == 0.
__global__ __launch_bounds__(256) void gemm64(const u16* __restrict__ A, const u16* __restrict__ Bt,
                                              float* __restrict__ C, int M, int N, int K) {
    __shared__ __align__(16) u16 As0[4096], Bs0[4096], As1[4096], Bs1[4096];
    const int tid = threadIdx.x, lane = tid & 63, w = tid >> 6;
    const int wm = w >> 1, wn = w & 1;
    const int l15 = lane & 15, g = lane >> 4;
    const int m0 = blockIdx.y * 64, n0 = blockIdx.x * 64;
    f32x4 acc[2][2] = {};

    const int lrow = lane >> 3;
    const int sch = (lane & 7) ^ lrow;
    const int c0 = w, c1 = w + 4;
    const u16* ga0 = A + (long)(m0 + c0 * 8 + lrow) * K + sch * 8;
    const u16* ga1 = A + (long)(m0 + c1 * 8 + lrow) * K + sch * 8;
    const u16* gb0 = Bt + (long)(n0 + c0 * 8 + lrow) * K + sch * 8;
    const u16* gb1 = Bt + (long)(n0 + c1 * 8 + lrow) * K + sch * 8;
    const int ra = wm * 32, rb = wn * 32;
    const int h7 = l15 & 7;

#define STAGE_T(koff, AS_, BS_) do { \
        GLOAD16(ga0 + (koff), &AS_[c0 * 512]); \
        GLOAD16(ga1 + (koff), &AS_[c1 * 512]); \
        GLOAD16(gb0 + (koff), &BS_[c0 * 512]); \
        GLOAD16(gb1 + (koff), &BS_[c1 * 512]); \
    } while (0)

    auto compute = [&](const u16* as_, const u16* bs_) {
        bf16x8 af[2][2], bfr[2][2];
#pragma unroll
        for (int i = 0; i < 2; ++i) {
            int rr = ra + i * 16 + l15;
#pragma unroll
            for (int kk = 0; kk < 2; ++kk)
                af[i][kk] = *(const bf16x8*)&as_[rr * 64 + (((kk * 4 + g) ^ h7) * 8)];
        }
#pragma unroll
        for (int j = 0; j < 2; ++j) {
            int rr = rb + j * 16 + l15;
#pragma unroll
            for (int kk = 0; kk < 2; ++kk)
                bfr[j][kk] = *(const bf16x8*)&bs_[rr * 64 + (((kk * 4 + g) ^ h7) * 8)];
        }
#pragma unroll
        for (int i = 0; i < 2; ++i)
#pragma unroll
            for (int j = 0; j < 2; ++j) {
                acc[i][j] = __builtin_amdgcn_mfma_f32_16x16x32_bf16(af[i][0], bfr[j][0], acc[i][j], 0, 0, 0);
                acc[i][j] = __builtin_amdgcn_mfma_f32_16x16x32_bf16(af[i][1], bfr[j][1], acc[i][j], 0, 0, 0);
            }
    };

    STAGE_T(0, As0, Bs0);
    for (int k0 = 0; k0 < K; k0 += 128) {
        STAGE_T(k0 + 64, As1, Bs1);
        asm volatile("s_waitcnt vmcnt(4)" ::: "memory");
        __builtin_amdgcn_s_barrier();
        __builtin_amdgcn_sched_barrier(0);
        compute(As0, Bs0);
        __builtin_amdgcn_s_barrier();
        if (k0 + 128 < K) {
            STAGE_T(k0 + 128, As0, Bs0);
            asm volatile("s_waitcnt vmcnt(4)" ::: "memory");
        } else {
            asm volatile("s_waitcnt vmcnt(0)" ::: "memory");
        }
        __builtin_amdgcn_s_barrier();
        __builtin_amdgcn_sched_barrier(0);
        compute(As1, Bs1);
        __builtin_amdgcn_s_barrier();
    }
#undef STAGE_T

#pragma unroll
    for (int i = 0; i < 2; ++i)
#pragma unroll
        for (int j = 0; j < 2; ++j)
#pragma unroll
            for (int r = 0; r < 4; ++r)
                C[(long)(m0 + ra + i * 16 + g * 4 + r) * N + n0 + rb + j * 16 + l15] = acc[i][j][r];
}

// ---------------- RMS norm + RoPE + cache scatter (QKV fused layout, stride 3072) ----------------
__global__ __launch_bounds__(256) void normrope(const float* __restrict__ QKVf,
        const float* __restrict__ rope,
        const float* __restrict__ qw, const float* __restrict__ kw,
        const int* __restrict__ startp, float* __restrict__ present,
        u16* __restrict__ Qn, u16* __restrict__ Kc) {
    const int wid = blockIdx.x * 4 + (threadIdx.x >> 6);
    const int lane = threadIdx.x & 63;
    const int start = startp[0];
    if (wid < 16384) { // Q: 1024 rows x 16 heads
        int row = wid >> 4, h = wid & 15;
        int b = row >> 9, s = row & 511;
        const float* src = QKVf + (long)row * 3072 + h * 128;
        float x1 = src[lane], x2 = src[64 + lane];
        float v = x1 * x1 + x2 * x2;
#pragma unroll
        for (int off = 32; off; off >>= 1) v += __shfl_xor(v, off, 64);
        float sc = rsqrtf(v * (1.0f / 128.0f) + 1e-6f);
        float y1 = x1 * sc * qw[lane], y2 = x2 * sc * qw[64 + lane];
        float c = rope[(long)row * 128 + lane], sn = rope[(long)row * 128 + 64 + lane];
        u16* dst = Qn + (((long)(b * 16 + h) * 512 + s) * 128);
        dst[lane] = f2bf(y1 * c - y2 * sn);
        dst[64 + lane] = f2bf(y2 * c + y1 * sn);
    } else if (wid < 20480) { // K: 1024 rows x 4 heads
        int j = wid - 16384;
        int row = j >> 2, h = j & 3;
        int b = row >> 9, s = row & 511;
        const float* src = QKVf + (long)row * 3072 + 2048 + h * 128;
        float x1 = src[lane], x2 = src[64 + lane];
        float v = x1 * x1 + x2 * x2;
#pragma unroll
        for (int off = 32; off; off >>= 1) v += __shfl_xor(v, off, 64);
        float sc = rsqrtf(v * (1.0f / 128.0f) + 1e-6f);
        float y1 = x1 * sc * kw[lane], y2 = x2 * sc * kw[64 + lane];
        float c = rope[(long)row * 128 + lane], sn = rope[(long)row * 128 + 64 + lane];
        float k1 = y1 * c - y2 * sn, k2 = y2 * c + y1 * sn;
        float* dst = present + (((long)(b * 2 + 0) * 4 + h) * MAXP_ + (start + s)) * 128;
        dst[lane] = k1; dst[64 + lane] = k2;
        u16* kc = Kc + (((long)(b * 4 + h)) * MAXP_ + start + s) * 128;
        kc[lane] = f2bf(k1); kc[64 + lane] = f2bf(k2);
    } else if (wid < 24576) { // V: 1024 rows x 4 heads (present copy only)
        int j = wid - 20480;
        int row = j >> 2, h = j & 3;
        int b = row >> 9, s = row & 511;
        const float* src = QKVf + (long)row * 3072 + 2560 + h * 128;
        float* dst = present + (((long)(b * 2 + 1) * 4 + h) * MAXP_ + (start + s)) * 128;
        dst[lane] = src[lane];
        dst[64 + lane] = src[64 + lane];
    }
}

// ---------------- new-V transpose into Vtc (bf16 [d][p]) ----------------
__global__ __launch_bounds__(256) void vtrans_new(const float* __restrict__ QKVf,
        const int* __restrict__ startp, u16* __restrict__ Vtc) {
    __shared__ __align__(16) u16 T[128][72];
    const int t = threadIdx.x;
    const int s0 = blockIdx.x * 64;
    const int bh = blockIdx.y, b = bh >> 2, h = bh & 3;
    const int sr = t >> 2, d0 = (t & 3) * 32;
    const float* src = QKVf + (long)(b * 512 + s0 + sr) * 3072 + 2560 + h * 128 + d0;
#pragma unroll
    for (int j = 0; j < 8; ++j) {
        f32x4 v = *(const f32x4*)(src + j * 4);
#pragma unroll
        for (int e = 0; e < 4; ++e) T[d0 + j * 4 + e][sr] = f2bf(v[e]);
    }
    __syncthreads();
    const int start = startp[0];
    const int d = t >> 1, pc = (t & 1) * 32;
    u16* dst = Vtc + ((long)(b * 4 + h) * 128 + d) * MAXP_ + start + s0 + pc;
#pragma unroll
    for (int k = 0; k < 32; ++k) dst[k] = T[d][pc + k];  // scalar: start may be unaligned
}

// ---------------- flash attention: key-split-in-block, XCD-pinned ----------------
// 1024 blocks: id -> bh=id&7 (XCD-pinned), c=(id>>3)&3, hp=(id>>5)&1, qt=id>>6.
// 4 waves: head hd=w&1 (hq = hkv*4+hp*2+hd), key-half=w>>1 (256 keys each of the 512-key chunk).
// Wave pairs merge (m,l,o) through LDS after the loop -> combine() sees one partial per chunk.
// launch_bounds(256,2): VGPR cap 128 (R10's (256,4) forced VGPR=64 -> total spill; body needs ~110).
// With ~110 VGPR + 34KB LDS -> 4 blocks/CU = 4 waves/SIMD (grid was the limiter at 512 blocks).
__global__ __launch_bounds__(256, 2) void attn(const u16* __restrict__ Qn,
        const u16* __restrict__ Kc, const u16* __restrict__ Vtc,
        const int* __restrict__ startp, const int* __restrict__ ctxp,
        u16* __restrict__ op, float* __restrict__ mp, float* __restrict__ lp) {
    __shared__ __align__(16) f32x4 Ol[2][2][8][64];   // [head][qf][df][lane]  32 KB
    __shared__ float Ml[2][2][64], Ll[2][2][64];      // stats from half-1 waves
    const int tid = threadIdx.x, lane = tid & 63, w = tid >> 6;
    const int l15 = lane & 15, g = lane >> 4;
    const bool ghi = (g >= 2);
    const int id = blockIdx.x;
    const int bh = id & 7;                  // b*4 + hkv, pinned to XCD id%8
    const int c = (id >> 3) & 3;            // chunk
    const int hp = (id >> 5) & 1;           // head pair
    const int q0 = (id >> 6) * 32;          // q-tile origin (16 tiles)
    const int b = bh >> 2, hkv = bh & 3;
    const int hd = w & 1, half = w >> 1;
    const int hq = hkv * 4 + hp * 2 + hd;
    const int start = startp[0];
    const int ctx = ctxp[b];

    int lim_blk = start + q0 + 32;
    if (lim_blk > ctx) lim_blk = ctx;
    const int pbeg = c * CHUNKP;
    int pend = pbeg + CHUNKP;
    if (pend > lim_blk) pend = lim_blk;
    if (pbeg >= pend) return;               // block-uniform

    // this wave's key half
    const int pbeg_h = pbeg + half * 256;
    int pend_h = pbeg + (half + 1) * 256;
    if (pend_h > pend) pend_h = pend;

    const long rowbase = (long)(b * 16 + hq) * 512 + q0;

    bf16x8 qb[2][4];
#pragma unroll
    for (int qf = 0; qf < 2; ++qf) {
        const u16* qp = Qn + (rowbase + qf * 16 + l15) * 128 + g * 8;
#pragma unroll
        for (int kf = 0; kf < 4; ++kf)
            qb[qf][kf] = *(const bf16x8*)(qp + kf * 32);
    }

    const u16* kbase = Kc + (long)bh * (MAXP_ * 128);
    const u16* vbase = Vtc + (long)bh * (128 * MAXP_) + (long)l15 * MAXP_;

    f32x4 o[2][8] = {};
    float m_run[2] = {-1e30f, -1e30f};
    float l_run[2] = {0.f, 0.f};
    int limq[2];
#pragma unroll
    for (int qf = 0; qf < 2; ++qf) {
        int lq = start + q0 + qf * 16 + l15 + 1;
        if (lq > ctx) lq = ctx;
        if (lq > pend_h) lq = pend_h;
        limq[qf] = lq;
    }
    const int addrA = (l15 + ((g & 1) << 5)) << 2;
    const int addrB = addrA + 64;
    const float scale = 0.08838834764831845f;

    if (pbeg_h < pend_h) {
        const int t0 = pbeg_h >> 6, t1 = (pend_h + 63) >> 6;
        for (int t = t0; t < t1; ++t) {
            const int p0 = t * 64;
            // QK^T swapped: sacc[kt][qf] = C[key=p0+kt*16+g*4+r][q=q0+qf*16+l15]
            f32x4 sacc[4][2] = {};
            __builtin_amdgcn_s_setprio(1);
#pragma unroll
            for (int kt = 0; kt < 4; ++kt) {
                const u16* ksrc = kbase + (long)(p0 + kt * 16 + l15) * 128 + g * 8;
#pragma unroll
                for (int kf = 0; kf < 4; ++kf) {
                    bf16x8 ka = *(const bf16x8*)(ksrc + kf * 32);
                    sacc[kt][0] = __builtin_amdgcn_mfma_f32_16x16x32_bf16(ka, qb[0][kf], sacc[kt][0], 0, 0, 0);
                    sacc[kt][1] = __builtin_amdgcn_mfma_f32_16x16x32_bf16(ka, qb[1][kf], sacc[kt][1], 0, 0, 0);
                }
            }
            __builtin_amdgcn_s_setprio(0);
            // mask + online softmax with defer-max; stats per q=l15 (replicated over g)
            u32 w0[4][2], w1[4][2];
#pragma unroll
            for (int qf = 0; qf < 2; ++qf) {
                float mx = -1e30f;
#pragma unroll
                for (int kt = 0; kt < 4; ++kt)
#pragma unroll
                    for (int r = 0; r < 4; ++r) {
                        int key = p0 + kt * 16 + g * 4 + r;
                        float x = (key < limq[qf]) ? sacc[kt][qf][r] * scale : -1e30f;
                        sacc[kt][qf][r] = x;
                        mx = fmaxf(mx, x);
                    }
                mx = fmaxf(mx, __shfl_xor(mx, 16, 64));
                mx = fmaxf(mx, __shfl_xor(mx, 32, 64));
                if (!__all(mx <= m_run[qf] + 8.f)) {
                    float mnew = fmaxf(m_run[qf], mx);
                    float alpha = __expf(m_run[qf] - mnew);
                    m_run[qf] = mnew;
                    l_run[qf] *= alpha;
                    f32x4 av;
#pragma unroll
                    for (int r = 0; r < 4; ++r) av[r] = __shfl(alpha, g * 4 + r, 64);
#pragma unroll
                    for (int df = 0; df < 8; ++df) {
                        o[qf][df][0] *= av[0]; o[qf][df][1] *= av[1];
                        o[qf][df][2] *= av[2]; o[qf][df][3] *= av[3];
                    }
                }
                const float mb = m_run[qf];
                float rs = 0.f;
#pragma unroll
                for (int kt = 0; kt < 4; ++kt) {
#pragma unroll
                    for (int r = 0; r < 4; ++r) {
                        float p = __expf(sacc[kt][qf][r] - mb);
                        sacc[kt][qf][r] = p;
                        rs += p;
                    }
                    w0[kt][qf] = packbf(sacc[kt][qf][0], sacc[kt][qf][1]);
                    w1[kt][qf] = packbf(sacc[kt][qf][2], sacc[kt][qf][3]);
                }
                rs += __shfl_xor(rs, 16, 64);
                rs += __shfl_xor(rs, 32, 64);
                l_run[qf] += rs;
            }
            // PV in two K=32 steps; P A-frag rebuilt via bpermute
#pragma unroll
            for (int ks = 0; ks < 2; ++ks) {
                bf16x8 pa[2];
#pragma unroll
                for (int qf = 0; qf < 2; ++qf) {
                    const int sL = 2 * ks, sH = 2 * ks + 1;
                    u32 d0 = ghi ? bperm(addrA, w0[sH][qf]) : bperm(addrA, w0[sL][qf]);
                    u32 d1 = ghi ? bperm(addrA, w1[sH][qf]) : bperm(addrA, w1[sL][qf]);
                    u32 d2 = ghi ? bperm(addrB, w0[sH][qf]) : bperm(addrB, w0[sL][qf]);
                    u32 d3 = ghi ? bperm(addrB, w1[sH][qf]) : bperm(addrB, w1[sL][qf]);
                    union { u32 d[4]; bf16x8 v; } pu;
                    pu.d[0] = d0; pu.d[1] = d1; pu.d[2] = d2; pu.d[3] = d3;
                    pa[qf] = pu.v;
                }
                const u16* vsrc = vbase + p0 + ks * 32 + g * 8;
                __builtin_amdgcn_s_setprio(1);
#pragma unroll
                for (int df = 0; df < 8; ++df) {
                    bf16x8 vb = *(const bf16x8*)(vsrc + (long)df * 16 * MAXP_);
                    o[0][df] = __builtin_amdgcn_mfma_f32_16x16x32_bf16(pa[0], vb, o[0][df], 0, 0, 0);
                    o[1][df] = __builtin_amdgcn_mfma_f32_16x16x32_bf16(pa[1], vb, o[1][df], 0, 0, 0);
                }
                __builtin_amdgcn_s_setprio(0);
            }
        }
    }

    // ---- merge key-halves through LDS: half-1 publishes, half-0 combines ----
    if (half == 1) {
#pragma unroll
        for (int qf = 0; qf < 2; ++qf) {
            Ml[hd][qf][lane] = m_run[qf];
            Ll[hd][qf][lane] = l_run[qf];
#pragma unroll
            for (int df = 0; df < 8; ++df)
                Ol[hd][qf][df][lane] = o[qf][df];
        }
    }
    __syncthreads();
    if (half == 1) return;
#pragma unroll
    for (int qf = 0; qf < 2; ++qf) {
        float mb_ = Ml[hd][qf][lane], lb_ = Ll[hd][qf][lane];
        float ma_ = m_run[qf], la_ = l_run[qf];
        float M = fmaxf(ma_, mb_);
        float wa = (la_ > 0.f) ? __expf(ma_ - M) : 0.f;
        float wb = (lb_ > 0.f) ? __expf(mb_ - M) : 0.f;
        m_run[qf] = M;
        l_run[qf] = la_ * wa + lb_ * wb;
        f32x4 wav, wbv;
#pragma unroll
        for (int r = 0; r < 4; ++r) {
            wav[r] = __shfl(wa, g * 4 + r, 64);
            wbv[r] = __shfl(wb, g * 4 + r, 64);
        }
#pragma unroll
        for (int df = 0; df < 8; ++df) {
            f32x4 ob = Ol[hd][qf][df][lane];
#pragma unroll
            for (int r = 0; r < 4; ++r)
                o[qf][df][r] = o[qf][df][r] * wav[r] + ob[r] * wbv[r];
        }
    }

    // epilogue: normalized bf16 partial + (m,l)
#pragma unroll
    for (int qf = 0; qf < 2; ++qf) {
        float invl = l_run[qf] > 0.f ? 1.0f / l_run[qf] : 0.f;
        f32x4 iv;
#pragma unroll
        for (int r = 0; r < 4; ++r) iv[r] = __shfl(invl, g * 4 + r, 64);
        u16* dst = op + ((long)c * TOTROWS + rowbase + qf * 16 + g * 4) * 128 + l15;
#pragma unroll
        for (int r = 0; r < 4; ++r)
#pragma unroll
            for (int df = 0; df < 8; ++df)
                dst[(long)r * 128 + df * 16] = f2bf(o[qf][df][r] * iv[r]);
        if (g == 0) {
            mp[(long)c * TOTROWS + rowbase + qf * 16 + l15] = m_run[qf];
            lp[(long)c * TOTROWS + rowbase + qf * 16 + l15] = l_run[qf];
        }
    }
}

// ---------------- combine split-KV partials -> Af bf16 [b*512+s][2048] ----------------
__global__ __launch_bounds__(256) void combine(const u16* __restrict__ op,
        const float* __restrict__ mp, const float* __restrict__ lp,
        const int* __restrict__ startp, const int* __restrict__ ctxp,
        u16* __restrict__ Af) {
    const int w = threadIdx.x >> 6, lane = threadIdx.x & 63;
    const long row = (long)blockIdx.x * 4 + w;
    const int b = (int)(row >> 13), hq = ((int)row >> 9) & 15, s = (int)row & 511;
    const int start = startp[0];
    int lim = start + s + 1;
    int cx = ctxp[b];
    if (lim > cx) lim = cx;
    float mc[NCALLOC], lc[NCALLOC];
    bool has[NCALLOC];
    float M = -1e30f;
#pragma unroll
    for (int c = 0; c < NCALLOC; ++c) {
        has[c] = (c * CHUNKP < lim);
        if (has[c]) {
            mc[c] = mp[(long)c * TOTROWS + row];
            lc[c] = lp[(long)c * TOTROWS + row];
            if (lc[c] > 0.f && mc[c] > M) M = mc[c];
        }
    }
    const int d0 = lane * 2;
    float Wt = 0.f, a0 = 0.f, a1 = 0.f;
#pragma unroll
    for (int c = 0; c < NCALLOC; ++c) {
        if (has[c] && lc[c] > 0.f) {
            float wg = lc[c] * __expf(mc[c] - M);
            Wt += wg;
            u32 pr = *(const u32*)&op[((long)c * TOTROWS + row) * 128 + d0];
            a0 += wg * bf2f((u16)(pr & 0xFFFF));
            a1 += wg * bf2f((u16)(pr >> 16));
        }
    }
    float inv = 1.0f / Wt;
    u32 pk = (u32)f2bf(a0 * inv) | ((u32)f2bf(a1 * inv) << 16);
    *(u32*)&Af[((long)(b * 512 + s) * 2048) + hq * 128 + d0] = pk;
}

extern "C" void kernel_launch(void* const* d_in, const int* in_sizes, int n_in,
                              void* d_out, int out_size, void* d_ws, size_t ws_size,
                              hipStream_t stream) {
    const float* hidden = (const float*)d_in[0];
    const float* past   = (const float*)d_in[1];
    const float* rope   = (const float*)d_in[2];
    const float* Wq     = (const float*)d_in[3];
    const float* Wk     = (const float*)d_in[4];
    const float* Wv     = (const float*)d_in[5];
    const float* Wo     = (const float*)d_in[6];
    const float* qw     = (const float*)d_in[7];
    const float* kw     = (const float*)d_in[8];
    const int*   ctx    = (const int*)d_in[9];
    const int*   start  = (const int*)d_in[10];

    float* out = (float*)d_out;
    float* present = out + 2097152;
    u16* Kc = (u16*)d_out;   // parked in attn-output region of d_out

    char* wsb = (char*)d_ws;
    u16*   hb    = (u16*)(wsb + 0);
    u16*   Wqkvt = (u16*)(wsb + 4194304);
    float* QKVf  = (float*)(wsb + 16777216);
    u16*   op    = (u16*)(wsb + 0);
    float* mp    = (float*)(wsb + 16777216);
    float* lp    = (float*)(wsb + 17039360);
    u16*   Wot   = (u16*)(wsb + 17301504);
    u16*   Qn    = (u16*)(wsb + 29360128);
    u16*   Af    = (u16*)(wsb + 29360128);
    u16*   Vtc   = (u16*)(wsb + 33554432);

    cvt_bf16<<<dim3(1024), dim3(256), 0, stream>>>(hidden, hb, 262144);                     // 1
    trans_w<<<dim3(32, 32), dim3(256), 0, stream>>>(Wq, Wqkvt, 2048, 2048, 0);              // 2
    trans_w<<<dim3(8, 32),  dim3(256), 0, stream>>>(Wk, Wqkvt, 512, 2048, 2048);            // 3
    trans_w<<<dim3(8, 32),  dim3(256), 0, stream>>>(Wv, Wqkvt, 512, 2048, 2560);            // 4
    copy_past2<<<dim3(64, 16), dim3(256), 0, stream>>>(past, present, Kc, Vtc, start, ctx); // 5
    gemm64<<<dim3(48, 16), dim3(256), 0, stream>>>(hb, Wqkvt, QKVf, 1024, 3072, 2048);      // 6
    normrope<<<dim3(6144), dim3(256), 0, stream>>>(QKVf, rope, qw, kw, start, present, Qn, Kc); // 7
    vtrans_new<<<dim3(8, 8), dim3(256), 0, stream>>>(QKVf, start, Vtc);                     // 8
    trans_w<<<dim3(32, 32), dim3(256), 0, stream>>>(Wo, Wot, 2048, 2048, 0);                // 9
    attn<<<dim3(1024), dim3(256), 0, stream>>>(Qn, Kc, Vtc, start, ctx, op, mp, lp);        // 10
    combine<<<dim3(4096), dim3(256), 0, stream>>>(op, mp, lp, start, ctx, Af);              // 11
    gemm64<<<dim3(32, 16), dim3(256), 0, stream>>>(Af, Wot, out, 1024, 2048, 2048);         // 12
}

// Round 13
// 162.213 us; speedup vs baseline: 1.4381x; 1.1058x over previous
//
#include <hip/hip_runtime.h>

typedef unsigned short u16;
typedef unsigned int u32;
typedef __attribute__((ext_vector_type(4))) float f32x4;
typedef __attribute__((ext_vector_type(8))) __bf16 bf16x8;
typedef __attribute__((ext_vector_type(8))) unsigned short u16x8;

#define MAXP_ 4096
#define TOTROWS 16384   // B*HQ*S = 2*16*512
#define NCHUNK 4
#define NCALLOC 4
#define CHUNKP 512

__device__ __forceinline__ u16 f2bf(float f) {
    union { float f; u32 u; } x; x.f = f;
    u32 r = x.u + 0x7FFFu + ((x.u >> 16) & 1u);
    return (u16)(r >> 16);
}
__device__ __forceinline__ float bf2f(u16 u) {
    union { u32 u; float f; } x; x.u = ((u32)u) << 16; return x.f;
}
// RNE bf16 pair pack
__device__ __forceinline__ u32 packbf(float lo, float hi) {
    return (u32)f2bf(lo) | ((u32)f2bf(hi) << 16);
}
__device__ __forceinline__ u32 bperm(int addr, u32 src) {
    return (u32)__builtin_amdgcn_ds_bpermute(addr, (int)src);
}

#define GLOAD16(g, l) __builtin_amdgcn_global_load_lds( \
    (const __attribute__((address_space(1))) void*)(g), \
    (__attribute__((address_space(3))) void*)(l), 16, 0, 0)

// ---------------- fp32 -> bf16 elementwise (n8 = count/8) ----------------
__global__ __launch_bounds__(256) void cvt_bf16(const float* __restrict__ x, u16* __restrict__ y, int n8) {
    int i = blockIdx.x * blockDim.x + threadIdx.x;
    if (i >= n8) return;
    const float* s = x + (long)i * 8;
    f32x4 a = *(const f32x4*)s;
    f32x4 b = *(const f32x4*)(s + 4);
    u16x8 o;
#pragma unroll
    for (int j = 0; j < 4; ++j) { o[j] = f2bf(a[j]); o[4 + j] = f2bf(b[j]); }
    *(u16x8*)&y[(long)i * 8] = o;
}

// ---------------- W[K][N] fp32 -> Wt[n_off+n][K] bf16 (tiled transpose) ----------------
__global__ __launch_bounds__(256) void trans_w(const float* __restrict__ W, u16* __restrict__ Wt,
                                               int N_w, int K, int n_off) {
    __shared__ __align__(16) u16 T[64][72];
    const int t = threadIdx.x;
    const int n0 = blockIdx.x * 64, k0 = blockIdx.y * 64;
    {
        int r = t >> 2, c4 = (t & 3) * 16;
        const float* src = W + (long)(k0 + r) * N_w + n0 + c4;
        f32x4 a0 = *(const f32x4*)src, a1 = *(const f32x4*)(src + 4);
        f32x4 a2 = *(const f32x4*)(src + 8), a3 = *(const f32x4*)(src + 12);
        u16x8 p0, p1;
#pragma unroll
        for (int j = 0; j < 4; ++j) {
            p0[j] = f2bf(a0[j]); p0[4 + j] = f2bf(a1[j]);
            p1[j] = f2bf(a2[j]); p1[4 + j] = f2bf(a3[j]);
        }
        *(u16x8*)&T[r][c4] = p0;
        *(u16x8*)&T[r][c4 + 8] = p1;
    }
    __syncthreads();
    {
        int n = t >> 2, k4 = (t & 3) * 16;
        u16x8 q0, q1;
#pragma unroll
        for (int j = 0; j < 8; ++j) { q0[j] = T[k4 + j][n]; q1[j] = T[k4 + 8 + j][n]; }
        u16* dst = Wt + (long)(n_off + n0 + n) * K + k0 + k4;
        *(u16x8*)dst = q0;
        *(u16x8*)(dst + 8) = q1;
    }
}

// ---------------- copy past -> present + bf16 K cache + bf16 V^T cache ----------------
__global__ __launch_bounds__(256) void copy_past2(const float* __restrict__ past,
        float* __restrict__ present, u16* __restrict__ Kc, u16* __restrict__ Vtc,
        const int* __restrict__ startp, const int* __restrict__ ctxp) {
    __shared__ __align__(16) u16 T[128][72];
    const int bkh = blockIdx.y;            // (b*2+kv)*4+h
    const int b = bkh >> 3, kv = (bkh >> 2) & 1, h = bkh & 3;
    const int p0 = blockIdx.x * 64;
    const int t = threadIdx.x;
    const int p = t >> 2, d0 = (t & 3) * 32;
    const float* src = past + ((long)bkh * MAXP_ + p0 + p) * 128 + d0;
    float* dst = present + ((long)bkh * MAXP_ + p0 + p) * 128 + d0;
    f32x4 v[8];
#pragma unroll
    for (int j = 0; j < 8; ++j) { v[j] = *(const f32x4*)(src + j * 4); *(f32x4*)(dst + j * 4) = v[j]; }
    // bf16 caches only needed for keys < min(start+512, ctx[b])
    int klim = startp[0] + 512;
    int cx = ctxp[b];
    if (klim > cx) klim = cx;
    if (p0 >= klim) return;
    if (kv == 0) {
        u16* kd = Kc + ((long)(b * 4 + h) * MAXP_ + p0 + p) * 128 + d0;
#pragma unroll
        for (int j2 = 0; j2 < 4; ++j2) {
            u16x8 o;
#pragma unroll
            for (int e = 0; e < 4; ++e) { o[e] = f2bf(v[j2 * 2][e]); o[4 + e] = f2bf(v[j2 * 2 + 1][e]); }
            *(u16x8*)&kd[j2 * 8] = o;
        }
    } else {
#pragma unroll
        for (int j = 0; j < 8; ++j)
#pragma unroll
            for (int e = 0; e < 4; ++e)
                T[d0 + j * 4 + e][p] = f2bf(v[j][e]);
        __syncthreads();
        int d = t >> 1, pc = (t & 1) * 32;
        u16* vd = Vtc + ((long)(b * 4 + h) * 128 + d) * MAXP_ + p0 + pc;
#pragma unroll
        for (int j = 0; j < 4; ++j)
            *(u16x8*)&vd[j * 8] = *(const u16x8*)&T[d][pc + j * 8];
    }
}

// ---------------- bf16 GEMM, A[M][K] @ Bt[N][K]^T -> C[M][N] f32 ----------------
// 64x64 tile, BK=64, double-buffered gload_lds with counted vmcnt (T3/T4). Requires K % 128 == 0.
__global__ __launch_bounds__(256) void gemm64(const u16* __restrict__ A, const u16* __restrict__ Bt,
                                              float* __restrict__ C, int M, int N, int K) {
    __shared__ __align__(16) u16 As0[4096], Bs0[4096], As1[4096], Bs1[4096];
    const int tid = threadIdx.x, lane = tid & 63, w = tid >> 6;
    const int wm = w >> 1, wn = w & 1;
    const int l15 = lane & 15, g = lane >> 4;
    const int m0 = blockIdx.y * 64, n0 = blockIdx.x * 64;
    f32x4 acc[2][2] = {};

    const int lrow = lane >> 3;
    const int sch = (lane & 7) ^ lrow;
    const int c0 = w, c1 = w + 4;
    const u16* ga0 = A + (long)(m0 + c0 * 8 + lrow) * K + sch * 8;
    const u16* ga1 = A + (long)(m0 + c1 * 8 + lrow) * K + sch * 8;
    const u16* gb0 = Bt + (long)(n0 + c0 * 8 + lrow) * K + sch * 8;
    const u16* gb1 = Bt + (long)(n0 + c1 * 8 + lrow) * K + sch * 8;
    const int ra = wm * 32, rb = wn * 32;
    const int h7 = l15 & 7;

#define STAGE_T(koff, AS_, BS_) do { \
        GLOAD16(ga0 + (koff), &AS_[c0 * 512]); \
        GLOAD16(ga1 + (koff), &AS_[c1 * 512]); \
        GLOAD16(gb0 + (koff), &BS_[c0 * 512]); \
        GLOAD16(gb1 + (koff), &BS_[c1 * 512]); \
    } while (0)

    auto compute = [&](const u16* as_, const u16* bs_) {
        bf16x8 af[2][2], bfr[2][2];
#pragma unroll
        for (int i = 0; i < 2; ++i) {
            int rr = ra + i * 16 + l15;
#pragma unroll
            for (int kk = 0; kk < 2; ++kk)
                af[i][kk] = *(const bf16x8*)&as_[rr * 64 + (((kk * 4 + g) ^ h7) * 8)];
        }
#pragma unroll
        for (int j = 0; j < 2; ++j) {
            int rr = rb + j * 16 + l15;
#pragma unroll
            for (int kk = 0; kk < 2; ++kk)
                bfr[j][kk] = *(const bf16x8*)&bs_[rr * 64 + (((kk * 4 + g) ^ h7) * 8)];
        }
#pragma unroll
        for (int i = 0; i < 2; ++i)
#pragma unroll
            for (int j = 0; j < 2; ++j) {
                acc[i][j] = __builtin_amdgcn_mfma_f32_16x16x32_bf16(af[i][0], bfr[j][0], acc[i][j], 0, 0, 0);
                acc[i][j] = __builtin_amdgcn_mfma_f32_16x16x32_bf16(af[i][1], bfr[j][1], acc[i][j], 0, 0, 0);
            }
    };

    STAGE_T(0, As0, Bs0);
    for (int k0 = 0; k0 < K; k0 += 128) {
        STAGE_T(k0 + 64, As1, Bs1);
        asm volatile("s_waitcnt vmcnt(4)" ::: "memory");
        __builtin_amdgcn_s_barrier();
        __builtin_amdgcn_sched_barrier(0);
        compute(As0, Bs0);
        __builtin_amdgcn_s_barrier();
        if (k0 + 128 < K) {
            STAGE_T(k0 + 128, As0, Bs0);
            asm volatile("s_waitcnt vmcnt(4)" ::: "memory");
        } else {
            asm volatile("s_waitcnt vmcnt(0)" ::: "memory");
        }
        __builtin_amdgcn_s_barrier();
        __builtin_amdgcn_sched_barrier(0);
        compute(As1, Bs1);
        __builtin_amdgcn_s_barrier();
    }
#undef STAGE_T

#pragma unroll
    for (int i = 0; i < 2; ++i)
#pragma unroll
        for (int j = 0; j < 2; ++j)
#pragma unroll
            for (int r = 0; r < 4; ++r)
                C[(long)(m0 + ra + i * 16 + g * 4 + r) * N + n0 + rb + j * 16 + l15] = acc[i][j][r];
}

// ---------------- RMS norm + RoPE + cache scatter (QKV fused layout, stride 3072) ----------------
__global__ __launch_bounds__(256) void normrope(const float* __restrict__ QKVf,
        const float* __restrict__ rope,
        const float* __restrict__ qw, const float* __restrict__ kw,
        const int* __restrict__ startp, float* __restrict__ present,
        u16* __restrict__ Qn, u16* __restrict__ Kc) {
    const int wid = blockIdx.x * 4 + (threadIdx.x >> 6);
    const int lane = threadIdx.x & 63;
    const int start = startp[0];
    if (wid < 16384) { // Q: 1024 rows x 16 heads
        int row = wid >> 4, h = wid & 15;
        int b = row >> 9, s = row & 511;
        const float* src = QKVf + (long)row * 3072 + h * 128;
        float x1 = src[lane], x2 = src[64 + lane];
        float v = x1 * x1 + x2 * x2;
#pragma unroll
        for (int off = 32; off; off >>= 1) v += __shfl_xor(v, off, 64);
        float sc = rsqrtf(v * (1.0f / 128.0f) + 1e-6f);
        float y1 = x1 * sc * qw[lane], y2 = x2 * sc * qw[64 + lane];
        float c = rope[(long)row * 128 + lane], sn = rope[(long)row * 128 + 64 + lane];
        u16* dst = Qn + (((long)(b * 16 + h) * 512 + s) * 128);
        dst[lane] = f2bf(y1 * c - y2 * sn);
        dst[64 + lane] = f2bf(y2 * c + y1 * sn);
    } else if (wid < 20480) { // K: 1024 rows x 4 heads
        int j = wid - 16384;
        int row = j >> 2, h = j & 3;
        int b = row >> 9, s = row & 511;
        const float* src = QKVf + (long)row * 3072 + 2048 + h * 128;
        float x1 = src[lane], x2 = src[64 + lane];
        float v = x1 * x1 + x2 * x2;
#pragma unroll
        for (int off = 32; off; off >>= 1) v += __shfl_xor(v, off, 64);
        float sc = rsqrtf(v * (1.0f / 128.0f) + 1e-6f);
        float y1 = x1 * sc * kw[lane], y2 = x2 * sc * kw[64 + lane];
        float c = rope[(long)row * 128 + lane], sn = rope[(long)row * 128 + 64 + lane];
        float k1 = y1 * c - y2 * sn, k2 = y2 * c + y1 * sn;
        float* dst = present + (((long)(b * 2 + 0) * 4 + h) * MAXP_ + (start + s)) * 128;
        dst[lane] = k1; dst[64 + lane] = k2;
        u16* kc = Kc + (((long)(b * 4 + h)) * MAXP_ + start + s) * 128;
        kc[lane] = f2bf(k1); kc[64 + lane] = f2bf(k2);
    } else if (wid < 24576) { // V: 1024 rows x 4 heads (present copy only)
        int j = wid - 20480;
        int row = j >> 2, h = j & 3;
        int b = row >> 9, s = row & 511;
        const float* src = QKVf + (long)row * 3072 + 2560 + h * 128;
        float* dst = present + (((long)(b * 2 + 1) * 4 + h) * MAXP_ + (start + s)) * 128;
        dst[lane] = src[lane];
        dst[64 + lane] = src[64 + lane];
    }
}

// ---------------- new-V transpose into Vtc (bf16 [d][p]) ----------------
__global__ __launch_bounds__(256) void vtrans_new(const float* __restrict__ QKVf,
        const int* __restrict__ startp, u16* __restrict__ Vtc) {
    __shared__ __align__(16) u16 T[128][72];
    const int t = threadIdx.x;
    const int s0 = blockIdx.x * 64;
    const int bh = blockIdx.y, b = bh >> 2, h = bh & 3;
    const int sr = t >> 2, d0 = (t & 3) * 32;
    const float* src = QKVf + (long)(b * 512 + s0 + sr) * 3072 + 2560 + h * 128 + d0;
#pragma unroll
    for (int j = 0; j < 8; ++j) {
        f32x4 v = *(const f32x4*)(src + j * 4);
#pragma unroll
        for (int e = 0; e < 4; ++e) T[d0 + j * 4 + e][sr] = f2bf(v[e]);
    }
    __syncthreads();
    const int start = startp[0];
    const int d = t >> 1, pc = (t & 1) * 32;
    u16* dst = Vtc + ((long)(b * 4 + h) * 128 + d) * MAXP_ + start + s0 + pc;
#pragma unroll
    for (int k = 0; k < 32; ++k) dst[k] = T[d][pc + k];  // scalar: start may be unaligned
}

// ---------------- flash attention: LDS-staged K/V (request-dedup), XCD-pinned ----------------
// Theory: prior zero-LDS versions were L1-request bound (each wave's strided K/V fragment
// loads = 16 cache lines/inst, x4 waves duplicating the same tile). Now each 64-key tile's
// K (16KB) and V^T (16KB) are staged ONCE per block via coalesced global_load_lds
// (8 lines/wave-inst), double-buffered with a single vmcnt(0)+barrier per tile (T3 minimum).
// XOR-swizzle byte^=(row&7)<<4 on BOTH stage-source and LDS-read (G21) -> 2-way conflicts.
// 512 blocks; bh=id&7 (XCD-pinned); 4 waves = 4 q-heads; 32 q-rows/wave; in-register P.
__global__ __launch_bounds__(256) void attn(const u16* __restrict__ Qn,
        const u16* __restrict__ Kc, const u16* __restrict__ Vtc,
        const int* __restrict__ startp, const int* __restrict__ ctxp,
        u16* __restrict__ op, float* __restrict__ mp, float* __restrict__ lp) {
    __shared__ __align__(16) char KsB[2][16384];   // [buf][64 rows x 256B]
    __shared__ __align__(16) char VsB[2][16384];   // [buf][128 rows x 128B]
    const int tid = threadIdx.x, lane = tid & 63, w = tid >> 6;
    const int l15 = lane & 15, g = lane >> 4;
    const bool ghi = (g >= 2);
    const int id = blockIdx.x;
    const int bh = id & 7;                  // b*4 + hkv, pinned to XCD id%8
    const int rest = id >> 3;
    const int c = rest >> 4;                // chunk 0..3
    const int q0 = (rest & 15) * 32;        // q-tile origin
    const int b = bh >> 2, hkv = bh & 3;
    const int hq = hkv * 4 + w;
    const int start = startp[0];
    const int ctx = ctxp[b];

    int lim_blk = start + q0 + 32;
    if (lim_blk > ctx) lim_blk = ctx;
    const int pbeg = c * CHUNKP;
    int pend = pbeg + CHUNKP;
    if (pend > lim_blk) pend = lim_blk;
    if (pbeg >= pend) return;               // block-uniform (before any barrier)

    const long rowbase = (long)(b * 16 + hq) * 512 + q0;

    // Q B-frags
    bf16x8 qb[2][4];
#pragma unroll
    for (int qf = 0; qf < 2; ++qf) {
        const u16* qp = Qn + (rowbase + qf * 16 + l15) * 128 + g * 8;
#pragma unroll
        for (int kf = 0; kf < 4; ++kf)
            qb[qf][kf] = *(const bf16x8*)(qp + kf * 32);
    }

    const char* kb8 = (const char*)(Kc + (long)bh * (MAXP_ * 128));
    const char* vb8 = (const char*)(Vtc + (long)bh * (128 * MAXP_));

    // stage one 64-key tile (K 16KB + V^T 16KB) with pre-swizzled source (G21)
    const int wbase = (tid & ~63) * 16;     // wave-uniform LDS base within a 4KB round
    auto STAGE = [&](int buf, int p0_) {
#pragma unroll
        for (int r = 0; r < 4; ++r) {
            int o = r * 4096 + tid * 16;
            int row = o >> 8;
            int colb = (o & 255) ^ ((row & 7) << 4);
            GLOAD16(kb8 + (long)(p0_ + row) * 256 + colb, &KsB[buf][r * 4096 + wbase]);
        }
#pragma unroll
        for (int r = 0; r < 4; ++r) {
            int o = r * 4096 + tid * 16;
            int row = o >> 7;
            int colb = (o & 127) ^ ((row & 7) << 4);
            GLOAD16(vb8 + (long)row * (MAXP_ * 2) + (long)p0_ * 2 + colb, &VsB[buf][r * 4096 + wbase]);
        }
    };

    f32x4 o[2][8] = {};
    float m_run[2] = {-1e30f, -1e30f};
    float l_run[2] = {0.f, 0.f};
    int limq[2];
#pragma unroll
    for (int qf = 0; qf < 2; ++qf) {
        int lq = start + q0 + qf * 16 + l15 + 1;
        if (lq > ctx) lq = ctx;
        if (lq > pend) lq = pend;
        limq[qf] = lq;
    }
    const int addrA = (l15 + ((g & 1) << 5)) << 2;
    const int addrB = addrA + 64;
    const float scale = 0.08838834764831845f;
    const int swz = (l15 & 7) << 4;          // read-side XOR (row&7 == l15&7 for all frags)

    const int t0 = pbeg >> 6, t1 = (pend + 63) >> 6;
    STAGE(0, t0 * 64);
    asm volatile("s_waitcnt vmcnt(0)" ::: "memory");
    __builtin_amdgcn_s_barrier();
    int cur = 0;
    for (int t = t0; t < t1; ++t) {
        const int p0 = t * 64;
        if (t + 1 < t1) STAGE(cur ^ 1, p0 + 64);   // async prefetch; in flight through compute
        // QK^T swapped: sacc[kt][qf] = C[key=p0+kt*16+g*4+r][q=q0+qf*16+l15]
        f32x4 sacc[4][2] = {};
#pragma unroll
        for (int kt = 0; kt < 4; ++kt) {
            const char* krow = &KsB[cur][(kt * 16 + l15) * 256];
#pragma unroll
            for (int kf = 0; kf < 4; ++kf) {
                bf16x8 ka = *(const bf16x8*)(krow + ((kf * 64 + g * 16) ^ swz));
                sacc[kt][0] = __builtin_amdgcn_mfma_f32_16x16x32_bf16(ka, qb[0][kf], sacc[kt][0], 0, 0, 0);
                sacc[kt][1] = __builtin_amdgcn_mfma_f32_16x16x32_bf16(ka, qb[1][kf], sacc[kt][1], 0, 0, 0);
            }
        }
        // mask + online softmax; stats per q=l15 (replicated over g)
        u32 w0[4][2], w1[4][2];
#pragma unroll
        for (int qf = 0; qf < 2; ++qf) {
            float mx = -1e30f;
#pragma unroll
            for (int kt = 0; kt < 4; ++kt)
#pragma unroll
                for (int r = 0; r < 4; ++r) {
                    int key = p0 + kt * 16 + g * 4 + r;
                    float x = (key < limq[qf]) ? sacc[kt][qf][r] * scale : -1e30f;
                    sacc[kt][qf][r] = x;
                    mx = fmaxf(mx, x);
                }
            mx = fmaxf(mx, __shfl_xor(mx, 16, 64));
            mx = fmaxf(mx, __shfl_xor(mx, 32, 64));
            float mnew = fmaxf(m_run[qf], mx);
            float alpha = __expf(m_run[qf] - mnew);
            m_run[qf] = mnew;
            float rs = 0.f;
#pragma unroll
            for (int kt = 0; kt < 4; ++kt) {
#pragma unroll
                for (int r = 0; r < 4; ++r) {
                    float p = __expf(sacc[kt][qf][r] - mnew);
                    sacc[kt][qf][r] = p;
                    rs += p;
                }
                w0[kt][qf] = packbf(sacc[kt][qf][0], sacc[kt][qf][1]);
                w1[kt][qf] = packbf(sacc[kt][qf][2], sacc[kt][qf][3]);
            }
            rs += __shfl_xor(rs, 16, 64);
            rs += __shfl_xor(rs, 32, 64);
            l_run[qf] = l_run[qf] * alpha + rs;
            f32x4 av;
#pragma unroll
            for (int r = 0; r < 4; ++r) av[r] = __shfl(alpha, g * 4 + r, 64);
#pragma unroll
            for (int df = 0; df < 8; ++df) {
                o[qf][df][0] *= av[0]; o[qf][df][1] *= av[1];
                o[qf][df][2] *= av[2]; o[qf][df][3] *= av[3];
            }
        }
        // PV in two K=32 steps; P A-frag via bpermute; V from LDS (swizzled read)
#pragma unroll
        for (int ks = 0; ks < 2; ++ks) {
            bf16x8 pa[2];
#pragma unroll
            for (int qf = 0; qf < 2; ++qf) {
                const int sL = 2 * ks, sH = 2 * ks + 1;
                u32 d0 = ghi ? bperm(addrA, w0[sH][qf]) : bperm(addrA, w0[sL][qf]);
                u32 d1 = ghi ? bperm(addrA, w1[sH][qf]) : bperm(addrA, w1[sL][qf]);
                u32 d2 = ghi ? bperm(addrB, w0[sH][qf]) : bperm(addrB, w0[sL][qf]);
                u32 d3 = ghi ? bperm(addrB, w1[sH][qf]) : bperm(addrB, w1[sL][qf]);
                union { u32 d[4]; bf16x8 v; } pu;
                pu.d[0] = d0; pu.d[1] = d1; pu.d[2] = d2; pu.d[3] = d3;
                pa[qf] = pu.v;
            }
#pragma unroll
            for (int df = 0; df < 8; ++df) {
                const char* vrow = &VsB[cur][(df * 16 + l15) * 128];
                bf16x8 vb = *(const bf16x8*)(vrow + ((ks * 64 + g * 16) ^ swz));
                o[0][df] = __builtin_amdgcn_mfma_f32_16x16x32_bf16(pa[0], vb, o[0][df], 0, 0, 0);
                o[1][df] = __builtin_amdgcn_mfma_f32_16x16x32_bf16(pa[1], vb, o[1][df], 0, 0, 0);
            }
        }
        // next tile ready + all waves done reading cur
        asm volatile("s_waitcnt vmcnt(0)" ::: "memory");
        __builtin_amdgcn_s_barrier();
        cur ^= 1;
    }
    // epilogue: normalized bf16 partial + (m,l)
#pragma unroll
    for (int qf = 0; qf < 2; ++qf) {
        float invl = l_run[qf] > 0.f ? 1.0f / l_run[qf] : 0.f;
        f32x4 iv;
#pragma unroll
        for (int r = 0; r < 4; ++r) iv[r] = __shfl(invl, g * 4 + r, 64);
        u16* dst = op + ((long)c * TOTROWS + rowbase + qf * 16 + g * 4) * 128 + l15;
#pragma unroll
        for (int r = 0; r < 4; ++r)
#pragma unroll
            for (int df = 0; df < 8; ++df)
                dst[(long)r * 128 + df * 16] = f2bf(o[qf][df][r] * iv[r]);
        if (g == 0) {
            mp[(long)c * TOTROWS + rowbase + qf * 16 + l15] = m_run[qf];
            lp[(long)c * TOTROWS + rowbase + qf * 16 + l15] = l_run[qf];
        }
    }
}

// ---------------- combine split-KV partials -> Af bf16 [b*512+s][2048] ----------------
__global__ __launch_bounds__(256) void combine(const u16* __restrict__ op,
        const float* __restrict__ mp, const float* __restrict__ lp,
        const int* __restrict__ startp, const int* __restrict__ ctxp,
        u16* __restrict__ Af) {
    const int w = threadIdx.x >> 6, lane = threadIdx.x & 63;
    const long row = (long)blockIdx.x * 4 + w;
    const int b = (int)(row >> 13), hq = ((int)row >> 9) & 15, s = (int)row & 511;
    const int start = startp[0];
    int lim = start + s + 1;
    int cx = ctxp[b];
    if (lim > cx) lim = cx;
    float mc[NCALLOC], lc[NCALLOC];
    bool has[NCALLOC];
    float M = -1e30f;
#pragma unroll
    for (int c = 0; c < NCALLOC; ++c) {
        has[c] = (c * CHUNKP < lim);
        if (has[c]) {
            mc[c] = mp[(long)c * TOTROWS + row];
            lc[c] = lp[(long)c * TOTROWS + row];
            if (lc[c] > 0.f && mc[c] > M) M = mc[c];
        }
    }
    const int d0 = lane * 2;
    float Wt = 0.f, a0 = 0.f, a1 = 0.f;
#pragma unroll
    for (int c = 0; c < NCALLOC; ++c) {
        if (has[c] && lc[c] > 0.f) {
            float wg = lc[c] * __expf(mc[c] - M);
            Wt += wg;
            u32 pr = *(const u32*)&op[((long)c * TOTROWS + row) * 128 + d0];
            a0 += wg * bf2f((u16)(pr & 0xFFFF));
            a1 += wg * bf2f((u16)(pr >> 16));
        }
    }
    float inv = 1.0f / Wt;
    u32 pk = (u32)f2bf(a0 * inv) | ((u32)f2bf(a1 * inv) << 16);
    *(u32*)&Af[((long)(b * 512 + s) * 2048) + hq * 128 + d0] = pk;
}

extern "C" void kernel_launch(void* const* d_in, const int* in_sizes, int n_in,
                              void* d_out, int out_size, void* d_ws, size_t ws_size,
                              hipStream_t stream) {
    const float* hidden = (const float*)d_in[0];
    const float* past   = (const float*)d_in[1];
    const float* rope   = (const float*)d_in[2];
    const float* Wq     = (const float*)d_in[3];
    const float* Wk     = (const float*)d_in[4];
    const float* Wv     = (const float*)d_in[5];
    const float* Wo     = (const float*)d_in[6];
    const float* qw     = (const float*)d_in[7];
    const float* kw     = (const float*)d_in[8];
    const int*   ctx    = (const int*)d_in[9];
    const int*   start  = (const int*)d_in[10];

    float* out = (float*)d_out;
    float* present = out + 2097152;
    u16* Kc = (u16*)d_out;   // parked in attn-output region of d_out

    char* wsb = (char*)d_ws;
    u16*   hb    = (u16*)(wsb + 0);
    u16*   Wqkvt = (u16*)(wsb + 4194304);
    float* QKVf  = (float*)(wsb + 16777216);
    u16*   op    = (u16*)(wsb + 0);
    float* mp    = (float*)(wsb + 16777216);
    float* lp    = (float*)(wsb + 17039360);
    u16*   Wot   = (u16*)(wsb + 17301504);
    u16*   Qn    = (u16*)(wsb + 29360128);
    u16*   Af    = (u16*)(wsb + 29360128);
    u16*   Vtc   = (u16*)(wsb + 33554432);

    cvt_bf16<<<dim3(1024), dim3(256), 0, stream>>>(hidden, hb, 262144);                     // 1
    trans_w<<<dim3(32, 32), dim3(256), 0, stream>>>(Wq, Wqkvt, 2048, 2048, 0);              // 2
    trans_w<<<dim3(8, 32),  dim3(256), 0, stream>>>(Wk, Wqkvt, 512, 2048, 2048);            // 3
    trans_w<<<dim3(8, 32),  dim3(256), 0, stream>>>(Wv, Wqkvt, 512, 2048, 2560);            // 4
    copy_past2<<<dim3(64, 16), dim3(256), 0, stream>>>(past, present, Kc, Vtc, start, ctx); // 5
    gemm64<<<dim3(48, 16), dim3(256), 0, stream>>>(hb, Wqkvt, QKVf, 1024, 3072, 2048);      // 6
    normrope<<<dim3(6144), dim3(256), 0, stream>>>(QKVf, rope, qw, kw, start, present, Qn, Kc); // 7
    vtrans_new<<<dim3(8, 8), dim3(256), 0, stream>>>(QKVf, start, Vtc);                     // 8
    trans_w<<<dim3(32, 32), dim3(256), 0, stream>>>(Wo, Wot, 2048, 2048, 0);                // 9
    attn<<<dim3(512), dim3(256), 0, stream>>>(Qn, Kc, Vtc, start, ctx, op, mp, lp);         // 10
    combine<<<dim3(4096), dim3(256), 0, stream>>>(op, mp, lp, start, ctx, Af);              // 11
    gemm64<<<dim3(32, 16), dim3(256), 0, stream>>>(Af, Wot, out, 1024, 2048, 2048);         // 12
}

// Round 15
// 130.146 us; speedup vs baseline: 1.7925x; 1.2464x over previous
//
#include <hip/hip_runtime.h>

typedef unsigned short u16;
typedef unsigned int u32;
typedef __attribute__((ext_vector_type(4))) float f32x4;
typedef __attribute__((ext_vector_type(8))) __bf16 bf16x8;
typedef __attribute__((ext_vector_type(8))) unsigned short u16x8;

#define MAXP_ 4096
#define TOTROWS 16384   // B*HQ*S = 2*16*512
#define NCHUNK 4
#define NCALLOC 4
#define CHUNKP 512

__device__ __forceinline__ u16 f2bf(float f) {
    union { float f; u32 u; } x; x.f = f;
    u32 r = x.u + 0x7FFFu + ((x.u >> 16) & 1u);
    return (u16)(r >> 16);
}
__device__ __forceinline__ float bf2f(u16 u) {
    union { u32 u; float f; } x; x.u = ((u32)u) << 16; return x.f;
}
// RNE bf16 pair pack
__device__ __forceinline__ u32 packbf(float lo, float hi) {
    return (u32)f2bf(lo) | ((u32)f2bf(hi) << 16);
}
__device__ __forceinline__ u32 bperm(int addr, u32 src) {
    return (u32)__builtin_amdgcn_ds_bpermute(addr, (int)src);
}

#define GLOAD16(g, l) __builtin_amdgcn_global_load_lds( \
    (const __attribute__((address_space(1))) void*)(g), \
    (__attribute__((address_space(3))) void*)(l), 16, 0, 0)

// ---------------- fused prep: cvt(hidden->bf16) + transpose Wq/Wk/Wv -> Wqkvt ----------------
// grid 2560 EXACTLY: [0,1024) cvt; [1024,2048) Wq (1024 blk); [2048,2304) Wk (256); [2304,2560) Wv (256).
// (R14 bug: grid 3584 sent 1024 stray blocks into the Wv branch -> OOB reads -> crash.)
__global__ __launch_bounds__(256) void prep(const float* __restrict__ hidden,
        const float* __restrict__ Wq, const float* __restrict__ Wk, const float* __restrict__ Wv,
        u16* __restrict__ hb, u16* __restrict__ Wqkvt) {
    const int bid = blockIdx.x;
    const int t = threadIdx.x;
    if (bid < 1024) {   // cvt: 262144 groups of 8
        int i = bid * 256 + t;
        const float* s = hidden + (long)i * 8;
        f32x4 a = *(const f32x4*)s;
        f32x4 b = *(const f32x4*)(s + 4);
        u16x8 o;
#pragma unroll
        for (int j = 0; j < 4; ++j) { o[j] = f2bf(a[j]); o[4 + j] = f2bf(b[j]); }
        *(u16x8*)&hb[(long)i * 8] = o;
        return;
    }
    __shared__ __align__(16) u16 T[64][72];
    const float* W; int N_w, n_off, n0, k0;
    if (bid < 2048)      { int b2 = bid - 1024; W = Wq; N_w = 2048; n_off = 0;    n0 = (b2 & 31) * 64; k0 = (b2 >> 5) * 64; }
    else if (bid < 2304) { int b2 = bid - 2048; W = Wk; N_w = 512;  n_off = 2048; n0 = (b2 & 7) * 64;  k0 = (b2 >> 3) * 64; }
    else                 { int b2 = bid - 2304; W = Wv; N_w = 512;  n_off = 2560; n0 = (b2 & 7) * 64;  k0 = (b2 >> 3) * 64; }
    {
        int r = t >> 2, c4 = (t & 3) * 16;
        const float* src = W + (long)(k0 + r) * N_w + n0 + c4;
        f32x4 a0 = *(const f32x4*)src, a1 = *(const f32x4*)(src + 4);
        f32x4 a2 = *(const f32x4*)(src + 8), a3 = *(const f32x4*)(src + 12);
        u16x8 p0, p1;
#pragma unroll
        for (int j = 0; j < 4; ++j) {
            p0[j] = f2bf(a0[j]); p0[4 + j] = f2bf(a1[j]);
            p1[j] = f2bf(a2[j]); p1[4 + j] = f2bf(a3[j]);
        }
        *(u16x8*)&T[r][c4] = p0;
        *(u16x8*)&T[r][c4 + 8] = p1;
    }
    __syncthreads();
    {
        int n = t >> 2, k4 = (t & 3) * 16;
        u16x8 q0, q1;
#pragma unroll
        for (int j = 0; j < 8; ++j) { q0[j] = T[k4 + j][n]; q1[j] = T[k4 + 8 + j][n]; }
        u16* dst = Wqkvt + (long)(n_off + n0 + n) * 2048 + k0 + k4;
        *(u16x8*)dst = q0;
        *(u16x8*)(dst + 8) = q1;
    }
}

// ---------------- W[K][N] fp32 -> Wt[n][K] bf16 (tiled transpose) — used late for Wo ----------------
__global__ __launch_bounds__(256) void trans_w(const float* __restrict__ W, u16* __restrict__ Wt,
                                               int N_w, int K, int n_off) {
    __shared__ __align__(16) u16 T[64][72];
    const int t = threadIdx.x;
    const int n0 = blockIdx.x * 64, k0 = blockIdx.y * 64;
    {
        int r = t >> 2, c4 = (t & 3) * 16;
        const float* src = W + (long)(k0 + r) * N_w + n0 + c4;
        f32x4 a0 = *(const f32x4*)src, a1 = *(const f32x4*)(src + 4);
        f32x4 a2 = *(const f32x4*)(src + 8), a3 = *(const f32x4*)(src + 12);
        u16x8 p0, p1;
#pragma unroll
        for (int j = 0; j < 4; ++j) {
            p0[j] = f2bf(a0[j]); p0[4 + j] = f2bf(a1[j]);
            p1[j] = f2bf(a2[j]); p1[4 + j] = f2bf(a3[j]);
        }
        *(u16x8*)&T[r][c4] = p0;
        *(u16x8*)&T[r][c4 + 8] = p1;
    }
    __syncthreads();
    {
        int n = t >> 2, k4 = (t & 3) * 16;
        u16x8 q0, q1;
#pragma unroll
        for (int j = 0; j < 8; ++j) { q0[j] = T[k4 + j][n]; q1[j] = T[k4 + 8 + j][n]; }
        u16* dst = Wt + (long)(n_off + n0 + n) * K + k0 + k4;
        *(u16x8*)dst = q0;
        *(u16x8*)(dst + 8) = q1;
    }
}

// ---------------- copy past -> present + bf16 K cache + bf16 V^T cache ----------------
__global__ __launch_bounds__(256) void copy_past2(const float* __restrict__ past,
        float* __restrict__ present, u16* __restrict__ Kc, u16* __restrict__ Vtc,
        const int* __restrict__ startp, const int* __restrict__ ctxp) {
    __shared__ __align__(16) u16 T[128][72];
    const int bkh = blockIdx.y;            // (b*2+kv)*4+h
    const int b = bkh >> 3, kv = (bkh >> 2) & 1, h = bkh & 3;
    const int p0 = blockIdx.x * 64;
    const int t = threadIdx.x;
    const int p = t >> 2, d0 = (t & 3) * 32;
    const float* src = past + ((long)bkh * MAXP_ + p0 + p) * 128 + d0;
    float* dst = present + ((long)bkh * MAXP_ + p0 + p) * 128 + d0;
    f32x4 v[8];
#pragma unroll
    for (int j = 0; j < 8; ++j) { v[j] = *(const f32x4*)(src + j * 4); *(f32x4*)(dst + j * 4) = v[j]; }
    int klim = startp[0] + 512;
    int cx = ctxp[b];
    if (klim > cx) klim = cx;
    if (p0 >= klim) return;
    if (kv == 0) {
        u16* kd = Kc + ((long)(b * 4 + h) * MAXP_ + p0 + p) * 128 + d0;
#pragma unroll
        for (int j2 = 0; j2 < 4; ++j2) {
            u16x8 o;
#pragma unroll
            for (int e = 0; e < 4; ++e) { o[e] = f2bf(v[j2 * 2][e]); o[4 + e] = f2bf(v[j2 * 2 + 1][e]); }
            *(u16x8*)&kd[j2 * 8] = o;
        }
    } else {
#pragma unroll
        for (int j = 0; j < 8; ++j)
#pragma unroll
            for (int e = 0; e < 4; ++e)
                T[d0 + j * 4 + e][p] = f2bf(v[j][e]);
        __syncthreads();
        int d = t >> 1, pc = (t & 1) * 32;
        u16* vd = Vtc + ((long)(b * 4 + h) * 128 + d) * MAXP_ + p0 + pc;
#pragma unroll
        for (int j = 0; j < 4; ++j)
            *(u16x8*)&vd[j * 8] = *(const u16x8*)&T[d][pc + j * 8];
    }
}

// ---------------- bf16 GEMM, A[M][K] @ Bt[N][K]^T -> C[M][N] f32 ----------------
__global__ __launch_bounds__(256) void gemm64(const u16* __restrict__ A, const u16* __restrict__ Bt,
                                              float* __restrict__ C, int M, int N, int K) {
    __shared__ __align__(16) u16 As0[4096], Bs0[4096], As1[4096], Bs1[4096];
    const int tid = threadIdx.x, lane = tid & 63, w = tid >> 6;
    const int wm = w >> 1, wn = w & 1;
    const int l15 = lane & 15, g = lane >> 4;
    const int m0 = blockIdx.y * 64, n0 = blockIdx.x * 64;
    f32x4 acc[2][2] = {};

    const int lrow = lane >> 3;
    const int sch = (lane & 7) ^ lrow;
    const int c0 = w, c1 = w + 4;
    const u16* ga0 = A + (long)(m0 + c0 * 8 + lrow) * K + sch * 8;
    const u16* ga1 = A + (long)(m0 + c1 * 8 + lrow) * K + sch * 8;
    const u16* gb0 = Bt + (long)(n0 + c0 * 8 + lrow) * K + sch * 8;
    const u16* gb1 = Bt + (long)(n0 + c1 * 8 + lrow) * K + sch * 8;
    const int ra = wm * 32, rb = wn * 32;
    const int h7 = l15 & 7;

#define STAGE_T(koff, AS_, BS_) do { \
        GLOAD16(ga0 + (koff), &AS_[c0 * 512]); \
        GLOAD16(ga1 + (koff), &AS_[c1 * 512]); \
        GLOAD16(gb0 + (koff), &BS_[c0 * 512]); \
        GLOAD16(gb1 + (koff), &BS_[c1 * 512]); \
    } while (0)

    auto compute = [&](const u16* as_, const u16* bs_) {
        bf16x8 af[2][2], bfr[2][2];
#pragma unroll
        for (int i = 0; i < 2; ++i) {
            int rr = ra + i * 16 + l15;
#pragma unroll
            for (int kk = 0; kk < 2; ++kk)
                af[i][kk] = *(const bf16x8*)&as_[rr * 64 + (((kk * 4 + g) ^ h7) * 8)];
        }
#pragma unroll
        for (int j = 0; j < 2; ++j) {
            int rr = rb + j * 16 + l15;
#pragma unroll
            for (int kk = 0; kk < 2; ++kk)
                bfr[j][kk] = *(const bf16x8*)&bs_[rr * 64 + (((kk * 4 + g) ^ h7) * 8)];
        }
#pragma unroll
        for (int i = 0; i < 2; ++i)
#pragma unroll
            for (int j = 0; j < 2; ++j) {
                acc[i][j] = __builtin_amdgcn_mfma_f32_16x16x32_bf16(af[i][0], bfr[j][0], acc[i][j], 0, 0, 0);
                acc[i][j] = __builtin_amdgcn_mfma_f32_16x16x32_bf16(af[i][1], bfr[j][1], acc[i][j], 0, 0, 0);
            }
    };

    STAGE_T(0, As0, Bs0);
    for (int k0 = 0; k0 < K; k0 += 128) {
        STAGE_T(k0 + 64, As1, Bs1);
        asm volatile("s_waitcnt vmcnt(4)" ::: "memory");
        __builtin_amdgcn_s_barrier();
        __builtin_amdgcn_sched_barrier(0);
        compute(As0, Bs0);
        __builtin_amdgcn_s_barrier();
        if (k0 + 128 < K) {
            STAGE_T(k0 + 128, As0, Bs0);
            asm volatile("s_waitcnt vmcnt(4)" ::: "memory");
        } else {
            asm volatile("s_waitcnt vmcnt(0)" ::: "memory");
        }
        __builtin_amdgcn_s_barrier();
        __builtin_amdgcn_sched_barrier(0);
        compute(As1, Bs1);
        __builtin_amdgcn_s_barrier();
    }
#undef STAGE_T

#pragma unroll
    for (int i = 0; i < 2; ++i)
#pragma unroll
        for (int j = 0; j < 2; ++j)
#pragma unroll
            for (int r = 0; r < 4; ++r)
                C[(long)(m0 + ra + i * 16 + g * 4 + r) * N + n0 + rb + j * 16 + l15] = acc[i][j][r];
}

// ---------------- fused RMS norm + RoPE + cache scatter + new-V transpose ----------------
// grid 6208: [0,6144) normrope (wid = bid*4 + wave); [6144,6208) vtrans (64 blocks = 8 s0 x 8 bh).
__global__ __launch_bounds__(256) void normrope_v(const float* __restrict__ QKVf,
        const float* __restrict__ rope,
        const float* __restrict__ qw, const float* __restrict__ kw,
        const int* __restrict__ startp, float* __restrict__ present,
        u16* __restrict__ Qn, u16* __restrict__ Kc, u16* __restrict__ Vtc) {
    const int bid = blockIdx.x;
    const int start = startp[0];
    if (bid < 6144) {
        const int wid = bid * 4 + (threadIdx.x >> 6);
        const int lane = threadIdx.x & 63;
        if (wid < 16384) { // Q: 1024 rows x 16 heads
            int row = wid >> 4, h = wid & 15;
            int b = row >> 9, s = row & 511;
            const float* src = QKVf + (long)row * 3072 + h * 128;
            float x1 = src[lane], x2 = src[64 + lane];
            float v = x1 * x1 + x2 * x2;
#pragma unroll
            for (int off = 32; off; off >>= 1) v += __shfl_xor(v, off, 64);
            float sc = rsqrtf(v * (1.0f / 128.0f) + 1e-6f);
            float y1 = x1 * sc * qw[lane], y2 = x2 * sc * qw[64 + lane];
            float c = rope[(long)row * 128 + lane], sn = rope[(long)row * 128 + 64 + lane];
            u16* dst = Qn + (((long)(b * 16 + h) * 512 + s) * 128);
            dst[lane] = f2bf(y1 * c - y2 * sn);
            dst[64 + lane] = f2bf(y2 * c + y1 * sn);
        } else if (wid < 20480) { // K: 1024 rows x 4 heads
            int j = wid - 16384;
            int row = j >> 2, h = j & 3;
            int b = row >> 9, s = row & 511;
            const float* src = QKVf + (long)row * 3072 + 2048 + h * 128;
            float x1 = src[lane], x2 = src[64 + lane];
            float v = x1 * x1 + x2 * x2;
#pragma unroll
            for (int off = 32; off; off >>= 1) v += __shfl_xor(v, off, 64);
            float sc = rsqrtf(v * (1.0f / 128.0f) + 1e-6f);
            float y1 = x1 * sc * kw[lane], y2 = x2 * sc * kw[64 + lane];
            float c = rope[(long)row * 128 + lane], sn = rope[(long)row * 128 + 64 + lane];
            float k1 = y1 * c - y2 * sn, k2 = y2 * c + y1 * sn;
            float* dst = present + (((long)(b * 2 + 0) * 4 + h) * MAXP_ + (start + s)) * 128;
            dst[lane] = k1; dst[64 + lane] = k2;
            u16* kc = Kc + (((long)(b * 4 + h)) * MAXP_ + start + s) * 128;
            kc[lane] = f2bf(k1); kc[64 + lane] = f2bf(k2);
        } else if (wid < 24576) { // V: present copy only
            int j = wid - 20480;
            int row = j >> 2, h = j & 3;
            int b = row >> 9, s = row & 511;
            const float* src = QKVf + (long)row * 3072 + 2560 + h * 128;
            float* dst = present + (((long)(b * 2 + 1) * 4 + h) * MAXP_ + (start + s)) * 128;
            dst[lane] = src[lane];
            dst[64 + lane] = src[64 + lane];
        }
        return;
    }
    // vtrans: new V -> Vtc bf16 [d][p]
    __shared__ __align__(16) u16 T[128][72];
    const int t = threadIdx.x;
    const int b2 = bid - 6144;
    const int s0 = (b2 & 7) * 64;
    const int bh = b2 >> 3, b = bh >> 2, h = bh & 3;
    const int sr = t >> 2, d0 = (t & 3) * 32;
    const float* src = QKVf + (long)(b * 512 + s0 + sr) * 3072 + 2560 + h * 128 + d0;
#pragma unroll
    for (int j = 0; j < 8; ++j) {
        f32x4 v = *(const f32x4*)(src + j * 4);
#pragma unroll
        for (int e = 0; e < 4; ++e) T[d0 + j * 4 + e][sr] = f2bf(v[e]);
    }
    __syncthreads();
    const int d = t >> 1, pc = (t & 1) * 32;
    u16* dst = Vtc + ((long)(b * 4 + h) * 128 + d) * MAXP_ + start + s0 + pc;
#pragma unroll
    for (int k = 0; k < 32; ++k) dst[k] = T[d][pc + k];  // scalar: start may be unaligned
}

// ---------------- flash attention: LDS-staged K/V, 8 waves, XCD-pinned, defer-max ----------------
// 512 blocks x 512 threads. bh=id&7 (XCD-pinned); c=(id>>3)>>4; q0=((id>>3)&15)*32.
// 8 waves = 4 heads x 2 q-subtiles of 16 rows: per-wave softmax/bpermute cost halved vs R13,
// TLP doubled (launch_bounds(512,4): VGPR cap 128 >= ~90 needed -> no spill).
// K/V tile staged ONCE per block (request-dedup, proven R13); defer-max (T13).
__global__ __launch_bounds__(512, 4) void attn(const u16* __restrict__ Qn,
        const u16* __restrict__ Kc, const u16* __restrict__ Vtc,
        const int* __restrict__ startp, const int* __restrict__ ctxp,
        u16* __restrict__ op, float* __restrict__ mp, float* __restrict__ lp) {
    __shared__ __align__(16) char KsB[2][16384];   // [buf][64 rows x 256B]
    __shared__ __align__(16) char VsB[2][16384];   // [buf][128 rows x 128B]
    const int tid = threadIdx.x, lane = tid & 63, w = tid >> 6;
    const int l15 = lane & 15, g = lane >> 4;
    const bool ghi = (g >= 2);
    const int id = blockIdx.x;
    const int bh = id & 7;
    const int rest = id >> 3;
    const int c = rest >> 4;
    const int q0 = (rest & 15) * 32;
    const int b = bh >> 2, hkv = bh & 3;
    const int hd = w & 3, qh = w >> 2;
    const int hq = hkv * 4 + hd;
    const int start = startp[0];
    const int ctx = ctxp[b];

    int lim_blk = start + q0 + 32;
    if (lim_blk > ctx) lim_blk = ctx;
    const int pbeg = c * CHUNKP;
    int pend = pbeg + CHUNKP;
    if (pend > lim_blk) pend = lim_blk;
    if (pbeg >= pend) return;               // block-uniform (before any barrier)

    const int qrow0 = q0 + qh * 16;
    const long rowbase = (long)(b * 16 + hq) * 512 + qrow0;

    bf16x8 qb[4];
    {
        const u16* qp = Qn + (rowbase + l15) * 128 + g * 8;
#pragma unroll
        for (int kf = 0; kf < 4; ++kf)
            qb[kf] = *(const bf16x8*)(qp + kf * 32);
    }

    const char* kb8 = (const char*)(Kc + (long)bh * (MAXP_ * 128));
    const char* vb8 = (const char*)(Vtc + (long)bh * (128 * MAXP_));

    // stage one 64-key tile (K 16KB + V^T 16KB); 512 threads -> 2 rounds each; G21 pre-swizzle
    const int wbase = (tid & ~63) * 16;
    auto STAGE = [&](int buf, int p0_) {
#pragma unroll
        for (int r = 0; r < 2; ++r) {
            int o_ = r * 8192 + tid * 16;
            int row = o_ >> 8;
            int colb = (o_ & 255) ^ ((row & 7) << 4);
            GLOAD16(kb8 + (long)(p0_ + row) * 256 + colb, &KsB[buf][r * 8192 + wbase]);
        }
#pragma unroll
        for (int r = 0; r < 2; ++r) {
            int o_ = r * 8192 + tid * 16;
            int row = o_ >> 7;
            int colb = (o_ & 127) ^ ((row & 7) << 4);
            GLOAD16(vb8 + (long)row * (MAXP_ * 2) + (long)p0_ * 2 + colb, &VsB[buf][r * 8192 + wbase]);
        }
    };

    f32x4 o[8] = {};
    float m_run = -1e30f, l_run = 0.f;
    int limq = start + qrow0 + l15 + 1;
    if (limq > ctx) limq = ctx;
    if (limq > pend) limq = pend;
    const int addrA = (l15 + ((g & 1) << 5)) << 2;
    const int addrB = addrA + 64;
    const float scale = 0.08838834764831845f;
    const int swz = (l15 & 7) << 4;

    const int t0 = pbeg >> 6, t1 = (pend + 63) >> 6;
    STAGE(0, t0 * 64);
    asm volatile("s_waitcnt vmcnt(0)" ::: "memory");
    __builtin_amdgcn_s_barrier();
    int cur = 0;
    for (int t = t0; t < t1; ++t) {
        const int p0 = t * 64;
        if (t + 1 < t1) STAGE(cur ^ 1, p0 + 64);   // async prefetch, in flight through compute
        // QK^T swapped: sacc[kt] = C[key=p0+kt*16+g*4+r][q=qrow0+l15]
        f32x4 sacc[4] = {};
#pragma unroll
        for (int kt = 0; kt < 4; ++kt) {
            const char* krow = &KsB[cur][(kt * 16 + l15) * 256];
#pragma unroll
            for (int kf = 0; kf < 4; ++kf) {
                bf16x8 ka = *(const bf16x8*)(krow + ((kf * 64 + g * 16) ^ swz));
                sacc[kt] = __builtin_amdgcn_mfma_f32_16x16x32_bf16(ka, qb[kf], sacc[kt], 0, 0, 0);
            }
        }
        // mask + online softmax with defer-max; stats per q=l15 (replicated over g)
        float mx = -1e30f;
#pragma unroll
        for (int kt = 0; kt < 4; ++kt)
#pragma unroll
            for (int r = 0; r < 4; ++r) {
                int key = p0 + kt * 16 + g * 4 + r;
                float x = (key < limq) ? sacc[kt][r] * scale : -1e30f;
                sacc[kt][r] = x;
                mx = fmaxf(mx, x);
            }
        mx = fmaxf(mx, __shfl_xor(mx, 16, 64));
        mx = fmaxf(mx, __shfl_xor(mx, 32, 64));
        if (!__all(mx <= m_run + 8.f)) {           // rescale path (rare after tile 0)
            float mnew = fmaxf(m_run, mx);
            float alpha = __expf(m_run - mnew);
            m_run = mnew;
            l_run *= alpha;
            f32x4 av;
#pragma unroll
            for (int r = 0; r < 4; ++r) av[r] = __shfl(alpha, g * 4 + r, 64);
#pragma unroll
            for (int df = 0; df < 8; ++df) {
                o[df][0] *= av[0]; o[df][1] *= av[1];
                o[df][2] *= av[2]; o[df][3] *= av[3];
            }
        }
        const float mb = m_run;
        float rs = 0.f;
        u32 w0[4], w1[4];
#pragma unroll
        for (int kt = 0; kt < 4; ++kt) {
#pragma unroll
            for (int r = 0; r < 4; ++r) {
                float p = __expf(sacc[kt][r] - mb);
                sacc[kt][r] = p;
                rs += p;
            }
            w0[kt] = packbf(sacc[kt][0], sacc[kt][1]);
            w1[kt] = packbf(sacc[kt][2], sacc[kt][3]);
        }
        rs += __shfl_xor(rs, 16, 64);
        rs += __shfl_xor(rs, 32, 64);
        l_run += rs;
        // PV in two K=32 steps; P A-frag via bpermute; V from LDS (swizzled read)
#pragma unroll
        for (int ks = 0; ks < 2; ++ks) {
            const int sL = 2 * ks, sH = 2 * ks + 1;
            u32 d0 = ghi ? bperm(addrA, w0[sH]) : bperm(addrA, w0[sL]);
            u32 d1 = ghi ? bperm(addrA, w1[sH]) : bperm(addrA, w1[sL]);
            u32 d2 = ghi ? bperm(addrB, w0[sH]) : bperm(addrB, w0[sL]);
            u32 d3 = ghi ? bperm(addrB, w1[sH]) : bperm(addrB, w1[sL]);
            union { u32 d[4]; bf16x8 v; } pu;
            pu.d[0] = d0; pu.d[1] = d1; pu.d[2] = d2; pu.d[3] = d3;
            bf16x8 pa = pu.v;
#pragma unroll
            for (int df = 0; df < 8; ++df) {
                const char* vrow = &VsB[cur][(df * 16 + l15) * 128];
                bf16x8 vb = *(const bf16x8*)(vrow + ((ks * 64 + g * 16) ^ swz));
                o[df] = __builtin_amdgcn_mfma_f32_16x16x32_bf16(pa, vb, o[df], 0, 0, 0);
            }
        }
        // next tile staged + all waves done reading cur
        asm volatile("s_waitcnt vmcnt(0)" ::: "memory");
        __builtin_amdgcn_s_barrier();
        cur ^= 1;
    }
    // epilogue: normalized bf16 partial + (m,l)
    {
        float invl = l_run > 0.f ? 1.0f / l_run : 0.f;
        f32x4 iv;
#pragma unroll
        for (int r = 0; r < 4; ++r) iv[r] = __shfl(invl, g * 4 + r, 64);
        u16* dst = op + ((long)c * TOTROWS + rowbase + g * 4) * 128 + l15;
#pragma unroll
        for (int r = 0; r < 4; ++r)
#pragma unroll
            for (int df = 0; df < 8; ++df)
                dst[(long)r * 128 + df * 16] = f2bf(o[df][r] * iv[r]);
        if (g == 0) {
            mp[(long)c * TOTROWS + rowbase + l15] = m_run;
            lp[(long)c * TOTROWS + rowbase + l15] = l_run;
        }
    }
}

// ---------------- combine split-KV partials -> Af bf16 [b*512+s][2048] ----------------
__global__ __launch_bounds__(256) void combine(const u16* __restrict__ op,
        const float* __restrict__ mp, const float* __restrict__ lp,
        const int* __restrict__ startp, const int* __restrict__ ctxp,
        u16* __restrict__ Af) {
    const int w = threadIdx.x >> 6, lane = threadIdx.x & 63;
    const long row = (long)blockIdx.x * 4 + w;
    const int b = (int)(row >> 13), hq = ((int)row >> 9) & 15, s = (int)row & 511;
    const int start = startp[0];
    int lim = start + s + 1;
    int cx = ctxp[b];
    if (lim > cx) lim = cx;
    float mc[NCALLOC], lc[NCALLOC];
    bool has[NCALLOC];
    float M = -1e30f;
#pragma unroll
    for (int c = 0; c < NCALLOC; ++c) {
        has[c] = (c * CHUNKP < lim);
        if (has[c]) {
            mc[c] = mp[(long)c * TOTROWS + row];
            lc[c] = lp[(long)c * TOTROWS + row];
            if (lc[c] > 0.f && mc[c] > M) M = mc[c];
        }
    }
    const int d0 = lane * 2;
    float Wt = 0.f, a0 = 0.f, a1 = 0.f;
#pragma unroll
    for (int c = 0; c < NCALLOC; ++c) {
        if (has[c] && lc[c] > 0.f) {
            float wg = lc[c] * __expf(mc[c] - M);
            Wt += wg;
            u32 pr = *(const u32*)&op[((long)c * TOTROWS + row) * 128 + d0];
            a0 += wg * bf2f((u16)(pr & 0xFFFF));
            a1 += wg * bf2f((u16)(pr >> 16));
        }
    }
    float inv = 1.0f / Wt;
    u32 pk = (u32)f2bf(a0 * inv) | ((u32)f2bf(a1 * inv) << 16);
    *(u32*)&Af[((long)(b * 512 + s) * 2048) + hq * 128 + d0] = pk;
}

extern "C" void kernel_launch(void* const* d_in, const int* in_sizes, int n_in,
                              void* d_out, int out_size, void* d_ws, size_t ws_size,
                              hipStream_t stream) {
    const float* hidden = (const float*)d_in[0];
    const float* past   = (const float*)d_in[1];
    const float* rope   = (const float*)d_in[2];
    const float* Wq     = (const float*)d_in[3];
    const float* Wk     = (const float*)d_in[4];
    const float* Wv     = (const float*)d_in[5];
    const float* Wo     = (const float*)d_in[6];
    const float* qw     = (const float*)d_in[7];
    const float* kw     = (const float*)d_in[8];
    const int*   ctx    = (const int*)d_in[9];
    const int*   start  = (const int*)d_in[10];

    float* out = (float*)d_out;
    float* present = out + 2097152;
    u16* Kc = (u16*)d_out;   // parked in attn-output region of d_out

    char* wsb = (char*)d_ws;
    u16*   hb    = (u16*)(wsb + 0);
    u16*   Wqkvt = (u16*)(wsb + 4194304);
    float* QKVf  = (float*)(wsb + 16777216);
    u16*   op    = (u16*)(wsb + 0);
    float* mp    = (float*)(wsb + 16777216);
    float* lp    = (float*)(wsb + 17039360);
    u16*   Wot   = (u16*)(wsb + 17301504);   // overlays QKVf -> written AFTER step 4
    u16*   Qn    = (u16*)(wsb + 29360128);
    u16*   Af    = (u16*)(wsb + 29360128);
    u16*   Vtc   = (u16*)(wsb + 33554432);

    prep<<<dim3(2560), dim3(256), 0, stream>>>(hidden, Wq, Wk, Wv, hb, Wqkvt);              // 1
    copy_past2<<<dim3(64, 16), dim3(256), 0, stream>>>(past, present, Kc, Vtc, start, ctx); // 2
    gemm64<<<dim3(48, 16), dim3(256), 0, stream>>>(hb, Wqkvt, QKVf, 1024, 3072, 2048);      // 3
    normrope_v<<<dim3(6208), dim3(256), 0, stream>>>(QKVf, rope, qw, kw, start, present, Qn, Kc, Vtc); // 4
    trans_w<<<dim3(32, 32), dim3(256), 0, stream>>>(Wo, Wot, 2048, 2048, 0);                // 5 (QKVf dead)
    attn<<<dim3(512), dim3(512), 0, stream>>>(Qn, Kc, Vtc, start, ctx, op, mp, lp);         // 6
    combine<<<dim3(4096), dim3(256), 0, stream>>>(op, mp, lp, start, ctx, Af);              // 7
    gemm64<<<dim3(32, 16), dim3(256), 0, stream>>>(Af, Wot, out, 1024, 2048, 2048);         // 8
}

// Round 16
// 120.532 us; speedup vs baseline: 1.9355x; 1.0798x over previous
//
#include <hip/hip_runtime.h>

typedef unsigned short u16;
typedef unsigned int u32;
typedef __attribute__((ext_vector_type(4))) float f32x4;
typedef __attribute__((ext_vector_type(8))) __bf16 bf16x8;
typedef __attribute__((ext_vector_type(8))) unsigned short u16x8;

#define MAXP_ 4096
#define TOTROWS 16384   // B*HQ*S = 2*16*512
#define NCHUNK 4
#define NCALLOC 4
#define CHUNKP 512

__device__ __forceinline__ u16 f2bf(float f) {
    union { float f; u32 u; } x; x.f = f;
    u32 r = x.u + 0x7FFFu + ((x.u >> 16) & 1u);
    return (u16)(r >> 16);
}
__device__ __forceinline__ float bf2f(u16 u) {
    union { u32 u; float f; } x; x.u = ((u32)u) << 16; return x.f;
}
// RNE bf16 pair pack
__device__ __forceinline__ u32 packbf(float lo, float hi) {
    return (u32)f2bf(lo) | ((u32)f2bf(hi) << 16);
}
__device__ __forceinline__ u32 bperm(int addr, u32 src) {
    return (u32)__builtin_amdgcn_ds_bpermute(addr, (int)src);
}

#define GLOAD16(g, l) __builtin_amdgcn_global_load_lds( \
    (const __attribute__((address_space(1))) void*)(g), \
    (__attribute__((address_space(3))) void*)(l), 16, 0, 0)

// ---------------- mega-prep: cvt + Wq/Wk/Wv transpose + past copy/caches [+ Wo transpose] ----------
// grid audit (R14 lesson — every branch's block count vs launch grid):
//   [0,1024)     cvt        1024 blk = 262144 grp / 256 thr   ✓
//   [1024,2048)  Wq trans   1024 blk = 32 n-tiles x 32 k-tiles ✓
//   [2048,2304)  Wk trans    256 blk =  8 x 32                 ✓
//   [2304,2560)  Wv trans    256 blk =  8 x 32                 ✓
//   [2560,3584)  past copy  1024 blk = 16 bkh x 64 p-tiles     ✓
//   [3584,4608)  Wo trans   1024 blk = 32 x 32 (only if grid==4608)
// Fallback (ws<48MB): launch grid 3584 (no Wo branch) and run trans_w separately later.
__global__ __launch_bounds__(256) void prep(const float* __restrict__ hidden,
        const float* __restrict__ Wq, const float* __restrict__ Wk, const float* __restrict__ Wv,
        const float* __restrict__ Wo, const float* __restrict__ past,
        u16* __restrict__ hb, u16* __restrict__ Wqkvt, u16* __restrict__ Wot,
        float* __restrict__ present, u16* __restrict__ Kc, u16* __restrict__ Vtc,
        const int* __restrict__ startp, const int* __restrict__ ctxp) {
    const int bid = blockIdx.x;
    const int t = threadIdx.x;
    if (bid < 1024) {   // cvt: 262144 groups of 8
        int i = bid * 256 + t;
        const float* s = hidden + (long)i * 8;
        f32x4 a = *(const f32x4*)s;
        f32x4 b = *(const f32x4*)(s + 4);
        u16x8 o;
#pragma unroll
        for (int j = 0; j < 4; ++j) { o[j] = f2bf(a[j]); o[4 + j] = f2bf(b[j]); }
        *(u16x8*)&hb[(long)i * 8] = o;
        return;
    }
    if (bid >= 2560 && bid < 3584) {   // past copy + bf16 K / V^T caches
        __shared__ __align__(16) u16 T[128][72];
        const int b2 = bid - 2560;
        const int bkh = b2 >> 6;            // (b*2+kv)*4+h
        const int p0 = (b2 & 63) * 64;
        const int b = bkh >> 3, kv = (bkh >> 2) & 1, h = bkh & 3;
        const int p = t >> 2, d0 = (t & 3) * 32;
        const float* src = past + ((long)bkh * MAXP_ + p0 + p) * 128 + d0;
        float* dst = present + ((long)bkh * MAXP_ + p0 + p) * 128 + d0;
        f32x4 v[8];
#pragma unroll
        for (int j = 0; j < 8; ++j) { v[j] = *(const f32x4*)(src + j * 4); *(f32x4*)(dst + j * 4) = v[j]; }
        int klim = startp[0] + 512;
        int cx = ctxp[b];
        if (klim > cx) klim = cx;
        if (p0 >= klim) return;
        if (kv == 0) {
            u16* kd = Kc + ((long)(b * 4 + h) * MAXP_ + p0 + p) * 128 + d0;
#pragma unroll
            for (int j2 = 0; j2 < 4; ++j2) {
                u16x8 o;
#pragma unroll
                for (int e = 0; e < 4; ++e) { o[e] = f2bf(v[j2 * 2][e]); o[4 + e] = f2bf(v[j2 * 2 + 1][e]); }
                *(u16x8*)&kd[j2 * 8] = o;
            }
        } else {
#pragma unroll
            for (int j = 0; j < 8; ++j)
#pragma unroll
                for (int e = 0; e < 4; ++e)
                    T[d0 + j * 4 + e][p] = f2bf(v[j][e]);
            __syncthreads();
            int d = t >> 1, pc = (t & 1) * 32;
            u16* vd = Vtc + ((long)(b * 4 + h) * 128 + d) * MAXP_ + p0 + pc;
#pragma unroll
            for (int j = 0; j < 4; ++j)
                *(u16x8*)&vd[j * 8] = *(const u16x8*)&T[d][pc + j * 8];
        }
        return;
    }
    // weight transpose branches
    __shared__ __align__(16) u16 T[64][72];
    const float* W; u16* Wdst; int N_w, n_off, n0, k0;
    if (bid < 2048)      { int b2 = bid - 1024; W = Wq; Wdst = Wqkvt; N_w = 2048; n_off = 0;    n0 = (b2 & 31) * 64; k0 = (b2 >> 5) * 64; }
    else if (bid < 2304) { int b2 = bid - 2048; W = Wk; Wdst = Wqkvt; N_w = 512;  n_off = 2048; n0 = (b2 & 7) * 64;  k0 = (b2 >> 3) * 64; }
    else if (bid < 2560) { int b2 = bid - 2304; W = Wv; Wdst = Wqkvt; N_w = 512;  n_off = 2560; n0 = (b2 & 7) * 64;  k0 = (b2 >> 3) * 64; }
    else                 { int b2 = bid - 3584; W = Wo; Wdst = Wot;   N_w = 2048; n_off = 0;    n0 = (b2 & 31) * 64; k0 = (b2 >> 5) * 64; }
    {
        int r = t >> 2, c4 = (t & 3) * 16;
        const float* src = W + (long)(k0 + r) * N_w + n0 + c4;
        f32x4 a0 = *(const f32x4*)src, a1 = *(const f32x4*)(src + 4);
        f32x4 a2 = *(const f32x4*)(src + 8), a3 = *(const f32x4*)(src + 12);
        u16x8 p0, p1;
#pragma unroll
        for (int j = 0; j < 4; ++j) {
            p0[j] = f2bf(a0[j]); p0[4 + j] = f2bf(a1[j]);
            p1[j] = f2bf(a2[j]); p1[4 + j] = f2bf(a3[j]);
        }
        *(u16x8*)&T[r][c4] = p0;
        *(u16x8*)&T[r][c4 + 8] = p1;
    }
    __syncthreads();
    {
        int n = t >> 2, k4 = (t & 3) * 16;
        u16x8 q0, q1;
#pragma unroll
        for (int j = 0; j < 8; ++j) { q0[j] = T[k4 + j][n]; q1[j] = T[k4 + 8 + j][n]; }
        u16* dst = Wdst + (long)(n_off + n0 + n) * 2048 + k0 + k4;
        *(u16x8*)dst = q0;
        *(u16x8*)(dst + 8) = q1;
    }
}

// ---------------- standalone Wo transpose (fallback path only) ----------------
__global__ __launch_bounds__(256) void trans_w(const float* __restrict__ W, u16* __restrict__ Wt,
                                               int N_w, int K, int n_off) {
    __shared__ __align__(16) u16 T[64][72];
    const int t = threadIdx.x;
    const int n0 = blockIdx.x * 64, k0 = blockIdx.y * 64;
    {
        int r = t >> 2, c4 = (t & 3) * 16;
        const float* src = W + (long)(k0 + r) * N_w + n0 + c4;
        f32x4 a0 = *(const f32x4*)src, a1 = *(const f32x4*)(src + 4);
        f32x4 a2 = *(const f32x4*)(src + 8), a3 = *(const f32x4*)(src + 12);
        u16x8 p0, p1;
#pragma unroll
        for (int j = 0; j < 4; ++j) {
            p0[j] = f2bf(a0[j]); p0[4 + j] = f2bf(a1[j]);
            p1[j] = f2bf(a2[j]); p1[4 + j] = f2bf(a3[j]);
        }
        *(u16x8*)&T[r][c4] = p0;
        *(u16x8*)&T[r][c4 + 8] = p1;
    }
    __syncthreads();
    {
        int n = t >> 2, k4 = (t & 3) * 16;
        u16x8 q0, q1;
#pragma unroll
        for (int j = 0; j < 8; ++j) { q0[j] = T[k4 + j][n]; q1[j] = T[k4 + 8 + j][n]; }
        u16* dst = Wt + (long)(n_off + n0 + n) * K + k0 + k4;
        *(u16x8*)dst = q0;
        *(u16x8*)(dst + 8) = q1;
    }
}

// ---------------- bf16 GEMM, A[M][K] @ Bt[N][K]^T -> C[M][N] f32 ----------------
// 64x64 tile, BK=64, dbuf gload_lds + counted vmcnt. 1D grid with XCD-pinned n-ranges (T1):
// xcd=bid&7 owns n-tiles [xcd*npx, (xcd+1)*npx) -> B panels L2-resident. Requires (N/64)%8==0.
__global__ __launch_bounds__(256) void gemm64(const u16* __restrict__ A, const u16* __restrict__ Bt,
                                              float* __restrict__ C, int M, int N, int K) {
    __shared__ __align__(16) u16 As0[4096], Bs0[4096], As1[4096], Bs1[4096];
    const int tid = threadIdx.x, lane = tid & 63, w = tid >> 6;
    const int wm = w >> 1, wn = w & 1;
    const int l15 = lane & 15, g = lane >> 4;
    const int ntile = N >> 6, npx = ntile >> 3;
    const int xcd = blockIdx.x & 7, j_ = blockIdx.x >> 3;
    const int m0 = (j_ / npx) * 64, n0 = (xcd * npx + j_ % npx) * 64;
    f32x4 acc[2][2] = {};

    const int lrow = lane >> 3;
    const int sch = (lane & 7) ^ lrow;
    const int c0 = w, c1 = w + 4;
    const u16* ga0 = A + (long)(m0 + c0 * 8 + lrow) * K + sch * 8;
    const u16* ga1 = A + (long)(m0 + c1 * 8 + lrow) * K + sch * 8;
    const u16* gb0 = Bt + (long)(n0 + c0 * 8 + lrow) * K + sch * 8;
    const u16* gb1 = Bt + (long)(n0 + c1 * 8 + lrow) * K + sch * 8;
    const int ra = wm * 32, rb = wn * 32;
    const int h7 = l15 & 7;

#define STAGE_T(koff, AS_, BS_) do { \
        GLOAD16(ga0 + (koff), &AS_[c0 * 512]); \
        GLOAD16(ga1 + (koff), &AS_[c1 * 512]); \
        GLOAD16(gb0 + (koff), &BS_[c0 * 512]); \
        GLOAD16(gb1 + (koff), &BS_[c1 * 512]); \
    } while (0)

    auto compute = [&](const u16* as_, const u16* bs_) {
        bf16x8 af[2][2], bfr[2][2];
#pragma unroll
        for (int i = 0; i < 2; ++i) {
            int rr = ra + i * 16 + l15;
#pragma unroll
            for (int kk = 0; kk < 2; ++kk)
                af[i][kk] = *(const bf16x8*)&as_[rr * 64 + (((kk * 4 + g) ^ h7) * 8)];
        }
#pragma unroll
        for (int j2 = 0; j2 < 2; ++j2) {
            int rr = rb + j2 * 16 + l15;
#pragma unroll
            for (int kk = 0; kk < 2; ++kk)
                bfr[j2][kk] = *(const bf16x8*)&bs_[rr * 64 + (((kk * 4 + g) ^ h7) * 8)];
        }
#pragma unroll
        for (int i = 0; i < 2; ++i)
#pragma unroll
            for (int j2 = 0; j2 < 2; ++j2) {
                acc[i][j2] = __builtin_amdgcn_mfma_f32_16x16x32_bf16(af[i][0], bfr[j2][0], acc[i][j2], 0, 0, 0);
                acc[i][j2] = __builtin_amdgcn_mfma_f32_16x16x32_bf16(af[i][1], bfr[j2][1], acc[i][j2], 0, 0, 0);
            }
    };

    STAGE_T(0, As0, Bs0);
    for (int k0 = 0; k0 < K; k0 += 128) {
        STAGE_T(k0 + 64, As1, Bs1);
        asm volatile("s_waitcnt vmcnt(4)" ::: "memory");
        __builtin_amdgcn_s_barrier();
        __builtin_amdgcn_sched_barrier(0);
        compute(As0, Bs0);
        __builtin_amdgcn_s_barrier();
        if (k0 + 128 < K) {
            STAGE_T(k0 + 128, As0, Bs0);
            asm volatile("s_waitcnt vmcnt(4)" ::: "memory");
        } else {
            asm volatile("s_waitcnt vmcnt(0)" ::: "memory");
        }
        __builtin_amdgcn_s_barrier();
        __builtin_amdgcn_sched_barrier(0);
        compute(As1, Bs1);
        __builtin_amdgcn_s_barrier();
    }
#undef STAGE_T

#pragma unroll
    for (int i = 0; i < 2; ++i)
#pragma unroll
        for (int j2 = 0; j2 < 2; ++j2)
#pragma unroll
            for (int r = 0; r < 4; ++r)
                C[(long)(m0 + ra + i * 16 + g * 4 + r) * N + n0 + rb + j2 * 16 + l15] = acc[i][j2][r];
}

// ---------------- fused RMS norm + RoPE + cache scatter + new-V transpose ----------------
// grid 6208: [0,6144) normrope (wid = bid*4 + wave); [6144,6208) vtrans (64 blocks = 8 s0 x 8 bh).
__global__ __launch_bounds__(256) void normrope_v(const float* __restrict__ QKVf,
        const float* __restrict__ rope,
        const float* __restrict__ qw, const float* __restrict__ kw,
        const int* __restrict__ startp, float* __restrict__ present,
        u16* __restrict__ Qn, u16* __restrict__ Kc, u16* __restrict__ Vtc) {
    const int bid = blockIdx.x;
    const int start = startp[0];
    if (bid < 6144) {
        const int wid = bid * 4 + (threadIdx.x >> 6);
        const int lane = threadIdx.x & 63;
        if (wid < 16384) { // Q: 1024 rows x 16 heads
            int row = wid >> 4, h = wid & 15;
            int b = row >> 9, s = row & 511;
            const float* src = QKVf + (long)row * 3072 + h * 128;
            float x1 = src[lane], x2 = src[64 + lane];
            float v = x1 * x1 + x2 * x2;
#pragma unroll
            for (int off = 32; off; off >>= 1) v += __shfl_xor(v, off, 64);
            float sc = rsqrtf(v * (1.0f / 128.0f) + 1e-6f);
            float y1 = x1 * sc * qw[lane], y2 = x2 * sc * qw[64 + lane];
            float c = rope[(long)row * 128 + lane], sn = rope[(long)row * 128 + 64 + lane];
            u16* dst = Qn + (((long)(b * 16 + h) * 512 + s) * 128);
            dst[lane] = f2bf(y1 * c - y2 * sn);
            dst[64 + lane] = f2bf(y2 * c + y1 * sn);
        } else if (wid < 20480) { // K: 1024 rows x 4 heads
            int j = wid - 16384;
            int row = j >> 2, h = j & 3;
            int b = row >> 9, s = row & 511;
            const float* src = QKVf + (long)row * 3072 + 2048 + h * 128;
            float x1 = src[lane], x2 = src[64 + lane];
            float v = x1 * x1 + x2 * x2;
#pragma unroll
            for (int off = 32; off; off >>= 1) v += __shfl_xor(v, off, 64);
            float sc = rsqrtf(v * (1.0f / 128.0f) + 1e-6f);
            float y1 = x1 * sc * kw[lane], y2 = x2 * sc * kw[64 + lane];
            float c = rope[(long)row * 128 + lane], sn = rope[(long)row * 128 + 64 + lane];
            float k1 = y1 * c - y2 * sn, k2 = y2 * c + y1 * sn;
            float* dst = present + (((long)(b * 2 + 0) * 4 + h) * MAXP_ + (start + s)) * 128;
            dst[lane] = k1; dst[64 + lane] = k2;
            u16* kc = Kc + (((long)(b * 4 + h)) * MAXP_ + start + s) * 128;
            kc[lane] = f2bf(k1); kc[64 + lane] = f2bf(k2);
        } else if (wid < 24576) { // V: present copy only
            int j = wid - 20480;
            int row = j >> 2, h = j & 3;
            int b = row >> 9, s = row & 511;
            const float* src = QKVf + (long)row * 3072 + 2560 + h * 128;
            float* dst = present + (((long)(b * 2 + 1) * 4 + h) * MAXP_ + (start + s)) * 128;
            dst[lane] = src[lane];
            dst[64 + lane] = src[64 + lane];
        }
        return;
    }
    // vtrans: new V -> Vtc bf16 [d][p]
    __shared__ __align__(16) u16 T[128][72];
    const int t = threadIdx.x;
    const int b2 = bid - 6144;
    const int s0 = (b2 & 7) * 64;
    const int bh = b2 >> 3, b = bh >> 2, h = bh & 3;
    const int sr = t >> 2, d0 = (t & 3) * 32;
    const float* src = QKVf + (long)(b * 512 + s0 + sr) * 3072 + 2560 + h * 128 + d0;
#pragma unroll
    for (int j = 0; j < 8; ++j) {
        f32x4 v = *(const f32x4*)(src + j * 4);
#pragma unroll
        for (int e = 0; e < 4; ++e) T[d0 + j * 4 + e][sr] = f2bf(v[e]);
    }
    __syncthreads();
    const int d = t >> 1, pc = (t & 1) * 32;
    u16* dst = Vtc + ((long)(b * 4 + h) * 128 + d) * MAXP_ + start + s0 + pc;
#pragma unroll
    for (int k = 0; k < 32; ++k) dst[k] = T[d][pc + k];  // scalar: start may be unaligned
}

// ---------------- flash attention: LDS-staged K/V, 8 waves, XCD-pinned, defer-max ----------------
// R15 attn VERBATIM (proven: attn < 39 us). 512 blocks x 512 threads.
__global__ __launch_bounds__(512, 4) void attn(const u16* __restrict__ Qn,
        const u16* __restrict__ Kc, const u16* __restrict__ Vtc,
        const int* __restrict__ startp, const int* __restrict__ ctxp,
        u16* __restrict__ op, float* __restrict__ mp, float* __restrict__ lp) {
    __shared__ __align__(16) char KsB[2][16384];   // [buf][64 rows x 256B]
    __shared__ __align__(16) char VsB[2][16384];   // [buf][128 rows x 128B]
    const int tid = threadIdx.x, lane = tid & 63, w = tid >> 6;
    const int l15 = lane & 15, g = lane >> 4;
    const bool ghi = (g >= 2);
    const int id = blockIdx.x;
    const int bh = id & 7;
    const int rest = id >> 3;
    const int c = rest >> 4;
    const int q0 = (rest & 15) * 32;
    const int b = bh >> 2, hkv = bh & 3;
    const int hd = w & 3, qh = w >> 2;
    const int hq = hkv * 4 + hd;
    const int start = startp[0];
    const int ctx = ctxp[b];

    int lim_blk = start + q0 + 32;
    if (lim_blk > ctx) lim_blk = ctx;
    const int pbeg = c * CHUNKP;
    int pend = pbeg + CHUNKP;
    if (pend > lim_blk) pend = lim_blk;
    if (pbeg >= pend) return;               // block-uniform (before any barrier)

    const int qrow0 = q0 + qh * 16;
    const long rowbase = (long)(b * 16 + hq) * 512 + qrow0;

    bf16x8 qb[4];
    {
        const u16* qp = Qn + (rowbase + l15) * 128 + g * 8;
#pragma unroll
        for (int kf = 0; kf < 4; ++kf)
            qb[kf] = *(const bf16x8*)(qp + kf * 32);
    }

    const char* kb8 = (const char*)(Kc + (long)bh * (MAXP_ * 128));
    const char* vb8 = (const char*)(Vtc + (long)bh * (128 * MAXP_));

    const int wbase = (tid & ~63) * 16;
    auto STAGE = [&](int buf, int p0_) {
#pragma unroll
        for (int r = 0; r < 2; ++r) {
            int o_ = r * 8192 + tid * 16;
            int row = o_ >> 8;
            int colb = (o_ & 255) ^ ((row & 7) << 4);
            GLOAD16(kb8 + (long)(p0_ + row) * 256 + colb, &KsB[buf][r * 8192 + wbase]);
        }
#pragma unroll
        for (int r = 0; r < 2; ++r) {
            int o_ = r * 8192 + tid * 16;
            int row = o_ >> 7;
            int colb = (o_ & 127) ^ ((row & 7) << 4);
            GLOAD16(vb8 + (long)row * (MAXP_ * 2) + (long)p0_ * 2 + colb, &VsB[buf][r * 8192 + wbase]);
        }
    };

    f32x4 o[8] = {};
    float m_run = -1e30f, l_run = 0.f;
    int limq = start + qrow0 + l15 + 1;
    if (limq > ctx) limq = ctx;
    if (limq > pend) limq = pend;
    const int addrA = (l15 + ((g & 1) << 5)) << 2;
    const int addrB = addrA + 64;
    const float scale = 0.08838834764831845f;
    const int swz = (l15 & 7) << 4;

    const int t0 = pbeg >> 6, t1 = (pend + 63) >> 6;
    STAGE(0, t0 * 64);
    asm volatile("s_waitcnt vmcnt(0)" ::: "memory");
    __builtin_amdgcn_s_barrier();
    int cur = 0;
    for (int t = t0; t < t1; ++t) {
        const int p0 = t * 64;
        if (t + 1 < t1) STAGE(cur ^ 1, p0 + 64);
        f32x4 sacc[4] = {};
#pragma unroll
        for (int kt = 0; kt < 4; ++kt) {
            const char* krow = &KsB[cur][(kt * 16 + l15) * 256];
#pragma unroll
            for (int kf = 0; kf < 4; ++kf) {
                bf16x8 ka = *(const bf16x8*)(krow + ((kf * 64 + g * 16) ^ swz));
                sacc[kt] = __builtin_amdgcn_mfma_f32_16x16x32_bf16(ka, qb[kf], sacc[kt], 0, 0, 0);
            }
        }
        float mx = -1e30f;
#pragma unroll
        for (int kt = 0; kt < 4; ++kt)
#pragma unroll
            for (int r = 0; r < 4; ++r) {
                int key = p0 + kt * 16 + g * 4 + r;
                float x = (key < limq) ? sacc[kt][r] * scale : -1e30f;
                sacc[kt][r] = x;
                mx = fmaxf(mx, x);
            }
        mx = fmaxf(mx, __shfl_xor(mx, 16, 64));
        mx = fmaxf(mx, __shfl_xor(mx, 32, 64));
        if (!__all(mx <= m_run + 8.f)) {
            float mnew = fmaxf(m_run, mx);
            float alpha = __expf(m_run - mnew);
            m_run = mnew;
            l_run *= alpha;
            f32x4 av;
#pragma unroll
            for (int r = 0; r < 4; ++r) av[r] = __shfl(alpha, g * 4 + r, 64);
#pragma unroll
            for (int df = 0; df < 8; ++df) {
                o[df][0] *= av[0]; o[df][1] *= av[1];
                o[df][2] *= av[2]; o[df][3] *= av[3];
            }
        }
        const float mb = m_run;
        float rs = 0.f;
        u32 w0[4], w1[4];
#pragma unroll
        for (int kt = 0; kt < 4; ++kt) {
#pragma unroll
            for (int r = 0; r < 4; ++r) {
                float p = __expf(sacc[kt][r] - mb);
                sacc[kt][r] = p;
                rs += p;
            }
            w0[kt] = packbf(sacc[kt][0], sacc[kt][1]);
            w1[kt] = packbf(sacc[kt][2], sacc[kt][3]);
        }
        rs += __shfl_xor(rs, 16, 64);
        rs += __shfl_xor(rs, 32, 64);
        l_run += rs;
#pragma unroll
        for (int ks = 0; ks < 2; ++ks) {
            const int sL = 2 * ks, sH = 2 * ks + 1;
            u32 d0 = ghi ? bperm(addrA, w0[sH]) : bperm(addrA, w0[sL]);
            u32 d1 = ghi ? bperm(addrA, w1[sH]) : bperm(addrA, w1[sL]);
            u32 d2 = ghi ? bperm(addrB, w0[sH]) : bperm(addrB, w0[sL]);
            u32 d3 = ghi ? bperm(addrB, w1[sH]) : bperm(addrB, w1[sL]);
            union { u32 d[4]; bf16x8 v; } pu;
            pu.d[0] = d0; pu.d[1] = d1; pu.d[2] = d2; pu.d[3] = d3;
            bf16x8 pa = pu.v;
#pragma unroll
            for (int df = 0; df < 8; ++df) {
                const char* vrow = &VsB[cur][(df * 16 + l15) * 128];
                bf16x8 vb = *(const bf16x8*)(vrow + ((ks * 64 + g * 16) ^ swz));
                o[df] = __builtin_amdgcn_mfma_f32_16x16x32_bf16(pa, vb, o[df], 0, 0, 0);
            }
        }
        asm volatile("s_waitcnt vmcnt(0)" ::: "memory");
        __builtin_amdgcn_s_barrier();
        cur ^= 1;
    }
    {
        float invl = l_run > 0.f ? 1.0f / l_run : 0.f;
        f32x4 iv;
#pragma unroll
        for (int r = 0; r < 4; ++r) iv[r] = __shfl(invl, g * 4 + r, 64);
        u16* dst = op + ((long)c * TOTROWS + rowbase + g * 4) * 128 + l15;
#pragma unroll
        for (int r = 0; r < 4; ++r)
#pragma unroll
            for (int df = 0; df < 8; ++df)
                dst[(long)r * 128 + df * 16] = f2bf(o[df][r] * iv[r]);
        if (g == 0) {
            mp[(long)c * TOTROWS + rowbase + l15] = m_run;
            lp[(long)c * TOTROWS + rowbase + l15] = l_run;
        }
    }
}

// ---------------- combine split-KV partials -> Af bf16 [b*512+s][2048] ----------------
__global__ __launch_bounds__(256) void combine(const u16* __restrict__ op,
        const float* __restrict__ mp, const float* __restrict__ lp,
        const int* __restrict__ startp, const int* __restrict__ ctxp,
        u16* __restrict__ Af) {
    const int w = threadIdx.x >> 6, lane = threadIdx.x & 63;
    const long row = (long)blockIdx.x * 4 + w;
    const int b = (int)(row >> 13), hq = ((int)row >> 9) & 15, s = (int)row & 511;
    const int start = startp[0];
    int lim = start + s + 1;
    int cx = ctxp[b];
    if (lim > cx) lim = cx;
    float mc[NCALLOC], lc[NCALLOC];
    bool has[NCALLOC];
    float M = -1e30f;
#pragma unroll
    for (int c = 0; c < NCALLOC; ++c) {
        has[c] = (c * CHUNKP < lim);
        if (has[c]) {
            mc[c] = mp[(long)c * TOTROWS + row];
            lc[c] = lp[(long)c * TOTROWS + row];
            if (lc[c] > 0.f && mc[c] > M) M = mc[c];
        }
    }
    const int d0 = lane * 2;
    float Wt = 0.f, a0 = 0.f, a1 = 0.f;
#pragma unroll
    for (int c = 0; c < NCALLOC; ++c) {
        if (has[c] && lc[c] > 0.f) {
            float wg = lc[c] * __expf(mc[c] - M);
            Wt += wg;
            u32 pr = *(const u32*)&op[((long)c * TOTROWS + row) * 128 + d0];
            a0 += wg * bf2f((u16)(pr & 0xFFFF));
            a1 += wg * bf2f((u16)(pr >> 16));
        }
    }
    float inv = 1.0f / Wt;
    u32 pk = (u32)f2bf(a0 * inv) | ((u32)f2bf(a1 * inv) << 16);
    *(u32*)&Af[((long)(b * 512 + s) * 2048) + hq * 128 + d0] = pk;
}

extern "C" void kernel_launch(void* const* d_in, const int* in_sizes, int n_in,
                              void* d_out, int out_size, void* d_ws, size_t ws_size,
                              hipStream_t stream) {
    const float* hidden = (const float*)d_in[0];
    const float* past   = (const float*)d_in[1];
    const float* rope   = (const float*)d_in[2];
    const float* Wq     = (const float*)d_in[3];
    const float* Wk     = (const float*)d_in[4];
    const float* Wv     = (const float*)d_in[5];
    const float* Wo     = (const float*)d_in[6];
    const float* qw     = (const float*)d_in[7];
    const float* kw     = (const float*)d_in[8];
    const int*   ctx    = (const int*)d_in[9];
    const int*   start  = (const int*)d_in[10];

    float* out = (float*)d_out;
    float* present = out + 2097152;
    u16* Kc = (u16*)d_out;   // parked in attn-output region of d_out

    char* wsb = (char*)d_ws;
    u16*   hb    = (u16*)(wsb + 0);
    u16*   Wqkvt = (u16*)(wsb + 4194304);
    float* QKVf  = (float*)(wsb + 16777216);
    u16*   op    = (u16*)(wsb + 0);
    float* mp    = (float*)(wsb + 16777216);
    float* lp    = (float*)(wsb + 17039360);
    u16*   Qn    = (u16*)(wsb + 29360128);
    u16*   Af    = (u16*)(wsb + 29360128);
    u16*   Vtc   = (u16*)(wsb + 33554432);
    const bool bigws = (ws_size >= 50331648ull);   // 48 MiB
    // preferred: Wot at [40M,48M) (independent of QKVf -> Wo transpose fuses into prep)
    // fallback:  Wot overlays QKVf tail [16.5M,24.5M) -> must transpose AFTER normrope_v
    u16* Wot = bigws ? (u16*)(wsb + 41943040) : (u16*)(wsb + 17301504);

    if (bigws) {
        prep<<<dim3(4608), dim3(256), 0, stream>>>(hidden, Wq, Wk, Wv, Wo, past,
                hb, Wqkvt, Wot, present, Kc, Vtc, start, ctx);                              // 1
        gemm64<<<dim3(768), dim3(256), 0, stream>>>(hb, Wqkvt, QKVf, 1024, 3072, 2048);     // 2
        normrope_v<<<dim3(6208), dim3(256), 0, stream>>>(QKVf, rope, qw, kw, start, present, Qn, Kc, Vtc); // 3
        attn<<<dim3(512), dim3(512), 0, stream>>>(Qn, Kc, Vtc, start, ctx, op, mp, lp);     // 4
        combine<<<dim3(4096), dim3(256), 0, stream>>>(op, mp, lp, start, ctx, Af);          // 5
        gemm64<<<dim3(512), dim3(256), 0, stream>>>(Af, Wot, out, 1024, 2048, 2048);        // 6
    } else {
        prep<<<dim3(3584), dim3(256), 0, stream>>>(hidden, Wq, Wk, Wv, Wo, past,
                hb, Wqkvt, Wot, present, Kc, Vtc, start, ctx);                              // 1 (no Wo branch)
        gemm64<<<dim3(768), dim3(256), 0, stream>>>(hb, Wqkvt, QKVf, 1024, 3072, 2048);     // 2
        normrope_v<<<dim3(6208), dim3(256), 0, stream>>>(QKVf, rope, qw, kw, start, present, Qn, Kc, Vtc); // 3
        trans_w<<<dim3(32, 32), dim3(256), 0, stream>>>(Wo, Wot, 2048, 2048, 0);            // 4 (QKVf dead)
        attn<<<dim3(512), dim3(512), 0, stream>>>(Qn, Kc, Vtc, start, ctx, op, mp, lp);     // 5
        combine<<<dim3(4096), dim3(256), 0, stream>>>(op, mp, lp, start, ctx, Af);          // 6
        gemm64<<<dim3(512), dim3(256), 0, stream>>>(Af, Wot, out, 1024, 2048, 2048);        // 7
    }
}

// Round 17
// 119.338 us; speedup vs baseline: 1.9548x; 1.0100x over previous
//
#include <hip/hip_runtime.h>

typedef unsigned short u16;
typedef unsigned int u32;
typedef __attribute__((ext_vector_type(4))) float f32x4;
typedef __attribute__((ext_vector_type(8))) __bf16 bf16x8;
typedef __attribute__((ext_vector_type(8))) unsigned short u16x8;

#define MAXP_ 4096
#define TOTROWS 16384   // B*HQ*S = 2*16*512
#define NCHUNK 4
#define NCALLOC 4
#define CHUNKP 512

__device__ __forceinline__ u16 f2bf(float f) {
    union { float f; u32 u; } x; x.f = f;
    u32 r = x.u + 0x7FFFu + ((x.u >> 16) & 1u);
    return (u16)(r >> 16);
}
__device__ __forceinline__ float bf2f(u16 u) {
    union { u32 u; float f; } x; x.u = ((u32)u) << 16; return x.f;
}
// RNE bf16 pair pack
__device__ __forceinline__ u32 packbf(float lo, float hi) {
    return (u32)f2bf(lo) | ((u32)f2bf(hi) << 16);
}
__device__ __forceinline__ u32 bperm(int addr, u32 src) {
    return (u32)__builtin_amdgcn_ds_bpermute(addr, (int)src);
}

#define GLOAD16(g, l) __builtin_amdgcn_global_load_lds( \
    (const __attribute__((address_space(1))) void*)(g), \
    (__attribute__((address_space(3))) void*)(l), 16, 0, 0)

// ---------------- mega-prep: cvt + Wq/Wk/Wv transpose + K/V bf16 caches [+ Wo transpose] ----------
// (past->present copy moved to hipMemcpyAsync; prep's past branch now only builds Kc/Vtc.)
// grid audit (R14 lesson — every branch's block count vs launch grid):
//   [0,1024)     cvt         1024 blk = 262144 grp / 256 thr    ✓
//   [1024,2048)  Wq trans    1024 blk = 32 n-tiles x 32 k-tiles ✓
//   [2048,2304)  Wk trans     256 blk =  8 x 32                 ✓
//   [2304,2560)  Wv trans     256 blk =  8 x 32                 ✓
//   [2560,3584)  K/V caches  1024 blk = 16 bkh x 64 p-tiles (p0>=klim exits immediately) ✓
//   [3584,4608)  Wo trans    1024 blk = 32 x 32 (only if grid==4608)
// Single unioned LDS T[128][72] (18.4KB) -> 8 blocks/CU (R16 had 27.6KB -> 38% occupancy).
__global__ __launch_bounds__(256) void prep(const float* __restrict__ hidden,
        const float* __restrict__ Wq, const float* __restrict__ Wk, const float* __restrict__ Wv,
        const float* __restrict__ Wo, const float* __restrict__ past,
        u16* __restrict__ hb, u16* __restrict__ Wqkvt, u16* __restrict__ Wot,
        u16* __restrict__ Kc, u16* __restrict__ Vtc,
        const int* __restrict__ startp, const int* __restrict__ ctxp) {
    __shared__ __align__(16) u16 T[128][72];
    const int bid = blockIdx.x;
    const int t = threadIdx.x;
    if (bid < 1024) {   // cvt: 262144 groups of 8
        int i = bid * 256 + t;
        const float* s = hidden + (long)i * 8;
        f32x4 a = *(const f32x4*)s;
        f32x4 b = *(const f32x4*)(s + 4);
        u16x8 o;
#pragma unroll
        for (int j = 0; j < 4; ++j) { o[j] = f2bf(a[j]); o[4 + j] = f2bf(b[j]); }
        *(u16x8*)&hb[(long)i * 8] = o;
        return;
    }
    if (bid >= 2560 && bid < 3584) {   // bf16 K / V^T caches from past (copy handled by memcpy)
        const int b2 = bid - 2560;
        const int bkh = b2 >> 6;            // (b*2+kv)*4+h
        const int p0 = (b2 & 63) * 64;
        const int b = bkh >> 3, kv = (bkh >> 2) & 1, h = bkh & 3;
        int klim = startp[0] + 512;
        int cx = ctxp[b];
        if (klim > cx) klim = cx;
        if (p0 >= klim) return;             // block-uniform
        const int p = t >> 2, d0 = (t & 3) * 32;
        const float* src = past + ((long)bkh * MAXP_ + p0 + p) * 128 + d0;
        f32x4 v[8];
#pragma unroll
        for (int j = 0; j < 8; ++j) v[j] = *(const f32x4*)(src + j * 4);
        if (kv == 0) {
            u16* kd = Kc + ((long)(b * 4 + h) * MAXP_ + p0 + p) * 128 + d0;
#pragma unroll
            for (int j2 = 0; j2 < 4; ++j2) {
                u16x8 o;
#pragma unroll
                for (int e = 0; e < 4; ++e) { o[e] = f2bf(v[j2 * 2][e]); o[4 + e] = f2bf(v[j2 * 2 + 1][e]); }
                *(u16x8*)&kd[j2 * 8] = o;
            }
        } else {
#pragma unroll
            for (int j = 0; j < 8; ++j)
#pragma unroll
                for (int e = 0; e < 4; ++e)
                    T[d0 + j * 4 + e][p] = f2bf(v[j][e]);
            __syncthreads();
            int d = t >> 1, pc = (t & 1) * 32;
            u16* vd = Vtc + ((long)(b * 4 + h) * 128 + d) * MAXP_ + p0 + pc;
#pragma unroll
            for (int j = 0; j < 4; ++j)
                *(u16x8*)&vd[j * 8] = *(const u16x8*)&T[d][pc + j * 8];
        }
        return;
    }
    // weight transpose branches (use rows [0,64) of T)
    const float* W; u16* Wdst; int N_w, n_off, n0, k0;
    if (bid < 2048)      { int b2 = bid - 1024; W = Wq; Wdst = Wqkvt; N_w = 2048; n_off = 0;    n0 = (b2 & 31) * 64; k0 = (b2 >> 5) * 64; }
    else if (bid < 2304) { int b2 = bid - 2048; W = Wk; Wdst = Wqkvt; N_w = 512;  n_off = 2048; n0 = (b2 & 7) * 64;  k0 = (b2 >> 3) * 64; }
    else if (bid < 2560) { int b2 = bid - 2304; W = Wv; Wdst = Wqkvt; N_w = 512;  n_off = 2560; n0 = (b2 & 7) * 64;  k0 = (b2 >> 3) * 64; }
    else                 { int b2 = bid - 3584; W = Wo; Wdst = Wot;   N_w = 2048; n_off = 0;    n0 = (b2 & 31) * 64; k0 = (b2 >> 5) * 64; }
    {
        int r = t >> 2, c4 = (t & 3) * 16;
        const float* src = W + (long)(k0 + r) * N_w + n0 + c4;
        f32x4 a0 = *(const f32x4*)src, a1 = *(const f32x4*)(src + 4);
        f32x4 a2 = *(const f32x4*)(src + 8), a3 = *(const f32x4*)(src + 12);
        u16x8 p0, p1;
#pragma unroll
        for (int j = 0; j < 4; ++j) {
            p0[j] = f2bf(a0[j]); p0[4 + j] = f2bf(a1[j]);
            p1[j] = f2bf(a2[j]); p1[4 + j] = f2bf(a3[j]);
        }
        *(u16x8*)&T[r][c4] = p0;
        *(u16x8*)&T[r][c4 + 8] = p1;
    }
    __syncthreads();
    {
        int n = t >> 2, k4 = (t & 3) * 16;
        u16x8 q0, q1;
#pragma unroll
        for (int j = 0; j < 8; ++j) { q0[j] = T[k4 + j][n]; q1[j] = T[k4 + 8 + j][n]; }
        u16* dst = Wdst + (long)(n_off + n0 + n) * 2048 + k0 + k4;
        *(u16x8*)dst = q0;
        *(u16x8*)(dst + 8) = q1;
    }
}

// ---------------- standalone Wo transpose (fallback path only) ----------------
__global__ __launch_bounds__(256) void trans_w(const float* __restrict__ W, u16* __restrict__ Wt,
                                               int N_w, int K, int n_off) {
    __shared__ __align__(16) u16 T[64][72];
    const int t = threadIdx.x;
    const int n0 = blockIdx.x * 64, k0 = blockIdx.y * 64;
    {
        int r = t >> 2, c4 = (t & 3) * 16;
        const float* src = W + (long)(k0 + r) * N_w + n0 + c4;
        f32x4 a0 = *(const f32x4*)src, a1 = *(const f32x4*)(src + 4);
        f32x4 a2 = *(const f32x4*)(src + 8), a3 = *(const f32x4*)(src + 12);
        u16x8 p0, p1;
#pragma unroll
        for (int j = 0; j < 4; ++j) {
            p0[j] = f2bf(a0[j]); p0[4 + j] = f2bf(a1[j]);
            p1[j] = f2bf(a2[j]); p1[4 + j] = f2bf(a3[j]);
        }
        *(u16x8*)&T[r][c4] = p0;
        *(u16x8*)&T[r][c4 + 8] = p1;
    }
    __syncthreads();
    {
        int n = t >> 2, k4 = (t & 3) * 16;
        u16x8 q0, q1;
#pragma unroll
        for (int j = 0; j < 8; ++j) { q0[j] = T[k4 + j][n]; q1[j] = T[k4 + 8 + j][n]; }
        u16* dst = Wt + (long)(n_off + n0 + n) * K + k0 + k4;
        *(u16x8*)dst = q0;
        *(u16x8*)(dst + 8) = q1;
    }
}

// ---------------- bf16 GEMM, A[M][K] @ Bt[N][K]^T -> C[M][N] f32 ----------------
// 64x64 tile, BK=64, dbuf gload_lds + counted vmcnt. 1D grid with XCD-pinned n-ranges (T1).
__global__ __launch_bounds__(256) void gemm64(const u16* __restrict__ A, const u16* __restrict__ Bt,
                                              float* __restrict__ C, int M, int N, int K) {
    __shared__ __align__(16) u16 As0[4096], Bs0[4096], As1[4096], Bs1[4096];
    const int tid = threadIdx.x, lane = tid & 63, w = tid >> 6;
    const int wm = w >> 1, wn = w & 1;
    const int l15 = lane & 15, g = lane >> 4;
    const int ntile = N >> 6, npx = ntile >> 3;
    const int xcd = blockIdx.x & 7, j_ = blockIdx.x >> 3;
    const int m0 = (j_ / npx) * 64, n0 = (xcd * npx + j_ % npx) * 64;
    f32x4 acc[2][2] = {};

    const int lrow = lane >> 3;
    const int sch = (lane & 7) ^ lrow;
    const int c0 = w, c1 = w + 4;
    const u16* ga0 = A + (long)(m0 + c0 * 8 + lrow) * K + sch * 8;
    const u16* ga1 = A + (long)(m0 + c1 * 8 + lrow) * K + sch * 8;
    const u16* gb0 = Bt + (long)(n0 + c0 * 8 + lrow) * K + sch * 8;
    const u16* gb1 = Bt + (long)(n0 + c1 * 8 + lrow) * K + sch * 8;
    const int ra = wm * 32, rb = wn * 32;
    const int h7 = l15 & 7;

#define STAGE_T(koff, AS_, BS_) do { \
        GLOAD16(ga0 + (koff), &AS_[c0 * 512]); \
        GLOAD16(ga1 + (koff), &AS_[c1 * 512]); \
        GLOAD16(gb0 + (koff), &BS_[c0 * 512]); \
        GLOAD16(gb1 + (koff), &BS_[c1 * 512]); \
    } while (0)

    auto compute = [&](const u16* as_, const u16* bs_) {
        bf16x8 af[2][2], bfr[2][2];
#pragma unroll
        for (int i = 0; i < 2; ++i) {
            int rr = ra + i * 16 + l15;
#pragma unroll
            for (int kk = 0; kk < 2; ++kk)
                af[i][kk] = *(const bf16x8*)&as_[rr * 64 + (((kk * 4 + g) ^ h7) * 8)];
        }
#pragma unroll
        for (int j2 = 0; j2 < 2; ++j2) {
            int rr = rb + j2 * 16 + l15;
#pragma unroll
            for (int kk = 0; kk < 2; ++kk)
                bfr[j2][kk] = *(const bf16x8*)&bs_[rr * 64 + (((kk * 4 + g) ^ h7) * 8)];
        }
#pragma unroll
        for (int i = 0; i < 2; ++i)
#pragma unroll
            for (int j2 = 0; j2 < 2; ++j2) {
                acc[i][j2] = __builtin_amdgcn_mfma_f32_16x16x32_bf16(af[i][0], bfr[j2][0], acc[i][j2], 0, 0, 0);
                acc[i][j2] = __builtin_amdgcn_mfma_f32_16x16x32_bf16(af[i][1], bfr[j2][1], acc[i][j2], 0, 0, 0);
            }
    };

    STAGE_T(0, As0, Bs0);
    for (int k0 = 0; k0 < K; k0 += 128) {
        STAGE_T(k0 + 64, As1, Bs1);
        asm volatile("s_waitcnt vmcnt(4)" ::: "memory");
        __builtin_amdgcn_s_barrier();
        __builtin_amdgcn_sched_barrier(0);
        compute(As0, Bs0);
        __builtin_amdgcn_s_barrier();
        if (k0 + 128 < K) {
            STAGE_T(k0 + 128, As0, Bs0);
            asm volatile("s_waitcnt vmcnt(4)" ::: "memory");
        } else {
            asm volatile("s_waitcnt vmcnt(0)" ::: "memory");
        }
        __builtin_amdgcn_s_barrier();
        __builtin_amdgcn_sched_barrier(0);
        compute(As1, Bs1);
        __builtin_amdgcn_s_barrier();
    }
#undef STAGE_T

#pragma unroll
    for (int i = 0; i < 2; ++i)
#pragma unroll
        for (int j2 = 0; j2 < 2; ++j2)
#pragma unroll
            for (int r = 0; r < 4; ++r)
                C[(long)(m0 + ra + i * 16 + g * 4 + r) * N + n0 + rb + j2 * 16 + l15] = acc[i][j2][r];
}

// ---------------- fused RMS norm + RoPE + cache scatter + new-V transpose ----------------
__global__ __launch_bounds__(256) void normrope_v(const float* __restrict__ QKVf,
        const float* __restrict__ rope,
        const float* __restrict__ qw, const float* __restrict__ kw,
        const int* __restrict__ startp, float* __restrict__ present,
        u16* __restrict__ Qn, u16* __restrict__ Kc, u16* __restrict__ Vtc) {
    const int bid = blockIdx.x;
    const int start = startp[0];
    if (bid < 6144) {
        const int wid = bid * 4 + (threadIdx.x >> 6);
        const int lane = threadIdx.x & 63;
        if (wid < 16384) { // Q: 1024 rows x 16 heads
            int row = wid >> 4, h = wid & 15;
            int b = row >> 9, s = row & 511;
            const float* src = QKVf + (long)row * 3072 + h * 128;
            float x1 = src[lane], x2 = src[64 + lane];
            float v = x1 * x1 + x2 * x2;
#pragma unroll
            for (int off = 32; off; off >>= 1) v += __shfl_xor(v, off, 64);
            float sc = rsqrtf(v * (1.0f / 128.0f) + 1e-6f);
            float y1 = x1 * sc * qw[lane], y2 = x2 * sc * qw[64 + lane];
            float c = rope[(long)row * 128 + lane], sn = rope[(long)row * 128 + 64 + lane];
            u16* dst = Qn + (((long)(b * 16 + h) * 512 + s) * 128);
            dst[lane] = f2bf(y1 * c - y2 * sn);
            dst[64 + lane] = f2bf(y2 * c + y1 * sn);
        } else if (wid < 20480) { // K: 1024 rows x 4 heads
            int j = wid - 16384;
            int row = j >> 2, h = j & 3;
            int b = row >> 9, s = row & 511;
            const float* src = QKVf + (long)row * 3072 + 2048 + h * 128;
            float x1 = src[lane], x2 = src[64 + lane];
            float v = x1 * x1 + x2 * x2;
#pragma unroll
            for (int off = 32; off; off >>= 1) v += __shfl_xor(v, off, 64);
            float sc = rsqrtf(v * (1.0f / 128.0f) + 1e-6f);
            float y1 = x1 * sc * kw[lane], y2 = x2 * sc * kw[64 + lane];
            float c = rope[(long)row * 128 + lane], sn = rope[(long)row * 128 + 64 + lane];
            float k1 = y1 * c - y2 * sn, k2 = y2 * c + y1 * sn;
            float* dst = present + (((long)(b * 2 + 0) * 4 + h) * MAXP_ + (start + s)) * 128;
            dst[lane] = k1; dst[64 + lane] = k2;
            u16* kc = Kc + (((long)(b * 4 + h)) * MAXP_ + start + s) * 128;
            kc[lane] = f2bf(k1); kc[64 + lane] = f2bf(k2);
        } else if (wid < 24576) { // V: present copy only
            int j = wid - 20480;
            int row = j >> 2, h = j & 3;
            int b = row >> 9, s = row & 511;
            const float* src = QKVf + (long)row * 3072 + 2560 + h * 128;
            float* dst = present + (((long)(b * 2 + 1) * 4 + h) * MAXP_ + (start + s)) * 128;
            dst[lane] = src[lane];
            dst[64 + lane] = src[64 + lane];
        }
        return;
    }
    // vtrans: new V -> Vtc bf16 [d][p]
    __shared__ __align__(16) u16 T[128][72];
    const int t = threadIdx.x;
    const int b2 = bid - 6144;
    const int s0 = (b2 & 7) * 64;
    const int bh = b2 >> 3, b = bh >> 2, h = bh & 3;
    const int sr = t >> 2, d0 = (t & 3) * 32;
    const float* src = QKVf + (long)(b * 512 + s0 + sr) * 3072 + 2560 + h * 128 + d0;
#pragma unroll
    for (int j = 0; j < 8; ++j) {
        f32x4 v = *(const f32x4*)(src + j * 4);
#pragma unroll
        for (int e = 0; e < 4; ++e) T[d0 + j * 4 + e][sr] = f2bf(v[e]);
    }
    __syncthreads();
    const int d = t >> 1, pc = (t & 1) * 32;
    u16* dst = Vtc + ((long)(b * 4 + h) * 128 + d) * MAXP_ + start + s0 + pc;
#pragma unroll
    for (int k = 0; k < 32; ++k) dst[k] = T[d][pc + k];  // scalar: start may be unaligned
}

// ---------------- flash attention: LDS-staged K/V, 8 waves, XCD-pinned, defer-max ----------------
// R15/R16 attn VERBATIM (proven). 512 blocks x 512 threads.
__global__ __launch_bounds__(512, 4) void attn(const u16* __restrict__ Qn,
        const u16* __restrict__ Kc, const u16* __restrict__ Vtc,
        const int* __restrict__ startp, const int* __restrict__ ctxp,
        u16* __restrict__ op, float* __restrict__ mp, float* __restrict__ lp) {
    __shared__ __align__(16) char KsB[2][16384];   // [buf][64 rows x 256B]
    __shared__ __align__(16) char VsB[2][16384];   // [buf][128 rows x 128B]
    const int tid = threadIdx.x, lane = tid & 63, w = tid >> 6;
    const int l15 = lane & 15, g = lane >> 4;
    const bool ghi = (g >= 2);
    const int id = blockIdx.x;
    const int bh = id & 7;
    const int rest = id >> 3;
    const int c = rest >> 4;
    const int q0 = (rest & 15) * 32;
    const int b = bh >> 2, hkv = bh & 3;
    const int hd = w & 3, qh = w >> 2;
    const int hq = hkv * 4 + hd;
    const int start = startp[0];
    const int ctx = ctxp[b];

    int lim_blk = start + q0 + 32;
    if (lim_blk > ctx) lim_blk = ctx;
    const int pbeg = c * CHUNKP;
    int pend = pbeg + CHUNKP;
    if (pend > lim_blk) pend = lim_blk;
    if (pbeg >= pend) return;               // block-uniform (before any barrier)

    const int qrow0 = q0 + qh * 16;
    const long rowbase = (long)(b * 16 + hq) * 512 + qrow0;

    bf16x8 qb[4];
    {
        const u16* qp = Qn + (rowbase + l15) * 128 + g * 8;
#pragma unroll
        for (int kf = 0; kf < 4; ++kf)
            qb[kf] = *(const bf16x8*)(qp + kf * 32);
    }

    const char* kb8 = (const char*)(Kc + (long)bh * (MAXP_ * 128));
    const char* vb8 = (const char*)(Vtc + (long)bh * (128 * MAXP_));

    const int wbase = (tid & ~63) * 16;
    auto STAGE = [&](int buf, int p0_) {
#pragma unroll
        for (int r = 0; r < 2; ++r) {
            int o_ = r * 8192 + tid * 16;
            int row = o_ >> 8;
            int colb = (o_ & 255) ^ ((row & 7) << 4);
            GLOAD16(kb8 + (long)(p0_ + row) * 256 + colb, &KsB[buf][r * 8192 + wbase]);
        }
#pragma unroll
        for (int r = 0; r < 2; ++r) {
            int o_ = r * 8192 + tid * 16;
            int row = o_ >> 7;
            int colb = (o_ & 127) ^ ((row & 7) << 4);
            GLOAD16(vb8 + (long)row * (MAXP_ * 2) + (long)p0_ * 2 + colb, &VsB[buf][r * 8192 + wbase]);
        }
    };

    f32x4 o[8] = {};
    float m_run = -1e30f, l_run = 0.f;
    int limq = start + qrow0 + l15 + 1;
    if (limq > ctx) limq = ctx;
    if (limq > pend) limq = pend;
    const int addrA = (l15 + ((g & 1) << 5)) << 2;
    const int addrB = addrA + 64;
    const float scale = 0.08838834764831845f;
    const int swz = (l15 & 7) << 4;

    const int t0 = pbeg >> 6, t1 = (pend + 63) >> 6;
    STAGE(0, t0 * 64);
    asm volatile("s_waitcnt vmcnt(0)" ::: "memory");
    __builtin_amdgcn_s_barrier();
    int cur = 0;
    for (int t = t0; t < t1; ++t) {
        const int p0 = t * 64;
        if (t + 1 < t1) STAGE(cur ^ 1, p0 + 64);
        f32x4 sacc[4] = {};
#pragma unroll
        for (int kt = 0; kt < 4; ++kt) {
            const char* krow = &KsB[cur][(kt * 16 + l15) * 256];
#pragma unroll
            for (int kf = 0; kf < 4; ++kf) {
                bf16x8 ka = *(const bf16x8*)(krow + ((kf * 64 + g * 16) ^ swz));
                sacc[kt] = __builtin_amdgcn_mfma_f32_16x16x32_bf16(ka, qb[kf], sacc[kt], 0, 0, 0);
            }
        }
        float mx = -1e30f;
#pragma unroll
        for (int kt = 0; kt < 4; ++kt)
#pragma unroll
            for (int r = 0; r < 4; ++r) {
                int key = p0 + kt * 16 + g * 4 + r;
                float x = (key < limq) ? sacc[kt][r] * scale : -1e30f;
                sacc[kt][r] = x;
                mx = fmaxf(mx, x);
            }
        mx = fmaxf(mx, __shfl_xor(mx, 16, 64));
        mx = fmaxf(mx, __shfl_xor(mx, 32, 64));
        if (!__all(mx <= m_run + 8.f)) {
            float mnew = fmaxf(m_run, mx);
            float alpha = __expf(m_run - mnew);
            m_run = mnew;
            l_run *= alpha;
            f32x4 av;
#pragma unroll
            for (int r = 0; r < 4; ++r) av[r] = __shfl(alpha, g * 4 + r, 64);
#pragma unroll
            for (int df = 0; df < 8; ++df) {
                o[df][0] *= av[0]; o[df][1] *= av[1];
                o[df][2] *= av[2]; o[df][3] *= av[3];
            }
        }
        const float mb = m_run;
        float rs = 0.f;
        u32 w0[4], w1[4];
#pragma unroll
        for (int kt = 0; kt < 4; ++kt) {
#pragma unroll
            for (int r = 0; r < 4; ++r) {
                float p = __expf(sacc[kt][r] - mb);
                sacc[kt][r] = p;
                rs += p;
            }
            w0[kt] = packbf(sacc[kt][0], sacc[kt][1]);
            w1[kt] = packbf(sacc[kt][2], sacc[kt][3]);
        }
        rs += __shfl_xor(rs, 16, 64);
        rs += __shfl_xor(rs, 32, 64);
        l_run += rs;
#pragma unroll
        for (int ks = 0; ks < 2; ++ks) {
            const int sL = 2 * ks, sH = 2 * ks + 1;
            u32 d0 = ghi ? bperm(addrA, w0[sH]) : bperm(addrA, w0[sL]);
            u32 d1 = ghi ? bperm(addrA, w1[sH]) : bperm(addrA, w1[sL]);
            u32 d2 = ghi ? bperm(addrB, w0[sH]) : bperm(addrB, w0[sL]);
            u32 d3 = ghi ? bperm(addrB, w1[sH]) : bperm(addrB, w1[sL]);
            union { u32 d[4]; bf16x8 v; } pu;
            pu.d[0] = d0; pu.d[1] = d1; pu.d[2] = d2; pu.d[3] = d3;
            bf16x8 pa = pu.v;
#pragma unroll
            for (int df = 0; df < 8; ++df) {
                const char* vrow = &VsB[cur][(df * 16 + l15) * 128];
                bf16x8 vb = *(const bf16x8*)(vrow + ((ks * 64 + g * 16) ^ swz));
                o[df] = __builtin_amdgcn_mfma_f32_16x16x32_bf16(pa, vb, o[df], 0, 0, 0);
            }
        }
        asm volatile("s_waitcnt vmcnt(0)" ::: "memory");
        __builtin_amdgcn_s_barrier();
        cur ^= 1;
    }
    {
        float invl = l_run > 0.f ? 1.0f / l_run : 0.f;
        f32x4 iv;
#pragma unroll
        for (int r = 0; r < 4; ++r) iv[r] = __shfl(invl, g * 4 + r, 64);
        u16* dst = op + ((long)c * TOTROWS + rowbase + g * 4) * 128 + l15;
#pragma unroll
        for (int r = 0; r < 4; ++r)
#pragma unroll
            for (int df = 0; df < 8; ++df)
                dst[(long)r * 128 + df * 16] = f2bf(o[df][r] * iv[r]);
        if (g == 0) {
            mp[(long)c * TOTROWS + rowbase + l15] = m_run;
            lp[(long)c * TOTROWS + rowbase + l15] = l_run;
        }
    }
}

// ---------------- combine split-KV partials -> Af bf16 [b*512+s][2048] ----------------
__global__ __launch_bounds__(256) void combine(const u16* __restrict__ op,
        const float* __restrict__ mp, const float* __restrict__ lp,
        const int* __restrict__ startp, const int* __restrict__ ctxp,
        u16* __restrict__ Af) {
    const int w = threadIdx.x >> 6, lane = threadIdx.x & 63;
    const long row = (long)blockIdx.x * 4 + w;
    const int b = (int)(row >> 13), hq = ((int)row >> 9) & 15, s = (int)row & 511;
    const int start = startp[0];
    int lim = start + s + 1;
    int cx = ctxp[b];
    if (lim > cx) lim = cx;
    float mc[NCALLOC], lc[NCALLOC];
    bool has[NCALLOC];
    float M = -1e30f;
#pragma unroll
    for (int c = 0; c < NCALLOC; ++c) {
        has[c] = (c * CHUNKP < lim);
        if (has[c]) {
            mc[c] = mp[(long)c * TOTROWS + row];
            lc[c] = lp[(long)c * TOTROWS + row];
            if (lc[c] > 0.f && mc[c] > M) M = mc[c];
        }
    }
    const int d0 = lane * 2;
    float Wt = 0.f, a0 = 0.f, a1 = 0.f;
#pragma unroll
    for (int c = 0; c < NCALLOC; ++c) {
        if (has[c] && lc[c] > 0.f) {
            float wg = lc[c] * __expf(mc[c] - M);
            Wt += wg;
            u32 pr = *(const u32*)&op[((long)c * TOTROWS + row) * 128 + d0];
            a0 += wg * bf2f((u16)(pr & 0xFFFF));
            a1 += wg * bf2f((u16)(pr >> 16));
        }
    }
    float inv = 1.0f / Wt;
    u32 pk = (u32)f2bf(a0 * inv) | ((u32)f2bf(a1 * inv) << 16);
    *(u32*)&Af[((long)(b * 512 + s) * 2048) + hq * 128 + d0] = pk;
}

extern "C" void kernel_launch(void* const* d_in, const int* in_sizes, int n_in,
                              void* d_out, int out_size, void* d_ws, size_t ws_size,
                              hipStream_t stream) {
    const float* hidden = (const float*)d_in[0];
    const float* past   = (const float*)d_in[1];
    const float* rope   = (const float*)d_in[2];
    const float* Wq     = (const float*)d_in[3];
    const float* Wk     = (const float*)d_in[4];
    const float* Wv     = (const float*)d_in[5];
    const float* Wo     = (const float*)d_in[6];
    const float* qw     = (const float*)d_in[7];
    const float* kw     = (const float*)d_in[8];
    const int*   ctx    = (const int*)d_in[9];
    const int*   start  = (const int*)d_in[10];

    float* out = (float*)d_out;
    float* present = out + 2097152;
    u16* Kc = (u16*)d_out;   // parked in attn-output region of d_out

    char* wsb = (char*)d_ws;
    u16*   hb    = (u16*)(wsb + 0);
    u16*   Wqkvt = (u16*)(wsb + 4194304);
    float* QKVf  = (float*)(wsb + 16777216);
    u16*   op    = (u16*)(wsb + 0);
    float* mp    = (float*)(wsb + 16777216);
    float* lp    = (float*)(wsb + 17039360);
    u16*   Qn    = (u16*)(wsb + 29360128);
    u16*   Af    = (u16*)(wsb + 29360128);
    u16*   Vtc   = (u16*)(wsb + 33554432);
    const bool bigws = (ws_size >= 50331648ull);   // 48 MiB
    u16* Wot = bigws ? (u16*)(wsb + 41943040) : (u16*)(wsb + 17301504);

    // past -> present: dedicated d2d copy (blit path, near-peak BW); must precede normrope_v.
    hipMemcpyAsync(present, past, 33554432ull, hipMemcpyDeviceToDevice, stream);

    if (bigws) {
        prep<<<dim3(4608), dim3(256), 0, stream>>>(hidden, Wq, Wk, Wv, Wo, past,
                hb, Wqkvt, Wot, Kc, Vtc, start, ctx);                                       // 1
        gemm64<<<dim3(768), dim3(256), 0, stream>>>(hb, Wqkvt, QKVf, 1024, 3072, 2048);     // 2
        normrope_v<<<dim3(6208), dim3(256), 0, stream>>>(QKVf, rope, qw, kw, start, present, Qn, Kc, Vtc); // 3
        attn<<<dim3(512), dim3(512), 0, stream>>>(Qn, Kc, Vtc, start, ctx, op, mp, lp);     // 4
        combine<<<dim3(4096), dim3(256), 0, stream>>>(op, mp, lp, start, ctx, Af);          // 5
        gemm64<<<dim3(512), dim3(256), 0, stream>>>(Af, Wot, out, 1024, 2048, 2048);        // 6
    } else {
        prep<<<dim3(3584), dim3(256), 0, stream>>>(hidden, Wq, Wk, Wv, Wo, past,
                hb, Wqkvt, Wot, Kc, Vtc, start, ctx);                                       // 1 (no Wo branch)
        gemm64<<<dim3(768), dim3(256), 0, stream>>>(hb, Wqkvt, QKVf, 1024, 3072, 2048);     // 2
        normrope_v<<<dim3(6208), dim3(256), 0, stream>>>(QKVf, rope, qw, kw, start, present, Qn, Kc, Vtc); // 3
        trans_w<<<dim3(32, 32), dim3(256), 0, stream>>>(Wo, Wot, 2048, 2048, 0);            // 4 (QKVf dead)
        attn<<<dim3(512), dim3(512), 0, stream>>>(Qn, Kc, Vtc, start, ctx, op, mp, lp);     // 5
        combine<<<dim3(4096), dim3(256), 0, stream>>>(op, mp, lp, start, ctx, Af);          // 6
        gemm64<<<dim3(512), dim3(256), 0, stream>>>(Af, Wot, out, 1024, 2048, 2048);        // 7
    }
}